// Round 9
// baseline (789.817 us; speedup 1.0000x reference)
//
#include <hip/hip_runtime.h>
#include <math.h>

// ---------------------------------------------------------------------------
// VQ-VAE forward on MI355X — round 9: g1 split-K x2 (+reduce), fused preps,
// fix_reduce folded into F2 staging. Everything else identical to round 8.
//   g1: partials = x @ W1^T (split-K, f32 partials in z_e section)
//       g1_reduce: h1 = relu(P0+P1+b1) -> hi/lo planes (emb_o section)
//   g2: z_e = h1 @ W2^T + b2            [planes -> f32 z_e output]
//   vq_mfma: MFMA dots + top-2 argmin + gap flag (GAP_T=2e-4)
//   fixup: F1 Part[c] = gatherX @ W1^T (6-way split-K, f64)
//          F2 Zf = relu(sum Part + b1) @ W2^T + b2  (fused reduce in staging)
//          F3 exact distances + argmin + z_q scatter
//   g3: h3 = relu(z_q @ W3^T + b3);  g4: recon = sigmoid(h3 @ W4^T + b4)
// ---------------------------------------------------------------------------

typedef short bf16x8 __attribute__((ext_vector_type(8)));
typedef short short8 __attribute__((ext_vector_type(8)));
typedef float f32x4  __attribute__((ext_vector_type(4)));

#define GAP_T   2e-4
#define FIX_CAP 4096

__device__ __forceinline__ unsigned short f32_to_bf16_rn(float v) {
    union { float f; unsigned u; } c; c.f = v;
    unsigned r = c.u + 0x7FFFu + ((c.u >> 16) & 1u);
    return (unsigned short)(r >> 16);
}
__device__ __forceinline__ float bf16_bits_to_f32(unsigned short b) {
    union { unsigned u; float f; } c; c.u = ((unsigned)b) << 16;
    return c.f;
}
__device__ __forceinline__ void glds16(const short* g, short* l) {
    __builtin_amdgcn_global_load_lds(
        (const __attribute__((address_space(1))) unsigned int*)g,
        (__attribute__((address_space(3))) unsigned int*)l, 16, 0, 0);
}

// ================= plane prep: all four weight matrices, one launch =========
__global__ __launch_bounds__(256) void prep_wall(
    const float* __restrict__ W1, const float* __restrict__ W2,
    const float* __restrict__ W3, const float* __restrict__ W4,
    short* __restrict__ w1h, short* __restrict__ w1l,
    short* __restrict__ w2h, short* __restrict__ w2l,
    short* __restrict__ w3h, short* __restrict__ w4h)
{
    // segments: [0,384) W1(400,3072,96) | [384,488) W2(1024,400,13)
    //           [488,616) W3(400,1024,32) | [616,928) W4(3072,400,13)
    const int bid = blockIdx.x;
    const float* Wsrc; int N, K, KT, local; short *hi, *lo;
    if (bid < 384)      { Wsrc = W1; N = 400;  K = 3072; KT = 96; local = bid;       hi = w1h; lo = w1l; }
    else if (bid < 488) { Wsrc = W2; N = 1024; K = 400;  KT = 13; local = bid - 384; hi = w2h; lo = w2l; }
    else if (bid < 616) { Wsrc = W3; N = 400;  K = 1024; KT = 32; local = bid - 488; hi = w3h; lo = nullptr; }
    else                { Wsrc = W4; N = 3072; K = 400;  KT = 13; local = bid - 616; hi = w4h; lo = nullptr; }

    const int kt = local % KT;
    const int nb = local / KT;
    const size_t tb = (size_t)local * 4096;
    for (int ci = threadIdx.x; ci < 512; ci += 256) {
        const int row = ci >> 2;
        const int sl  = ci & 3;
        const int k0  = ((sl ^ (row & 3)) << 3);
        const int n   = nb * 128 + row;
        const int kk  = kt * 32 + k0;
        float f[8];
        #pragma unroll
        for (int e = 0; e < 8; ++e)
            f[e] = (n < N && kk + e < K) ? Wsrc[(size_t)n * K + kk + e] : 0.f;
        short8 h, l;
        #pragma unroll
        for (int e = 0; e < 8; ++e) {
            const unsigned short hb = f32_to_bf16_rn(f[e]);
            h[e] = (short)hb;
            l[e] = (short)f32_to_bf16_rn(f[e] - bf16_bits_to_f32(hb));
        }
        *reinterpret_cast<short8*>(&hi[tb + ci * 8]) = h;
        if (lo) *reinterpret_cast<short8*>(&lo[tb + ci * 8]) = l;
    }
}

// ========================= plane prep: x (A operand) ========================
__global__ __launch_bounds__(256) void prep_xplanes(
    const float* __restrict__ x, short* __restrict__ hi, short* __restrict__ lo)
{
    const int kt = blockIdx.x % 96;
    const int mb = blockIdx.x / 96;
    const size_t tb = (size_t)blockIdx.x * 4096;
    for (int ci = threadIdx.x; ci < 512; ci += 256) {
        const int row = ci >> 2;
        const int sl  = ci & 3;
        const int k0  = ((sl ^ (row & 3)) << 3);
        const float* src = &x[(size_t)(mb * 128 + row) * 3072 + kt * 32 + k0];
        const float4 f0 = *reinterpret_cast<const float4*>(src);
        const float4 f1 = *reinterpret_cast<const float4*>(src + 4);
        const float ff[8] = {f0.x, f0.y, f0.z, f0.w, f1.x, f1.y, f1.z, f1.w};
        short8 h, l;
        #pragma unroll
        for (int e = 0; e < 8; ++e) {
            const unsigned short hb = f32_to_bf16_rn(ff[e]);
            h[e] = (short)hb;
            l[e] = (short)f32_to_bf16_rn(ff[e] - bf16_bits_to_f32(hb));
        }
        *reinterpret_cast<short8*>(&hi[tb + ci * 8]) = h;
        *reinterpret_cast<short8*>(&lo[tb + ci * 8]) = l;
    }
}

// ====================== plane-fed MFMA GEMM (NT) ===========================
// OUTMODE: 0 f32 C; 1 hi plane; 2 hi+lo planes; 3 f32 K-split partial
// (no bias/act, col-stride = KTout, chunk blockIdx.z, rows 16384)
template<int NSPLIT, int ACT, int AMODE, int OUTMODE, int KSPLIT>
__global__ __launch_bounds__(256) void gemm_pl(
    const short* __restrict__ Ahi, const short* __restrict__ Alo,
    const float* __restrict__ Af32, int AK,
    const short* __restrict__ Bhi, const short* __restrict__ Blo,
    const float* __restrict__ bias,
    float* __restrict__ Cf32, short* __restrict__ Cphi, short* __restrict__ Cplo,
    int N, int KT, int KTout)
{
    __shared__ short lds[NSPLIT * 2 * 4096];

    const int tid  = threadIdx.x;
    const int lane = tid & 63;
    const int w_id = tid >> 6;
    const int wr   = (w_id >> 1) * 64;
    const int wc   = (w_id & 1)  * 64;
    const int m0   = blockIdx.y * 128;
    const int n0   = blockIdx.x * 128;
    const int l15  = lane & 15;
    const int lg   = lane >> 4;

    f32x4 acc[4][4];
    #pragma unroll
    for (int i = 0; i < 4; ++i)
        #pragma unroll
        for (int j = 0; j < 4; ++j) acc[i][j] = (f32x4){0.f, 0.f, 0.f, 0.f};

    const int kchunk = KT / KSPLIT;
    const int ktbeg  = (KSPLIT > 1) ? blockIdx.z * kchunk : 0;

    for (int kt = ktbeg; kt < ktbeg + kchunk; ++kt) {
        if (AMODE == 0) {
            const size_t at = ((size_t)blockIdx.y * KT + kt) * 4096;
            #pragma unroll
            for (int q = 0; q < 2; ++q) {
                const int o = (w_id * 2 + q) * 512 + lane * 8;
                glds16(Ahi + at + o, &lds[o]);
                if (NSPLIT > 1) glds16(Alo + at + o, &lds[4096 + o]);
            }
        } else {
            #pragma unroll
            for (int i = 0; i < 2; ++i) {
                const int ci  = tid + i * 256;
                const int row = ci >> 2;
                const int sl  = ci & 3;
                const int k0  = ((sl ^ (row & 3)) << 3);
                const float* src = &Af32[(size_t)(m0 + row) * AK + kt * 32 + k0];
                const float4 f0 = *reinterpret_cast<const float4*>(src);
                const float4 f1 = *reinterpret_cast<const float4*>(src + 4);
                const float ff[8] = {f0.x, f0.y, f0.z, f0.w, f1.x, f1.y, f1.z, f1.w};
                short8 h;
                #pragma unroll
                for (int e = 0; e < 8; ++e) h[e] = (short)f32_to_bf16_rn(ff[e]);
                *reinterpret_cast<short8*>(&lds[ci * 8]) = h;
            }
        }
        {
            const size_t bt = ((size_t)blockIdx.x * KT + kt) * 4096;
            #pragma unroll
            for (int q = 0; q < 2; ++q) {
                const int o = (w_id * 2 + q) * 512 + lane * 8;
                glds16(Bhi + bt + o, &lds[NSPLIT * 4096 + o]);
                if (NSPLIT > 1) glds16(Blo + bt + o, &lds[(NSPLIT + 1) * 4096 + o]);
            }
        }
        __syncthreads();

        bf16x8 bfr[4][NSPLIT];
        #pragma unroll
        for (int fc = 0; fc < 4; ++fc) {
            const int rn  = wc + fc * 16 + l15;
            const int idx = rn * 32 + ((lg ^ (rn & 3)) << 3);
            #pragma unroll
            for (int s = 0; s < NSPLIT; ++s)
                bfr[fc][s] = *reinterpret_cast<const bf16x8*>(&lds[(NSPLIT + s) * 4096 + idx]);
        }
        #pragma unroll
        for (int fr = 0; fr < 4; ++fr) {
            const int rm  = wr + fr * 16 + l15;
            const int idx = rm * 32 + ((lg ^ (rm & 3)) << 3);
            const bf16x8 a0 = *reinterpret_cast<const bf16x8*>(&lds[idx]);
            bf16x8 a1;
            if (NSPLIT > 1)
                a1 = *reinterpret_cast<const bf16x8*>(&lds[4096 + idx]);
            #pragma unroll
            for (int fc = 0; fc < 4; ++fc) {
                acc[fr][fc] = __builtin_amdgcn_mfma_f32_16x16x32_bf16(
                    a0, bfr[fc][0], acc[fr][fc], 0, 0, 0);
                if (NSPLIT > 1) {
                    acc[fr][fc] = __builtin_amdgcn_mfma_f32_16x16x32_bf16(
                        a0, bfr[fc][1], acc[fr][fc], 0, 0, 0);
                    acc[fr][fc] = __builtin_amdgcn_mfma_f32_16x16x32_bf16(
                        a1, bfr[fc][0], acc[fr][fc], 0, 0, 0);
                }
            }
        }
        __syncthreads();
    }

    if (OUTMODE == 3) {
        float* P = Cf32 + (size_t)blockIdx.z * 16384 * KTout;
        #pragma unroll
        for (int fr = 0; fr < 4; ++fr)
            #pragma unroll
            for (int fc = 0; fc < 4; ++fc) {
                const int col = n0 + wc + fc * 16 + l15;
                #pragma unroll
                for (int j = 0; j < 4; ++j) {
                    const int rowg = m0 + wr + fr * 16 + lg * 4 + j;
                    P[(size_t)rowg * KTout + col] = acc[fr][fc][j];
                }
            }
        return;
    }

    float bv[4];
    #pragma unroll
    for (int fc = 0; fc < 4; ++fc) {
        const int col = n0 + wc + fc * 16 + l15;
        bv[fc] = (col < N) ? bias[col] : 0.f;
    }
    #pragma unroll
    for (int fr = 0; fr < 4; ++fr) {
        #pragma unroll
        for (int fc = 0; fc < 4; ++fc) {
            const int col = n0 + wc + fc * 16 + l15;
            #pragma unroll
            for (int j = 0; j < 4; ++j) {
                const int rowg = m0 + wr + fr * 16 + lg * 4 + j;
                float v = acc[fr][fc][j] + bv[fc];
                if (ACT == 1) v = fmaxf(v, 0.f);
                else if (ACT == 2) v = 1.f / (1.f + expf(-v));
                if (OUTMODE == 0) {
                    if (col < N) Cf32[(size_t)rowg * N + col] = v;
                } else {
                    const int kto = col >> 5;
                    if (kto < KTout) {
                        const int r = rowg & 127, k = col & 31;
                        const size_t off = ((size_t)blockIdx.y * KTout + kto) * 4096
                                         + r * 32 + (((k >> 3) ^ (r & 3)) << 3) + (k & 7);
                        const unsigned short hb = f32_to_bf16_rn(v);
                        Cphi[off] = (short)hb;
                        if (OUTMODE == 2)
                            Cplo[off] = (short)f32_to_bf16_rn(v - bf16_bits_to_f32(hb));
                    }
                }
            }
        }
    }
}

// ========== g1 reduce: h1 = relu(P0+P1+b1) -> hi/lo planes ==================
__global__ __launch_bounds__(256) void g1_reduce(
    const float* __restrict__ part, const float* __restrict__ b1,
    short* __restrict__ h1h, short* __restrict__ h1l)
{
    const int kto = blockIdx.x % 13;
    const int mb  = blockIdx.x / 13;
    const size_t tb = (size_t)blockIdx.x * 4096;
    const float* p1 = part + (size_t)16384 * 512;
    for (int ci = threadIdx.x; ci < 512; ci += 256) {
        const int row = ci >> 2;
        const int sl  = ci & 3;
        const int k0  = ((sl ^ (row & 3)) << 3);
        const int gr  = mb * 128 + row;
        const int gc  = kto * 32 + k0;
        const size_t base = (size_t)gr * 512 + gc;
        short8 h, l;
        #pragma unroll
        for (int e = 0; e < 8; ++e) {
            const int n = gc + e;
            float v = part[base + e] + p1[base + e] + (n < 400 ? b1[n] : 0.f);
            v = fmaxf(v, 0.f);
            const unsigned short hb = f32_to_bf16_rn(v);
            h[e] = (short)hb;
            l[e] = (short)f32_to_bf16_rn(v - bf16_bits_to_f32(hb));
        }
        *reinterpret_cast<short8*>(&h1h[tb + ci * 8]) = h;
        *reinterpret_cast<short8*>(&h1l[tb + ci * 8]) = l;
    }
}

// ============================ VQ prep (one block) ===========================
__global__ void vq_prep(const float* __restrict__ Wemb, short* __restrict__ planes,
                        double* __restrict__ wn, int* __restrict__ flag_cnt)
{
    const int tid = threadIdx.x;
    if (tid == 0) *flag_cnt = 0;
    if (tid < 128) {
        double s = 0.0;
        for (int k = 0; k < 128; ++k) {
            const double w = (double)Wemb[k * 128 + tid];
            s = fma(w, w, s);
        }
        wn[tid] = s;
    }
    for (int t = tid; t < 16384; t += 256) {
        const int k = t >> 7, n = t & 127;
        const float w = Wemb[t];
        const unsigned short hi = f32_to_bf16_rn(w);
        const unsigned short lo = f32_to_bf16_rn(w - bf16_bits_to_f32(hi));
        const int off = n * 128 + (((k >> 3) ^ (n & 7)) << 3) + (k & 7);
        planes[off]         = (short)hi;
        planes[16384 + off] = (short)lo;
    }
}

// ============================ VQ MFMA + argmin ==============================
__global__ __launch_bounds__(512) void vq_mfma(
    const float* __restrict__ z_e, const short* __restrict__ planes,
    const double* __restrict__ wn_g, float* __restrict__ zq,
    int* __restrict__ flag_cnt, int* __restrict__ flag_ids)
{
    __shared__ short  Wsh[32768];
    __shared__ float  zsh[16 * 1024];
    __shared__ double wn_sh[128];
    __shared__ double cmb_v1[128][2];
    __shared__ double cmb_v2[128][2];
    __shared__ int    cmb_i[128][2];
    __shared__ int    idx_sh[128];
    __shared__ int    sflag[16];

    const int tid = threadIdx.x;
    const int b0  = blockIdx.x * 16;

    for (int c = tid; c < 4096; c += 512)
        *reinterpret_cast<int4*>(&Wsh[c * 8]) =
            *reinterpret_cast<const int4*>(&planes[c * 8]);
    for (int c = tid; c < 128; c += 512) wn_sh[c] = wn_g[c];
    for (int c = tid; c < 4096; c += 512) {
        const int D    = c * 16;
        const int s    = D >> 12;
        const int dr   = D & 4095;
        const int srcb = dr ^ (((dr >> 8) & 3) << 5);
        *reinterpret_cast<int4*>(reinterpret_cast<char*>(zsh) + D) =
            *reinterpret_cast<const int4*>(
                reinterpret_cast<const char*>(z_e) + (size_t)(b0 + s) * 4096 + srcb);
    }
    if (tid < 16) sflag[tid] = 0;
    __syncthreads();

    const int lane = tid & 63;
    const int w_id = tid >> 6;
    const int wr   = (w_id >> 1) * 32;
    const int wc   = (w_id & 1) * 64;
    const int l15  = lane & 15;
    const int lg   = lane >> 4;

    f32x4 acc[2][4];
    #pragma unroll
    for (int i = 0; i < 2; ++i)
        #pragma unroll
        for (int j = 0; j < 4; ++j) acc[i][j] = (f32x4){0.f, 0.f, 0.f, 0.f};

    #pragma unroll
    for (int ks = 0; ks < 4; ++ks) {
        bf16x8 bh[4], bl[4];
        #pragma unroll
        for (int cf = 0; cf < 4; ++cf) {
            const int n     = wc + cf * 16 + l15;
            const int slotp = (ks * 4 + lg) ^ (n & 7);
            const int off   = n * 128 + slotp * 8;
            bh[cf] = *reinterpret_cast<const bf16x8*>(&Wsh[off]);
            bl[cf] = *reinterpret_cast<const bf16x8*>(&Wsh[16384 + off]);
        }
        bf16x8 ah[2], al[2];
        #pragma unroll
        for (int rf = 0; rf < 2; ++rf) {
            const int row   = wr + rf * 16 + l15;
            const int s_loc = row >> 3;
            const int d     = row & 7;
            const int kb    = ks * 32 + lg * 8;
            const int xr    = (lg & 3) << 5;
            const char* zb  = reinterpret_cast<const char*>(zsh) + s_loc * 4096;
            bf16x8 h8, L8;
            #pragma unroll
            for (int j = 0; j < 8; ++j) {
                const float a = *reinterpret_cast<const float*>(
                    zb + ((32 * (kb + j) + 4 * d) ^ xr));
                const unsigned short hi = f32_to_bf16_rn(a);
                h8[j] = (short)hi;
                L8[j] = (short)f32_to_bf16_rn(a - bf16_bits_to_f32(hi));
            }
            ah[rf] = h8; al[rf] = L8;
        }
        #pragma unroll
        for (int rf = 0; rf < 2; ++rf)
            #pragma unroll
            for (int cf = 0; cf < 4; ++cf) {
                acc[rf][cf] = __builtin_amdgcn_mfma_f32_16x16x32_bf16(
                    ah[rf], bh[cf], acc[rf][cf], 0, 0, 0);
                acc[rf][cf] = __builtin_amdgcn_mfma_f32_16x16x32_bf16(
                    ah[rf], bl[cf], acc[rf][cf], 0, 0, 0);
                acc[rf][cf] = __builtin_amdgcn_mfma_f32_16x16x32_bf16(
                    al[rf], bh[cf], acc[rf][cf], 0, 0, 0);
            }
    }

    #pragma unroll
    for (int rf = 0; rf < 2; ++rf)
        #pragma unroll
        for (int j = 0; j < 4; ++j) {
            double v1 = 1e300, v2 = 1e300; int i1 = 0;
            #pragma unroll
            for (int cf = 0; cf < 4; ++cf) {
                const int n = wc + cf * 16 + l15;
                const double v = wn_sh[n] - 2.0 * (double)acc[rf][cf][j];
                if (v < v1)      { v2 = v1; v1 = v; i1 = n; }
                else if (v < v2) { v2 = v; }
            }
            #pragma unroll
            for (int off = 1; off < 16; off <<= 1) {
                const double ov1 = __shfl_xor(v1, off);
                const int    oi1 = __shfl_xor(i1, off);
                const double ov2 = __shfl_xor(v2, off);
                if (ov1 < v1 || (ov1 == v1 && oi1 < i1)) {
                    v2 = fmin(v1, ov2); v1 = ov1; i1 = oi1;
                } else {
                    v2 = fmin(v2, ov1);
                }
            }
            if (l15 == 0) {
                const int r = wr + rf * 16 + lg * 4 + j;
                cmb_v1[r][w_id & 1] = v1;
                cmb_v2[r][w_id & 1] = v2;
                cmb_i [r][w_id & 1] = i1;
            }
        }
    __syncthreads();

    if (tid < 128) {
        const double v1a = cmb_v1[tid][0], v1b = cmb_v1[tid][1];
        double v1, v2; int i1;
        if (v1b < v1a) { v1 = v1b; i1 = cmb_i[tid][1]; v2 = fmin(v1a, cmb_v2[tid][1]); }
        else           { v1 = v1a; i1 = cmb_i[tid][0]; v2 = fmin(v1b, cmb_v2[tid][0]); }
        idx_sh[tid] = i1;
        if (v2 - v1 < GAP_T) sflag[tid >> 3] = 1;
    }
    __syncthreads();
    if (tid < 16 && sflag[tid]) {
        const int p = atomicAdd(flag_cnt, 1);
        flag_ids[p] = b0 + tid;
    }

    for (int t = tid; t < 16384; t += 512) {
        const int s = t >> 10, i = t & 1023;
        const int k = i >> 3, d = i & 7;
        const int n = idx_sh[(s << 3) | d];
        const int off = n * 128 + (((k >> 3) ^ (n & 7)) << 3) + (k & 7);
        const float val = bf16_bits_to_f32((unsigned short)Wsh[off]) +
                          bf16_bits_to_f32((unsigned short)Wsh[16384 + off]);
        zq[(size_t)(b0 + s) * 1024 + i] = val;
    }
}

// ================= fixup F1/F2: 64x64-tile f64 GEMM (NT) ===================
// FUSERED (F2): A element = relu(b1[k] + sum_{c<6} Part[c][m][k]).
#define FLP 68
template<bool GATHER, bool SPLITK, bool FUSERED, typename TA>
__global__ __launch_bounds__(256) void gemm_f64t(
    const TA* __restrict__ A, const float* __restrict__ Wf,
    const int* __restrict__ ids, const int* __restrict__ cntp,
    const float* __restrict__ biasA, const float* __restrict__ bias,
    double* __restrict__ C,
    int AK, int N, int CN, int klen, int cap)
{
    __shared__ double As[16 * FLP];
    __shared__ double Ws[16 * FLP];

    const int tid = threadIdx.x;
    const int tx  = tid & 15;
    const int ty  = tid >> 4;
    const int m0  = blockIdx.y * 64;
    const int n0  = blockIdx.x * 64;
    const int cnt = (*cntp < cap) ? *cntp : cap;
    if (m0 >= cnt) return;

    const int k0 = SPLITK ? blockIdx.z * klen : 0;
    if (SPLITK) C += (size_t)blockIdx.z * cap * CN;

    const int srow = tid >> 2;
    const int sc4  = (tid & 3) << 2;

    const TA* arow;
    if (GATHER) {
        const int m  = m0 + srow;
        const int id = (m < cnt) ? ids[m] : 0;
        arow = A + (size_t)id * AK;
    } else {
        arow = A + (size_t)(m0 + srow) * AK;
    }
    const int   nrow = n0 + srow;
    const float* wrow = Wf + (size_t)(nrow < N ? nrow : 0) * AK;
    const bool  wok  = (nrow < N);

    double acc[4][4];
    #pragma unroll
    for (int i = 0; i < 4; ++i)
        #pragma unroll
        for (int j = 0; j < 4; ++j) acc[i][j] = 0.0;

    for (int kt = 0; kt < klen; kt += 16) {
        const int kb = k0 + kt + sc4;
        if constexpr (FUSERED) {
            const size_t cs = (size_t)cap * AK;
            #pragma unroll
            for (int e = 0; e < 4; ++e) {
                double s = (double)biasA[kb + e];
                #pragma unroll
                for (int c = 0; c < 6; ++c) s += arow[c * cs + kb + e];
                As[(sc4 + e) * FLP + srow] = s > 0.0 ? s : 0.0;
            }
        } else if constexpr (sizeof(TA) == 4) {
            const float4 v = *reinterpret_cast<const float4*>(&arow[kb]);
            As[(sc4 + 0) * FLP + srow] = (double)v.x;
            As[(sc4 + 1) * FLP + srow] = (double)v.y;
            As[(sc4 + 2) * FLP + srow] = (double)v.z;
            As[(sc4 + 3) * FLP + srow] = (double)v.w;
        } else {
            const double2 v0 = *reinterpret_cast<const double2*>(&arow[kb]);
            const double2 v1 = *reinterpret_cast<const double2*>(&arow[kb + 2]);
            As[(sc4 + 0) * FLP + srow] = v0.x;
            As[(sc4 + 1) * FLP + srow] = v0.y;
            As[(sc4 + 2) * FLP + srow] = v1.x;
            As[(sc4 + 3) * FLP + srow] = v1.y;
        }
        float4 w = make_float4(0.f, 0.f, 0.f, 0.f);
        if (wok) w = *reinterpret_cast<const float4*>(&wrow[kb]);
        Ws[(sc4 + 0) * FLP + srow] = (double)w.x;
        Ws[(sc4 + 1) * FLP + srow] = (double)w.y;
        Ws[(sc4 + 2) * FLP + srow] = (double)w.z;
        Ws[(sc4 + 3) * FLP + srow] = (double)w.w;
        __syncthreads();

        #pragma unroll
        for (int k = 0; k < 16; ++k) {
            const double2 A0 = *reinterpret_cast<const double2*>(&As[k * FLP + ty * 4]);
            const double2 A1 = *reinterpret_cast<const double2*>(&As[k * FLP + ty * 4 + 2]);
            const double2 B0 = *reinterpret_cast<const double2*>(&Ws[k * FLP + tx * 4]);
            const double2 B1 = *reinterpret_cast<const double2*>(&Ws[k * FLP + tx * 4 + 2]);
            const double a[4] = {A0.x, A0.y, A1.x, A1.y};
            const double b[4] = {B0.x, B0.y, B1.x, B1.y};
            #pragma unroll
            for (int i = 0; i < 4; ++i)
                #pragma unroll
                for (int j = 0; j < 4; ++j)
                    acc[i][j] = fma(a[i], b[j], acc[i][j]);
        }
        __syncthreads();
    }

    #pragma unroll
    for (int i = 0; i < 4; ++i) {
        const int row = m0 + ty * 4 + i;
        #pragma unroll
        for (int j = 0; j < 4; ++j) {
            const int col = n0 + tx * 4 + j;
            if (col < N)
                C[(size_t)row * CN + col] =
                    acc[i][j] + (bias ? (double)bias[col] : 0.0);
        }
    }
}

// ======= fixup F3: exact f64 distances + argmin + z_q scatter ===============
__global__ __launch_bounds__(512) void fix_argmin(
    const double* __restrict__ Zf, const float* __restrict__ Wemb,
    const int* __restrict__ cntp, const int* __restrict__ ids,
    float* __restrict__ zq, int cap)
{
    __shared__ float  wesh[16384];
    __shared__ double zsh[4][1032];
    __shared__ double dist[4 * 8 * 128];
    __shared__ int    idxf[32];

    const int tid  = threadIdx.x;
    const int lane = tid & 63;
    const int wv   = tid >> 6;
    const int cnt  = (*cntp < cap) ? *cntp : cap;
    const int base = blockIdx.x * 4;
    if (base >= cnt) return;
    const int ns = (cnt - base < 4) ? (cnt - base) : 4;

    for (int i = tid; i < 4096; i += 512)
        reinterpret_cast<float4*>(wesh)[i] =
            reinterpret_cast<const float4*>(Wemb)[i];
    for (int i = tid; i < 4 * 512; i += 512) {
        const int s = i >> 9, e = (i & 511) * 2;
        if (s < ns) {
            const double2 v = *reinterpret_cast<const double2*>(
                &Zf[(size_t)(base + s) * 1024 + e]);
            zsh[s][e] = v.x;
            zsh[s][e + 1] = v.y;
        }
    }
    __syncthreads();

    for (int t = tid; t < ns * 1024; t += 512) {
        const int s = t >> 10, d = (t >> 7) & 7, n = t & 127;
        double acc = 0.0;
        for (int k = 0; k < 128; ++k) {
            const double diff = zsh[s][k * 8 + d] - (double)wesh[k * 128 + n];
            acc = fma(diff, diff, acc);
        }
        dist[(s * 8 + d) * 128 + n] = acc;
    }
    __syncthreads();

    for (int p = wv; p < ns * 8; p += 8) {
        const double* dp = &dist[p * 128];
        double v0 = dp[lane], vx = dp[lane + 64];
        double v; int ix;
        if (vx < v0) { v = vx; ix = lane + 64; }
        else         { v = v0; ix = lane; }
        #pragma unroll
        for (int off = 32; off > 0; off >>= 1) {
            const double ov = __shfl_down(v, off);
            const int    oi = __shfl_down(ix, off);
            if (ov < v || (ov == v && oi < ix)) { v = ov; ix = oi; }
        }
        if (lane == 0) idxf[p] = ix;
    }
    __syncthreads();

    for (int i = tid; i < ns * 1024; i += 512) {
        const int s = i >> 10, ii = i & 1023;
        zq[(size_t)ids[base + s] * 1024 + ii] =
            wesh[(ii >> 3) * 128 + idxf[s * 8 + (ii & 7)]];
    }
}

// ---------------------------------------------------------------------------
extern "C" void kernel_launch(void* const* d_in, const int* in_sizes, int n_in,
                              void* d_out, int out_size, void* d_ws, size_t ws_size,
                              hipStream_t stream)
{
    const float* x    = (const float*)d_in[0];
    const float* W1   = (const float*)d_in[1];
    const float* b1   = (const float*)d_in[2];
    const float* W2   = (const float*)d_in[3];
    const float* b2   = (const float*)d_in[4];
    const float* W3   = (const float*)d_in[5];
    const float* b3   = (const float*)d_in[6];
    const float* W4   = (const float*)d_in[7];
    const float* b4   = (const float*)d_in[8];
    const float* Wemb = (const float*)d_in[9];

    const int B = 16384;
    float* out   = (float*)d_out;
    float* recon = out;                                // B*3072
    float* z_e   = out + (size_t)B * 3072;             // B*1024
    float* emb_o = z_e + (size_t)B * 1024;             // B*1024 == z_q

    constexpr size_t X_PL  = 50331648;
    constexpr size_t H1_PL = 6815744;
    constexpr size_t H3_PL = 6815744;
    constexpr size_t W1_PL = 1572864;
    constexpr size_t W2_PL = 425984;
    constexpr size_t W3_PL = 524288;
    constexpr size_t W4_PL = 1277952;

    short* xh  = (short*)recon;          // x planes in recon section
    short* xl  = xh + X_PL;
    short* h1h = (short*)emb_o;          // h1 planes in emb_o section
    short* h1l = h1h + H1_PL;

    short*  h3h      = (short*)d_ws;
    short*  w1h      = h3h + H3_PL;
    short*  w1l      = w1h + W1_PL;
    short*  w2h      = w1l + W1_PL;
    short*  w2l      = w2h + W2_PL;
    short*  w3h      = w2l + W2_PL;
    short*  w4h      = w3h + W3_PL;
    short*  wembpl   = w4h + W4_PL;
    double* wn       = (double*)(wembpl + 32768);
    int*    flag_cnt = (int*)(wn + 128);
    int*    flag_ids = flag_cnt + 64;

    // g1 split-K partials live in the z_e section (dead until g2 writes it):
    // 2 chunks x 16384 x 512 f32 = 67.1 MB = exactly the z_e section size.
    float* partial = z_e;

    // fixup scratch in the recon section (x-planes dead after g1; g4 writes
    // recon last): Part[6] @ +0 (78.6MB), Zf @ +96MB (33.5MB)
    char*   scr  = (char*)recon;
    double* Part = (double*)scr;
    double* Zf   = (double*)(scr + (96ull << 20));

    // ---- prep ----
    prep_wall<<<dim3(928), dim3(256), 0, stream>>>(
        W1, W2, W3, W4, w1h, w1l, w2h, w2l, w3h, w4h);
    prep_xplanes<<<dim3(12288), dim3(256), 0, stream>>>(x, xh, xl);
    vq_prep<<<dim3(1), dim3(256), 0, stream>>>(Wemb, wembpl, wn, flag_cnt);

    // ---- encoder ----
    // g1: split-K x2 partials (f32, no bias/act) -> reduce to h1 planes
    gemm_pl<2, 0, 0, 3, 2><<<dim3(4, 128, 2), dim3(256), 0, stream>>>(
        xh, xl, nullptr, 0, w1h, w1l, b1, partial, nullptr, nullptr, 400, 96, 512);
    g1_reduce<<<dim3(1664), dim3(256), 0, stream>>>(partial, b1, h1h, h1l);
    // g2: z_e (overwrites the partial buffer with the real output)
    gemm_pl<2, 0, 0, 0, 1><<<dim3(8, 128), dim3(256), 0, stream>>>(
        h1h, h1l, nullptr, 0, w2h, w2l, b2, z_e, nullptr, nullptr, 1024, 13, 0);

    // ---- VQ + fixup ----
    vq_mfma<<<dim3(1024), dim3(512), 0, stream>>>(z_e, wembpl, wn, emb_o,
                                                  flag_cnt, flag_ids);
    gemm_f64t<true, true, false, float><<<dim3(7, FIX_CAP / 64, 6), dim3(256), 0, stream>>>(
        x, W1, flag_ids, flag_cnt, nullptr, nullptr, Part, 3072, 400, 400, 512, FIX_CAP);
    gemm_f64t<false, false, true, double><<<dim3(16, FIX_CAP / 64), dim3(256), 0, stream>>>(
        Part, W2, nullptr, flag_cnt, b1, b2, Zf, 400, 1024, 1024, 400, FIX_CAP);
    fix_argmin<<<dim3(FIX_CAP / 4), dim3(512), 0, stream>>>(
        Zf, Wemb, flag_cnt, flag_ids, emb_o, FIX_CAP);

    // ---- decoder ----
    gemm_pl<1, 1, 1, 1, 1><<<dim3(4, 128), dim3(256), 0, stream>>>(
        nullptr, nullptr, emb_o, 1024, w3h, nullptr, b3, nullptr, h3h, nullptr,
        400, 32, 13);
    gemm_pl<1, 2, 0, 0, 1><<<dim3(24, 128), dim3(256), 0, stream>>>(
        h3h, nullptr, nullptr, 0, w4h, nullptr, b4, recon, nullptr, nullptr,
        3072, 13, 0);
}

// Round 10
// 765.443 us; speedup vs baseline: 1.0318x; 1.0318x over previous
//
#include <hip/hip_runtime.h>
#include <math.h>

// ---------------------------------------------------------------------------
// VQ-VAE forward on MI355X — round 10: revert g1 split-K (structure-bound at
// ~760 TF, m97 2-barrier ceiling); z_q emitted as pre-swizzled bf16 plane by
// vq_mfma/fix_argmin so g3 is plane-fed (no f32 re-reads, no staging VALU).
//   g1: h1 = relu(x @ W1^T + b1)        [x,W1 hi/lo planes -> h1 hi/lo planes]
//   g2: z_e = h1 @ W2^T + b2            [planes -> f32 z_e output]
//   vq_mfma: MFMA dots + top-2 argmin + gap flag; writes z_q f32 + bf16 plane
//   fixup: F1 Part[c] = gatherX @ W1^T (6-way split-K, f64 64^2 tiles)
//          F2 Zf = relu(sum Part + b1) @ W2^T + b2  (fused reduce in staging)
//          F3 exact distances + argmin + z_q scatter (f32 + plane patch)
//   g3: h3 = relu(z_q @ W3^T + b3)      [z_q plane -> h3 hi plane]
//   g4: recon = sigmoid(h3 @ W4^T + b4) [planes -> f32 recon]
// Recon-section lifetime: [x planes during prep/g1] -> dead -> [Part @+0,
// Zf @+96MB, zqh @+144MB] -> g4 writes final recon.
// ---------------------------------------------------------------------------

typedef short bf16x8 __attribute__((ext_vector_type(8)));
typedef short short8 __attribute__((ext_vector_type(8)));
typedef float f32x4  __attribute__((ext_vector_type(4)));

#define GAP_T   2e-4
#define FIX_CAP 4096

__device__ __forceinline__ unsigned short f32_to_bf16_rn(float v) {
    union { float f; unsigned u; } c; c.f = v;
    unsigned r = c.u + 0x7FFFu + ((c.u >> 16) & 1u);
    return (unsigned short)(r >> 16);
}
__device__ __forceinline__ float bf16_bits_to_f32(unsigned short b) {
    union { unsigned u; float f; } c; c.u = ((unsigned)b) << 16;
    return c.f;
}
__device__ __forceinline__ void glds16(const short* g, short* l) {
    __builtin_amdgcn_global_load_lds(
        (const __attribute__((address_space(1))) unsigned int*)g,
        (__attribute__((address_space(3))) unsigned int*)l, 16, 0, 0);
}
// z_q plane offset for global row id, column ii (K=1024, 32 k-tiles/m-tile)
__device__ __forceinline__ size_t zq_plane_off(int id, int ii) {
    const int mb = id >> 7, r = id & 127;
    const int kt = ii >> 5, kc = ii & 31;
    return ((size_t)(mb * 32 + kt) * 4096)
         + r * 32 + (((kc >> 3) ^ (r & 3)) << 3) + (kc & 7);
}

// ================= plane prep: all four weight matrices, one launch =========
__global__ __launch_bounds__(256) void prep_wall(
    const float* __restrict__ W1, const float* __restrict__ W2,
    const float* __restrict__ W3, const float* __restrict__ W4,
    short* __restrict__ w1h, short* __restrict__ w1l,
    short* __restrict__ w2h, short* __restrict__ w2l,
    short* __restrict__ w3h, short* __restrict__ w4h)
{
    const int bid = blockIdx.x;
    const float* Wsrc; int N, K, KT, local; short *hi, *lo;
    if (bid < 384)      { Wsrc = W1; N = 400;  K = 3072; KT = 96; local = bid;       hi = w1h; lo = w1l; }
    else if (bid < 488) { Wsrc = W2; N = 1024; K = 400;  KT = 13; local = bid - 384; hi = w2h; lo = w2l; }
    else if (bid < 616) { Wsrc = W3; N = 400;  K = 1024; KT = 32; local = bid - 488; hi = w3h; lo = nullptr; }
    else                { Wsrc = W4; N = 3072; K = 400;  KT = 13; local = bid - 616; hi = w4h; lo = nullptr; }

    const int kt = local % KT;
    const int nb = local / KT;
    const size_t tb = (size_t)local * 4096;
    for (int ci = threadIdx.x; ci < 512; ci += 256) {
        const int row = ci >> 2;
        const int sl  = ci & 3;
        const int k0  = ((sl ^ (row & 3)) << 3);
        const int n   = nb * 128 + row;
        const int kk  = kt * 32 + k0;
        float f[8];
        #pragma unroll
        for (int e = 0; e < 8; ++e)
            f[e] = (n < N && kk + e < K) ? Wsrc[(size_t)n * K + kk + e] : 0.f;
        short8 h, l;
        #pragma unroll
        for (int e = 0; e < 8; ++e) {
            const unsigned short hb = f32_to_bf16_rn(f[e]);
            h[e] = (short)hb;
            l[e] = (short)f32_to_bf16_rn(f[e] - bf16_bits_to_f32(hb));
        }
        *reinterpret_cast<short8*>(&hi[tb + ci * 8]) = h;
        if (lo) *reinterpret_cast<short8*>(&lo[tb + ci * 8]) = l;
    }
}

// ========================= plane prep: x (A operand) ========================
__global__ __launch_bounds__(256) void prep_xplanes(
    const float* __restrict__ x, short* __restrict__ hi, short* __restrict__ lo)
{
    const int kt = blockIdx.x % 96;
    const int mb = blockIdx.x / 96;
    const size_t tb = (size_t)blockIdx.x * 4096;
    for (int ci = threadIdx.x; ci < 512; ci += 256) {
        const int row = ci >> 2;
        const int sl  = ci & 3;
        const int k0  = ((sl ^ (row & 3)) << 3);
        const float* src = &x[(size_t)(mb * 128 + row) * 3072 + kt * 32 + k0];
        const float4 f0 = *reinterpret_cast<const float4*>(src);
        const float4 f1 = *reinterpret_cast<const float4*>(src + 4);
        const float ff[8] = {f0.x, f0.y, f0.z, f0.w, f1.x, f1.y, f1.z, f1.w};
        short8 h, l;
        #pragma unroll
        for (int e = 0; e < 8; ++e) {
            const unsigned short hb = f32_to_bf16_rn(ff[e]);
            h[e] = (short)hb;
            l[e] = (short)f32_to_bf16_rn(ff[e] - bf16_bits_to_f32(hb));
        }
        *reinterpret_cast<short8*>(&hi[tb + ci * 8]) = h;
        *reinterpret_cast<short8*>(&lo[tb + ci * 8]) = l;
    }
}

// ====================== plane-fed MFMA GEMM (NT) ===========================
// OUTMODE: 0 f32 C; 1 hi plane; 2 hi+lo planes
template<int NSPLIT, int ACT, int OUTMODE>
__global__ __launch_bounds__(256) void gemm_pl(
    const short* __restrict__ Ahi, const short* __restrict__ Alo,
    const short* __restrict__ Bhi, const short* __restrict__ Blo,
    const float* __restrict__ bias,
    float* __restrict__ Cf32, short* __restrict__ Cphi, short* __restrict__ Cplo,
    int N, int KT, int KTout)
{
    __shared__ short lds[NSPLIT * 2 * 4096];

    const int tid  = threadIdx.x;
    const int lane = tid & 63;
    const int w_id = tid >> 6;
    const int wr   = (w_id >> 1) * 64;
    const int wc   = (w_id & 1)  * 64;
    const int m0   = blockIdx.y * 128;
    const int n0   = blockIdx.x * 128;
    const int l15  = lane & 15;
    const int lg   = lane >> 4;

    f32x4 acc[4][4];
    #pragma unroll
    for (int i = 0; i < 4; ++i)
        #pragma unroll
        for (int j = 0; j < 4; ++j) acc[i][j] = (f32x4){0.f, 0.f, 0.f, 0.f};

    for (int kt = 0; kt < KT; ++kt) {
        {
            const size_t at = ((size_t)blockIdx.y * KT + kt) * 4096;
            #pragma unroll
            for (int q = 0; q < 2; ++q) {
                const int o = (w_id * 2 + q) * 512 + lane * 8;
                glds16(Ahi + at + o, &lds[o]);
                if (NSPLIT > 1) glds16(Alo + at + o, &lds[4096 + o]);
            }
        }
        {
            const size_t bt = ((size_t)blockIdx.x * KT + kt) * 4096;
            #pragma unroll
            for (int q = 0; q < 2; ++q) {
                const int o = (w_id * 2 + q) * 512 + lane * 8;
                glds16(Bhi + bt + o, &lds[NSPLIT * 4096 + o]);
                if (NSPLIT > 1) glds16(Blo + bt + o, &lds[(NSPLIT + 1) * 4096 + o]);
            }
        }
        __syncthreads();

        bf16x8 bfr[4][NSPLIT];
        #pragma unroll
        for (int fc = 0; fc < 4; ++fc) {
            const int rn  = wc + fc * 16 + l15;
            const int idx = rn * 32 + ((lg ^ (rn & 3)) << 3);
            #pragma unroll
            for (int s = 0; s < NSPLIT; ++s)
                bfr[fc][s] = *reinterpret_cast<const bf16x8*>(&lds[(NSPLIT + s) * 4096 + idx]);
        }
        #pragma unroll
        for (int fr = 0; fr < 4; ++fr) {
            const int rm  = wr + fr * 16 + l15;
            const int idx = rm * 32 + ((lg ^ (rm & 3)) << 3);
            const bf16x8 a0 = *reinterpret_cast<const bf16x8*>(&lds[idx]);
            bf16x8 a1;
            if (NSPLIT > 1)
                a1 = *reinterpret_cast<const bf16x8*>(&lds[4096 + idx]);
            #pragma unroll
            for (int fc = 0; fc < 4; ++fc) {
                acc[fr][fc] = __builtin_amdgcn_mfma_f32_16x16x32_bf16(
                    a0, bfr[fc][0], acc[fr][fc], 0, 0, 0);
                if (NSPLIT > 1) {
                    acc[fr][fc] = __builtin_amdgcn_mfma_f32_16x16x32_bf16(
                        a0, bfr[fc][1], acc[fr][fc], 0, 0, 0);
                    acc[fr][fc] = __builtin_amdgcn_mfma_f32_16x16x32_bf16(
                        a1, bfr[fc][0], acc[fr][fc], 0, 0, 0);
                }
            }
        }
        __syncthreads();
    }

    float bv[4];
    #pragma unroll
    for (int fc = 0; fc < 4; ++fc) {
        const int col = n0 + wc + fc * 16 + l15;
        bv[fc] = (col < N) ? bias[col] : 0.f;
    }
    #pragma unroll
    for (int fr = 0; fr < 4; ++fr) {
        #pragma unroll
        for (int fc = 0; fc < 4; ++fc) {
            const int col = n0 + wc + fc * 16 + l15;
            #pragma unroll
            for (int j = 0; j < 4; ++j) {
                const int rowg = m0 + wr + fr * 16 + lg * 4 + j;
                float v = acc[fr][fc][j] + bv[fc];
                if (ACT == 1) v = fmaxf(v, 0.f);
                else if (ACT == 2) v = 1.f / (1.f + expf(-v));
                if (OUTMODE == 0) {
                    if (col < N) Cf32[(size_t)rowg * N + col] = v;
                } else {
                    const int kto = col >> 5;
                    if (kto < KTout) {
                        const int r = rowg & 127, k = col & 31;
                        const size_t off = ((size_t)blockIdx.y * KTout + kto) * 4096
                                         + r * 32 + (((k >> 3) ^ (r & 3)) << 3) + (k & 7);
                        const unsigned short hb = f32_to_bf16_rn(v);
                        Cphi[off] = (short)hb;
                        if (OUTMODE == 2)
                            Cplo[off] = (short)f32_to_bf16_rn(v - bf16_bits_to_f32(hb));
                    }
                }
            }
        }
    }
}

// ============================ VQ prep (one block) ===========================
__global__ void vq_prep(const float* __restrict__ Wemb, short* __restrict__ planes,
                        double* __restrict__ wn, int* __restrict__ flag_cnt)
{
    const int tid = threadIdx.x;
    if (tid == 0) *flag_cnt = 0;
    if (tid < 128) {
        double s = 0.0;
        for (int k = 0; k < 128; ++k) {
            const double w = (double)Wemb[k * 128 + tid];
            s = fma(w, w, s);
        }
        wn[tid] = s;
    }
    for (int t = tid; t < 16384; t += 256) {
        const int k = t >> 7, n = t & 127;
        const float w = Wemb[t];
        const unsigned short hi = f32_to_bf16_rn(w);
        const unsigned short lo = f32_to_bf16_rn(w - bf16_bits_to_f32(hi));
        const int off = n * 128 + (((k >> 3) ^ (n & 7)) << 3) + (k & 7);
        planes[off]         = (short)hi;
        planes[16384 + off] = (short)lo;
    }
}

// ============================ VQ MFMA + argmin ==============================
// Writes z_q f32 into emb_o AND bf16_rn(z_q) into the tiled z_q plane (g3's
// A operand). Plane value == bf16_rn of the same f32 g3 used to convert.
__global__ __launch_bounds__(512) void vq_mfma(
    const float* __restrict__ z_e, const short* __restrict__ planes,
    const double* __restrict__ wn_g, float* __restrict__ zq,
    short* __restrict__ zqh,
    int* __restrict__ flag_cnt, int* __restrict__ flag_ids)
{
    __shared__ short  Wsh[32768];
    __shared__ float  zsh[16 * 1024];
    __shared__ double wn_sh[128];
    __shared__ double cmb_v1[128][2];
    __shared__ double cmb_v2[128][2];
    __shared__ int    cmb_i[128][2];
    __shared__ int    idx_sh[128];
    __shared__ int    sflag[16];

    const int tid = threadIdx.x;
    const int b0  = blockIdx.x * 16;

    for (int c = tid; c < 4096; c += 512)
        *reinterpret_cast<int4*>(&Wsh[c * 8]) =
            *reinterpret_cast<const int4*>(&planes[c * 8]);
    for (int c = tid; c < 128; c += 512) wn_sh[c] = wn_g[c];
    for (int c = tid; c < 4096; c += 512) {
        const int D    = c * 16;
        const int s    = D >> 12;
        const int dr   = D & 4095;
        const int srcb = dr ^ (((dr >> 8) & 3) << 5);
        *reinterpret_cast<int4*>(reinterpret_cast<char*>(zsh) + D) =
            *reinterpret_cast<const int4*>(
                reinterpret_cast<const char*>(z_e) + (size_t)(b0 + s) * 4096 + srcb);
    }
    if (tid < 16) sflag[tid] = 0;
    __syncthreads();

    const int lane = tid & 63;
    const int w_id = tid >> 6;
    const int wr   = (w_id >> 1) * 32;
    const int wc   = (w_id & 1) * 64;
    const int l15  = lane & 15;
    const int lg   = lane >> 4;

    f32x4 acc[2][4];
    #pragma unroll
    for (int i = 0; i < 2; ++i)
        #pragma unroll
        for (int j = 0; j < 4; ++j) acc[i][j] = (f32x4){0.f, 0.f, 0.f, 0.f};

    #pragma unroll
    for (int ks = 0; ks < 4; ++ks) {
        bf16x8 bh[4], bl[4];
        #pragma unroll
        for (int cf = 0; cf < 4; ++cf) {
            const int n     = wc + cf * 16 + l15;
            const int slotp = (ks * 4 + lg) ^ (n & 7);
            const int off   = n * 128 + slotp * 8;
            bh[cf] = *reinterpret_cast<const bf16x8*>(&Wsh[off]);
            bl[cf] = *reinterpret_cast<const bf16x8*>(&Wsh[16384 + off]);
        }
        bf16x8 ah[2], al[2];
        #pragma unroll
        for (int rf = 0; rf < 2; ++rf) {
            const int row   = wr + rf * 16 + l15;
            const int s_loc = row >> 3;
            const int d     = row & 7;
            const int kb    = ks * 32 + lg * 8;
            const int xr    = (lg & 3) << 5;
            const char* zb  = reinterpret_cast<const char*>(zsh) + s_loc * 4096;
            bf16x8 h8, L8;
            #pragma unroll
            for (int j = 0; j < 8; ++j) {
                const float a = *reinterpret_cast<const float*>(
                    zb + ((32 * (kb + j) + 4 * d) ^ xr));
                const unsigned short hi = f32_to_bf16_rn(a);
                h8[j] = (short)hi;
                L8[j] = (short)f32_to_bf16_rn(a - bf16_bits_to_f32(hi));
            }
            ah[rf] = h8; al[rf] = L8;
        }
        #pragma unroll
        for (int rf = 0; rf < 2; ++rf)
            #pragma unroll
            for (int cf = 0; cf < 4; ++cf) {
                acc[rf][cf] = __builtin_amdgcn_mfma_f32_16x16x32_bf16(
                    ah[rf], bh[cf], acc[rf][cf], 0, 0, 0);
                acc[rf][cf] = __builtin_amdgcn_mfma_f32_16x16x32_bf16(
                    ah[rf], bl[cf], acc[rf][cf], 0, 0, 0);
                acc[rf][cf] = __builtin_amdgcn_mfma_f32_16x16x32_bf16(
                    al[rf], bh[cf], acc[rf][cf], 0, 0, 0);
            }
    }

    #pragma unroll
    for (int rf = 0; rf < 2; ++rf)
        #pragma unroll
        for (int j = 0; j < 4; ++j) {
            double v1 = 1e300, v2 = 1e300; int i1 = 0;
            #pragma unroll
            for (int cf = 0; cf < 4; ++cf) {
                const int n = wc + cf * 16 + l15;
                const double v = wn_sh[n] - 2.0 * (double)acc[rf][cf][j];
                if (v < v1)      { v2 = v1; v1 = v; i1 = n; }
                else if (v < v2) { v2 = v; }
            }
            #pragma unroll
            for (int off = 1; off < 16; off <<= 1) {
                const double ov1 = __shfl_xor(v1, off);
                const int    oi1 = __shfl_xor(i1, off);
                const double ov2 = __shfl_xor(v2, off);
                if (ov1 < v1 || (ov1 == v1 && oi1 < i1)) {
                    v2 = fmin(v1, ov2); v1 = ov1; i1 = oi1;
                } else {
                    v2 = fmin(v2, ov1);
                }
            }
            if (l15 == 0) {
                const int r = wr + rf * 16 + lg * 4 + j;
                cmb_v1[r][w_id & 1] = v1;
                cmb_v2[r][w_id & 1] = v2;
                cmb_i [r][w_id & 1] = i1;
            }
        }
    __syncthreads();

    if (tid < 128) {
        const double v1a = cmb_v1[tid][0], v1b = cmb_v1[tid][1];
        double v1, v2; int i1;
        if (v1b < v1a) { v1 = v1b; i1 = cmb_i[tid][1]; v2 = fmin(v1a, cmb_v2[tid][1]); }
        else           { v1 = v1a; i1 = cmb_i[tid][0]; v2 = fmin(v1b, cmb_v2[tid][0]); }
        idx_sh[tid] = i1;
        if (v2 - v1 < GAP_T) sflag[tid >> 3] = 1;
    }
    __syncthreads();
    if (tid < 16 && sflag[tid]) {
        const int p = atomicAdd(flag_cnt, 1);
        flag_ids[p] = b0 + tid;
    }

    for (int t = tid; t < 16384; t += 512) {
        const int s = t >> 10, i = t & 1023;
        const int k = i >> 3, d = i & 7;
        const int n = idx_sh[(s << 3) | d];
        const int off = n * 128 + (((k >> 3) ^ (n & 7)) << 3) + (k & 7);
        const float val = bf16_bits_to_f32((unsigned short)Wsh[off]) +
                          bf16_bits_to_f32((unsigned short)Wsh[16384 + off]);
        zq[(size_t)(b0 + s) * 1024 + i] = val;
        zqh[zq_plane_off(b0 + s, i)] = (short)f32_to_bf16_rn(val);
    }
}

// ================= fixup F1/F2: 64x64-tile f64 GEMM (NT) ===================
#define FLP 68
template<bool GATHER, bool SPLITK, bool FUSERED, typename TA>
__global__ __launch_bounds__(256) void gemm_f64t(
    const TA* __restrict__ A, const float* __restrict__ Wf,
    const int* __restrict__ ids, const int* __restrict__ cntp,
    const float* __restrict__ biasA, const float* __restrict__ bias,
    double* __restrict__ C,
    int AK, int N, int CN, int klen, int cap)
{
    __shared__ double As[16 * FLP];
    __shared__ double Ws[16 * FLP];

    const int tid = threadIdx.x;
    const int tx  = tid & 15;
    const int ty  = tid >> 4;
    const int m0  = blockIdx.y * 64;
    const int n0  = blockIdx.x * 64;
    const int cnt = (*cntp < cap) ? *cntp : cap;
    if (m0 >= cnt) return;

    const int k0 = SPLITK ? blockIdx.z * klen : 0;
    if (SPLITK) C += (size_t)blockIdx.z * cap * CN;

    const int srow = tid >> 2;
    const int sc4  = (tid & 3) << 2;

    const TA* arow;
    if (GATHER) {
        const int m  = m0 + srow;
        const int id = (m < cnt) ? ids[m] : 0;
        arow = A + (size_t)id * AK;
    } else {
        arow = A + (size_t)(m0 + srow) * AK;
    }
    const int   nrow = n0 + srow;
    const float* wrow = Wf + (size_t)(nrow < N ? nrow : 0) * AK;
    const bool  wok  = (nrow < N);

    double acc[4][4];
    #pragma unroll
    for (int i = 0; i < 4; ++i)
        #pragma unroll
        for (int j = 0; j < 4; ++j) acc[i][j] = 0.0;

    for (int kt = 0; kt < klen; kt += 16) {
        const int kb = k0 + kt + sc4;
        if constexpr (FUSERED) {
            const size_t cs = (size_t)cap * AK;
            #pragma unroll
            for (int e = 0; e < 4; ++e) {
                double s = (double)biasA[kb + e];
                #pragma unroll
                for (int c = 0; c < 6; ++c) s += arow[c * cs + kb + e];
                As[(sc4 + e) * FLP + srow] = s > 0.0 ? s : 0.0;
            }
        } else if constexpr (sizeof(TA) == 4) {
            const float4 v = *reinterpret_cast<const float4*>(&arow[kb]);
            As[(sc4 + 0) * FLP + srow] = (double)v.x;
            As[(sc4 + 1) * FLP + srow] = (double)v.y;
            As[(sc4 + 2) * FLP + srow] = (double)v.z;
            As[(sc4 + 3) * FLP + srow] = (double)v.w;
        } else {
            const double2 v0 = *reinterpret_cast<const double2*>(&arow[kb]);
            const double2 v1 = *reinterpret_cast<const double2*>(&arow[kb + 2]);
            As[(sc4 + 0) * FLP + srow] = v0.x;
            As[(sc4 + 1) * FLP + srow] = v0.y;
            As[(sc4 + 2) * FLP + srow] = v1.x;
            As[(sc4 + 3) * FLP + srow] = v1.y;
        }
        float4 w = make_float4(0.f, 0.f, 0.f, 0.f);
        if (wok) w = *reinterpret_cast<const float4*>(&wrow[kb]);
        Ws[(sc4 + 0) * FLP + srow] = (double)w.x;
        Ws[(sc4 + 1) * FLP + srow] = (double)w.y;
        Ws[(sc4 + 2) * FLP + srow] = (double)w.z;
        Ws[(sc4 + 3) * FLP + srow] = (double)w.w;
        __syncthreads();

        #pragma unroll
        for (int k = 0; k < 16; ++k) {
            const double2 A0 = *reinterpret_cast<const double2*>(&As[k * FLP + ty * 4]);
            const double2 A1 = *reinterpret_cast<const double2*>(&As[k * FLP + ty * 4 + 2]);
            const double2 B0 = *reinterpret_cast<const double2*>(&Ws[k * FLP + tx * 4]);
            const double2 B1 = *reinterpret_cast<const double2*>(&Ws[k * FLP + tx * 4 + 2]);
            const double a[4] = {A0.x, A0.y, A1.x, A1.y};
            const double b[4] = {B0.x, B0.y, B1.x, B1.y};
            #pragma unroll
            for (int i = 0; i < 4; ++i)
                #pragma unroll
                for (int j = 0; j < 4; ++j)
                    acc[i][j] = fma(a[i], b[j], acc[i][j]);
        }
        __syncthreads();
    }

    #pragma unroll
    for (int i = 0; i < 4; ++i) {
        const int row = m0 + ty * 4 + i;
        #pragma unroll
        for (int j = 0; j < 4; ++j) {
            const int col = n0 + tx * 4 + j;
            if (col < N)
                C[(size_t)row * CN + col] =
                    acc[i][j] + (bias ? (double)bias[col] : 0.0);
        }
    }
}

// ======= fixup F3: exact f64 distances + argmin + z_q scatter ===============
__global__ __launch_bounds__(512) void fix_argmin(
    const double* __restrict__ Zf, const float* __restrict__ Wemb,
    const int* __restrict__ cntp, const int* __restrict__ ids,
    float* __restrict__ zq, short* __restrict__ zqh, int cap)
{
    __shared__ float  wesh[16384];
    __shared__ double zsh[4][1032];
    __shared__ double dist[4 * 8 * 128];
    __shared__ int    idxf[32];

    const int tid  = threadIdx.x;
    const int lane = tid & 63;
    const int wv   = tid >> 6;
    const int cnt  = (*cntp < cap) ? *cntp : cap;
    const int base = blockIdx.x * 4;
    if (base >= cnt) return;
    const int ns = (cnt - base < 4) ? (cnt - base) : 4;

    for (int i = tid; i < 4096; i += 512)
        reinterpret_cast<float4*>(wesh)[i] =
            reinterpret_cast<const float4*>(Wemb)[i];
    for (int i = tid; i < 4 * 512; i += 512) {
        const int s = i >> 9, e = (i & 511) * 2;
        if (s < ns) {
            const double2 v = *reinterpret_cast<const double2*>(
                &Zf[(size_t)(base + s) * 1024 + e]);
            zsh[s][e] = v.x;
            zsh[s][e + 1] = v.y;
        }
    }
    __syncthreads();

    for (int t = tid; t < ns * 1024; t += 512) {
        const int s = t >> 10, d = (t >> 7) & 7, n = t & 127;
        double acc = 0.0;
        for (int k = 0; k < 128; ++k) {
            const double diff = zsh[s][k * 8 + d] - (double)wesh[k * 128 + n];
            acc = fma(diff, diff, acc);
        }
        dist[(s * 8 + d) * 128 + n] = acc;
    }
    __syncthreads();

    for (int p = wv; p < ns * 8; p += 8) {
        const double* dp = &dist[p * 128];
        double v0 = dp[lane], vx = dp[lane + 64];
        double v; int ix;
        if (vx < v0) { v = vx; ix = lane + 64; }
        else         { v = v0; ix = lane; }
        #pragma unroll
        for (int off = 32; off > 0; off >>= 1) {
            const double ov = __shfl_down(v, off);
            const int    oi = __shfl_down(ix, off);
            if (ov < v || (ov == v && oi < ix)) { v = ov; ix = oi; }
        }
        if (lane == 0) idxf[p] = ix;
    }
    __syncthreads();

    for (int i = tid; i < ns * 1024; i += 512) {
        const int s = i >> 10, ii = i & 1023;
        const int id = ids[base + s];
        const float val = wesh[(ii >> 3) * 128 + idxf[s * 8 + (ii & 7)]];
        zq[(size_t)id * 1024 + ii] = val;
        zqh[zq_plane_off(id, ii)] = (short)f32_to_bf16_rn(val);
    }
}

// ---------------------------------------------------------------------------
extern "C" void kernel_launch(void* const* d_in, const int* in_sizes, int n_in,
                              void* d_out, int out_size, void* d_ws, size_t ws_size,
                              hipStream_t stream)
{
    const float* x    = (const float*)d_in[0];
    const float* W1   = (const float*)d_in[1];
    const float* b1   = (const float*)d_in[2];
    const float* W2   = (const float*)d_in[3];
    const float* b2   = (const float*)d_in[4];
    const float* W3   = (const float*)d_in[5];
    const float* b3   = (const float*)d_in[6];
    const float* W4   = (const float*)d_in[7];
    const float* b4   = (const float*)d_in[8];
    const float* Wemb = (const float*)d_in[9];

    const int B = 16384;
    float* out   = (float*)d_out;
    float* recon = out;                                // B*3072
    float* z_e   = out + (size_t)B * 3072;             // B*1024
    float* emb_o = z_e + (size_t)B * 1024;             // B*1024 == z_q

    constexpr size_t X_PL  = 50331648;
    constexpr size_t H1_PL = 6815744;
    constexpr size_t H3_PL = 6815744;
    constexpr size_t W1_PL = 1572864;
    constexpr size_t W2_PL = 425984;
    constexpr size_t W3_PL = 524288;
    constexpr size_t W4_PL = 1277952;

    short* xh  = (short*)recon;          // x planes in recon section
    short* xl  = xh + X_PL;
    short* h1h = (short*)emb_o;          // h1 planes in emb_o section
    short* h1l = h1h + H1_PL;

    short*  h3h      = (short*)d_ws;
    short*  w1h      = h3h + H3_PL;
    short*  w1l      = w1h + W1_PL;
    short*  w2h      = w1l + W1_PL;
    short*  w2l      = w2h + W2_PL;
    short*  w3h      = w2l + W2_PL;
    short*  w4h      = w3h + W3_PL;
    short*  wembpl   = w4h + W4_PL;
    double* wn       = (double*)(wembpl + 32768);
    int*    flag_cnt = (int*)(wn + 128);
    int*    flag_ids = flag_cnt + 64;

    // recon-section scratch (x-planes dead after g1; g4 writes recon last):
    // Part[6] @ +0 (78.6MB), Zf @ +96MB (33.5MB), zqh plane @ +144MB (33.5MB)
    char*   scr  = (char*)recon;
    double* Part = (double*)scr;
    double* Zf   = (double*)(scr + (96ull  << 20));
    short*  zqh  = (short*) (scr + (144ull << 20));

    // ---- prep ----
    prep_wall<<<dim3(928), dim3(256), 0, stream>>>(
        W1, W2, W3, W4, w1h, w1l, w2h, w2l, w3h, w4h);
    prep_xplanes<<<dim3(12288), dim3(256), 0, stream>>>(x, xh, xl);
    vq_prep<<<dim3(1), dim3(256), 0, stream>>>(Wemb, wembpl, wn, flag_cnt);

    // ---- encoder ----
    gemm_pl<2, 1, 2><<<dim3(4, 128), dim3(256), 0, stream>>>(
        xh, xl, w1h, w1l, b1, nullptr, h1h, h1l, 400, 96, 13);
    gemm_pl<2, 0, 0><<<dim3(8, 128), dim3(256), 0, stream>>>(
        h1h, h1l, w2h, w2l, b2, z_e, nullptr, nullptr, 1024, 13, 0);

    // ---- VQ + fixup ----
    vq_mfma<<<dim3(1024), dim3(512), 0, stream>>>(z_e, wembpl, wn, emb_o, zqh,
                                                  flag_cnt, flag_ids);
    gemm_f64t<true, true, false, float><<<dim3(7, FIX_CAP / 64, 6), dim3(256), 0, stream>>>(
        x, W1, flag_ids, flag_cnt, nullptr, nullptr, Part, 3072, 400, 400, 512, FIX_CAP);
    gemm_f64t<false, false, true, double><<<dim3(16, FIX_CAP / 64), dim3(256), 0, stream>>>(
        Part, W2, nullptr, flag_cnt, b1, b2, Zf, 400, 1024, 1024, 400, FIX_CAP);
    fix_argmin<<<dim3(FIX_CAP / 4), dim3(512), 0, stream>>>(
        Zf, Wemb, flag_cnt, flag_ids, emb_o, zqh, FIX_CAP);

    // ---- decoder ----
    gemm_pl<1, 1, 1><<<dim3(4, 128), dim3(256), 0, stream>>>(
        zqh, nullptr, w3h, nullptr, b3, nullptr, h3h, nullptr, 400, 32, 13);
    gemm_pl<1, 2, 0><<<dim3(24, 128), dim3(256), 0, stream>>>(
        h3h, nullptr, w4h, nullptr, b4, recon, nullptr, nullptr, 3072, 13, 0);
}

// Round 11
// 679.405 us; speedup vs baseline: 1.1625x; 1.1266x over previous
//
#include <hip/hip_runtime.h>
#include <math.h>

// ---------------------------------------------------------------------------
// VQ-VAE forward on MI355X — round 11: gemm_pl gets minimum-2-phase double-
// buffered staging (issue next K-tile's global_load_lds BEFORE computing the
// current tile; ONE barrier per K-step) — T3-lite from the technique catalog.
// Numerics bit-identical to round 10. Preps merged into one launch.
//   g1: h1 = relu(x @ W1^T + b1)        [x,W1 hi/lo planes -> h1 hi/lo planes]
//   g2: z_e = h1 @ W2^T + b2            [planes -> f32 z_e output]
//   vq_mfma: MFMA dots + top-2 argmin + gap flag; writes z_q f32 + bf16 plane
//   fixup: F1 Part[c] = gatherX @ W1^T (6-way split-K, f64 64^2 tiles)
//          F2 Zf = relu(sum Part + b1) @ W2^T + b2  (fused reduce in staging)
//          F3 exact distances + argmin + z_q scatter (f32 + plane patch)
//   g3: h3 = relu(z_q @ W3^T + b3)      [z_q plane -> h3 hi plane]
//   g4: recon = sigmoid(h3 @ W4^T + b4) [planes -> f32 recon]
// ---------------------------------------------------------------------------

typedef short bf16x8 __attribute__((ext_vector_type(8)));
typedef short short8 __attribute__((ext_vector_type(8)));
typedef float f32x4  __attribute__((ext_vector_type(4)));

#define GAP_T   2e-4
#define FIX_CAP 4096

__device__ __forceinline__ unsigned short f32_to_bf16_rn(float v) {
    union { float f; unsigned u; } c; c.f = v;
    unsigned r = c.u + 0x7FFFu + ((c.u >> 16) & 1u);
    return (unsigned short)(r >> 16);
}
__device__ __forceinline__ float bf16_bits_to_f32(unsigned short b) {
    union { unsigned u; float f; } c; c.u = ((unsigned)b) << 16;
    return c.f;
}
__device__ __forceinline__ void glds16(const short* g, short* l) {
    __builtin_amdgcn_global_load_lds(
        (const __attribute__((address_space(1))) unsigned int*)g,
        (__attribute__((address_space(3))) unsigned int*)l, 16, 0, 0);
}
__device__ __forceinline__ size_t zq_plane_off(int id, int ii) {
    const int mb = id >> 7, r = id & 127;
    const int kt = ii >> 5, kc = ii & 31;
    return ((size_t)(mb * 32 + kt) * 4096)
         + r * 32 + (((kc >> 3) ^ (r & 3)) << 3) + (kc & 7);
}

// ================== merged prep: x planes + W planes + VQ prep ==============
__global__ __launch_bounds__(256) void prep_all(
    const float* __restrict__ x,
    const float* __restrict__ W1, const float* __restrict__ W2,
    const float* __restrict__ W3, const float* __restrict__ W4,
    const float* __restrict__ Wemb,
    short* __restrict__ xh,  short* __restrict__ xl,
    short* __restrict__ w1h, short* __restrict__ w1l,
    short* __restrict__ w2h, short* __restrict__ w2l,
    short* __restrict__ w3h, short* __restrict__ w4h,
    short* __restrict__ wembpl, double* __restrict__ wn,
    int* __restrict__ flag_cnt)
{
    const int tid = threadIdx.x;
    int bid = blockIdx.x;

    if (bid < 12288) {   // -------- x planes --------
        const int kt = bid % 96;
        const int mb = bid / 96;
        const size_t tb = (size_t)bid * 4096;
        for (int ci = tid; ci < 512; ci += 256) {
            const int row = ci >> 2;
            const int sl  = ci & 3;
            const int k0  = ((sl ^ (row & 3)) << 3);
            const float* src = &x[(size_t)(mb * 128 + row) * 3072 + kt * 32 + k0];
            const float4 f0 = *reinterpret_cast<const float4*>(src);
            const float4 f1 = *reinterpret_cast<const float4*>(src + 4);
            const float ff[8] = {f0.x, f0.y, f0.z, f0.w, f1.x, f1.y, f1.z, f1.w};
            short8 h, l;
            #pragma unroll
            for (int e = 0; e < 8; ++e) {
                const unsigned short hb = f32_to_bf16_rn(ff[e]);
                h[e] = (short)hb;
                l[e] = (short)f32_to_bf16_rn(ff[e] - bf16_bits_to_f32(hb));
            }
            *reinterpret_cast<short8*>(&xh[tb + ci * 8]) = h;
            *reinterpret_cast<short8*>(&xl[tb + ci * 8]) = l;
        }
        return;
    }
    bid -= 12288;

    if (bid < 928) {     // -------- weight planes --------
        const float* Wsrc; int N, K, KT, local; short *hi, *lo;
        if (bid < 384)      { Wsrc = W1; N = 400;  K = 3072; KT = 96; local = bid;       hi = w1h; lo = w1l; }
        else if (bid < 488) { Wsrc = W2; N = 1024; K = 400;  KT = 13; local = bid - 384; hi = w2h; lo = w2l; }
        else if (bid < 616) { Wsrc = W3; N = 400;  K = 1024; KT = 32; local = bid - 488; hi = w3h; lo = nullptr; }
        else                { Wsrc = W4; N = 3072; K = 400;  KT = 13; local = bid - 616; hi = w4h; lo = nullptr; }

        const int kt = local % KT;
        const int nb = local / KT;
        const size_t tb = (size_t)local * 4096;
        for (int ci = tid; ci < 512; ci += 256) {
            const int row = ci >> 2;
            const int sl  = ci & 3;
            const int k0  = ((sl ^ (row & 3)) << 3);
            const int n   = nb * 128 + row;
            const int kk  = kt * 32 + k0;
            float f[8];
            #pragma unroll
            for (int e = 0; e < 8; ++e)
                f[e] = (n < N && kk + e < K) ? Wsrc[(size_t)n * K + kk + e] : 0.f;
            short8 h, l;
            #pragma unroll
            for (int e = 0; e < 8; ++e) {
                const unsigned short hb = f32_to_bf16_rn(f[e]);
                h[e] = (short)hb;
                l[e] = (short)f32_to_bf16_rn(f[e] - bf16_bits_to_f32(hb));
            }
            *reinterpret_cast<short8*>(&hi[tb + ci * 8]) = h;
            if (lo) *reinterpret_cast<short8*>(&lo[tb + ci * 8]) = l;
        }
        return;
    }

    // -------- VQ prep (single block) --------
    if (tid == 0) *flag_cnt = 0;
    if (tid < 128) {
        double s = 0.0;
        for (int k = 0; k < 128; ++k) {
            const double w = (double)Wemb[k * 128 + tid];
            s = fma(w, w, s);
        }
        wn[tid] = s;
    }
    for (int t = tid; t < 16384; t += 256) {
        const int k = t >> 7, n = t & 127;
        const float w = Wemb[t];
        const unsigned short hi = f32_to_bf16_rn(w);
        const unsigned short lo = f32_to_bf16_rn(w - bf16_bits_to_f32(hi));
        const int off = n * 128 + (((k >> 3) ^ (n & 7)) << 3) + (k & 7);
        wembpl[off]         = (short)hi;
        wembpl[16384 + off] = (short)lo;
    }
}

// ====================== plane-fed MFMA GEMM (NT), 2-phase ===================
// OUTMODE: 0 f32 C; 1 hi plane; 2 hi+lo planes
template<int NSPLIT, int ACT, int OUTMODE>
__global__ __launch_bounds__(256) void gemm_pl(
    const short* __restrict__ Ahi, const short* __restrict__ Alo,
    const short* __restrict__ Bhi, const short* __restrict__ Blo,
    const float* __restrict__ bias,
    float* __restrict__ Cf32, short* __restrict__ Cphi, short* __restrict__ Cplo,
    int N, int KT, int KTout)
{
    // double-buffered: buffer = NSPLIT*2 tiles of 4096 shorts
    __shared__ short lds[2 * NSPLIT * 2 * 4096];

    const int tid  = threadIdx.x;
    const int lane = tid & 63;
    const int w_id = tid >> 6;
    const int wr   = (w_id >> 1) * 64;
    const int wc   = (w_id & 1)  * 64;
    const int m0   = blockIdx.y * 128;
    const int n0   = blockIdx.x * 128;
    const int l15  = lane & 15;
    const int lg   = lane >> 4;
    constexpr int BUF = NSPLIT * 2 * 4096;

    f32x4 acc[4][4];
    #pragma unroll
    for (int i = 0; i < 4; ++i)
        #pragma unroll
        for (int j = 0; j < 4; ++j) acc[i][j] = (f32x4){0.f, 0.f, 0.f, 0.f};

    // issue the async global->LDS DMAs for K-tile kt into buffer `buf`
    auto stage = [&](int buf, int kt) {
        short* L = &lds[buf * BUF];
        const size_t at = ((size_t)blockIdx.y * KT + kt) * 4096;
        const size_t bt = ((size_t)blockIdx.x * KT + kt) * 4096;
        #pragma unroll
        for (int q = 0; q < 2; ++q) {
            const int o = (w_id * 2 + q) * 512 + lane * 8;
            glds16(Ahi + at + o, &L[o]);
            if (NSPLIT > 1) glds16(Alo + at + o, &L[4096 + o]);
            glds16(Bhi + bt + o, &L[NSPLIT * 4096 + o]);
            if (NSPLIT > 1) glds16(Blo + bt + o, &L[(NSPLIT + 1) * 4096 + o]);
        }
    };

    stage(0, 0);
    __syncthreads();                 // drain tile-0 DMAs

    int cur = 0;
    for (int kt = 0; kt < KT; ++kt) {
        if (kt + 1 < KT) stage(cur ^ 1, kt + 1);   // prefetch: in flight during MFMA

        const short* L = &lds[cur * BUF];
        bf16x8 bfr[4][NSPLIT];
        #pragma unroll
        for (int fc = 0; fc < 4; ++fc) {
            const int rn  = wc + fc * 16 + l15;
            const int idx = rn * 32 + ((lg ^ (rn & 3)) << 3);
            #pragma unroll
            for (int s = 0; s < NSPLIT; ++s)
                bfr[fc][s] = *reinterpret_cast<const bf16x8*>(&L[(NSPLIT + s) * 4096 + idx]);
        }
        #pragma unroll
        for (int fr = 0; fr < 4; ++fr) {
            const int rm  = wr + fr * 16 + l15;
            const int idx = rm * 32 + ((lg ^ (rm & 3)) << 3);
            const bf16x8 a0 = *reinterpret_cast<const bf16x8*>(&L[idx]);
            bf16x8 a1;
            if (NSPLIT > 1)
                a1 = *reinterpret_cast<const bf16x8*>(&L[4096 + idx]);
            #pragma unroll
            for (int fc = 0; fc < 4; ++fc) {
                acc[fr][fc] = __builtin_amdgcn_mfma_f32_16x16x32_bf16(
                    a0, bfr[fc][0], acc[fr][fc], 0, 0, 0);
                if (NSPLIT > 1) {
                    acc[fr][fc] = __builtin_amdgcn_mfma_f32_16x16x32_bf16(
                        a0, bfr[fc][1], acc[fr][fc], 0, 0, 0);
                    acc[fr][fc] = __builtin_amdgcn_mfma_f32_16x16x32_bf16(
                        a1, bfr[fc][0], acc[fr][fc], 0, 0, 0);
                }
            }
        }
        __syncthreads();             // drains prefetch DMAs + guards buffer reuse
        cur ^= 1;
    }

    float bv[4];
    #pragma unroll
    for (int fc = 0; fc < 4; ++fc) {
        const int col = n0 + wc + fc * 16 + l15;
        bv[fc] = (col < N) ? bias[col] : 0.f;
    }
    #pragma unroll
    for (int fr = 0; fr < 4; ++fr) {
        #pragma unroll
        for (int fc = 0; fc < 4; ++fc) {
            const int col = n0 + wc + fc * 16 + l15;
            #pragma unroll
            for (int j = 0; j < 4; ++j) {
                const int rowg = m0 + wr + fr * 16 + lg * 4 + j;
                float v = acc[fr][fc][j] + bv[fc];
                if (ACT == 1) v = fmaxf(v, 0.f);
                else if (ACT == 2) v = 1.f / (1.f + expf(-v));
                if (OUTMODE == 0) {
                    if (col < N) Cf32[(size_t)rowg * N + col] = v;
                } else {
                    const int kto = col >> 5;
                    if (kto < KTout) {
                        const int r = rowg & 127, k = col & 31;
                        const size_t off = ((size_t)blockIdx.y * KTout + kto) * 4096
                                         + r * 32 + (((k >> 3) ^ (r & 3)) << 3) + (k & 7);
                        const unsigned short hb = f32_to_bf16_rn(v);
                        Cphi[off] = (short)hb;
                        if (OUTMODE == 2)
                            Cplo[off] = (short)f32_to_bf16_rn(v - bf16_bits_to_f32(hb));
                    }
                }
            }
        }
    }
}

// ============================ VQ MFMA + argmin ==============================
__global__ __launch_bounds__(512) void vq_mfma(
    const float* __restrict__ z_e, const short* __restrict__ planes,
    const double* __restrict__ wn_g, float* __restrict__ zq,
    short* __restrict__ zqh,
    int* __restrict__ flag_cnt, int* __restrict__ flag_ids)
{
    __shared__ short  Wsh[32768];
    __shared__ float  zsh[16 * 1024];
    __shared__ double wn_sh[128];
    __shared__ double cmb_v1[128][2];
    __shared__ double cmb_v2[128][2];
    __shared__ int    cmb_i[128][2];
    __shared__ int    idx_sh[128];
    __shared__ int    sflag[16];

    const int tid = threadIdx.x;
    const int b0  = blockIdx.x * 16;

    for (int c = tid; c < 4096; c += 512)
        *reinterpret_cast<int4*>(&Wsh[c * 8]) =
            *reinterpret_cast<const int4*>(&planes[c * 8]);
    for (int c = tid; c < 128; c += 512) wn_sh[c] = wn_g[c];
    for (int c = tid; c < 4096; c += 512) {
        const int D    = c * 16;
        const int s    = D >> 12;
        const int dr   = D & 4095;
        const int srcb = dr ^ (((dr >> 8) & 3) << 5);
        *reinterpret_cast<int4*>(reinterpret_cast<char*>(zsh) + D) =
            *reinterpret_cast<const int4*>(
                reinterpret_cast<const char*>(z_e) + (size_t)(b0 + s) * 4096 + srcb);
    }
    if (tid < 16) sflag[tid] = 0;
    __syncthreads();

    const int lane = tid & 63;
    const int w_id = tid >> 6;
    const int wr   = (w_id >> 1) * 32;
    const int wc   = (w_id & 1) * 64;
    const int l15  = lane & 15;
    const int lg   = lane >> 4;

    f32x4 acc[2][4];
    #pragma unroll
    for (int i = 0; i < 2; ++i)
        #pragma unroll
        for (int j = 0; j < 4; ++j) acc[i][j] = (f32x4){0.f, 0.f, 0.f, 0.f};

    #pragma unroll
    for (int ks = 0; ks < 4; ++ks) {
        bf16x8 bh[4], bl[4];
        #pragma unroll
        for (int cf = 0; cf < 4; ++cf) {
            const int n     = wc + cf * 16 + l15;
            const int slotp = (ks * 4 + lg) ^ (n & 7);
            const int off   = n * 128 + slotp * 8;
            bh[cf] = *reinterpret_cast<const bf16x8*>(&Wsh[off]);
            bl[cf] = *reinterpret_cast<const bf16x8*>(&Wsh[16384 + off]);
        }
        bf16x8 ah[2], al[2];
        #pragma unroll
        for (int rf = 0; rf < 2; ++rf) {
            const int row   = wr + rf * 16 + l15;
            const int s_loc = row >> 3;
            const int d     = row & 7;
            const int kb    = ks * 32 + lg * 8;
            const int xr    = (lg & 3) << 5;
            const char* zb  = reinterpret_cast<const char*>(zsh) + s_loc * 4096;
            bf16x8 h8, L8;
            #pragma unroll
            for (int j = 0; j < 8; ++j) {
                const float a = *reinterpret_cast<const float*>(
                    zb + ((32 * (kb + j) + 4 * d) ^ xr));
                const unsigned short hi = f32_to_bf16_rn(a);
                h8[j] = (short)hi;
                L8[j] = (short)f32_to_bf16_rn(a - bf16_bits_to_f32(hi));
            }
            ah[rf] = h8; al[rf] = L8;
        }
        #pragma unroll
        for (int rf = 0; rf < 2; ++rf)
            #pragma unroll
            for (int cf = 0; cf < 4; ++cf) {
                acc[rf][cf] = __builtin_amdgcn_mfma_f32_16x16x32_bf16(
                    ah[rf], bh[cf], acc[rf][cf], 0, 0, 0);
                acc[rf][cf] = __builtin_amdgcn_mfma_f32_16x16x32_bf16(
                    ah[rf], bl[cf], acc[rf][cf], 0, 0, 0);
                acc[rf][cf] = __builtin_amdgcn_mfma_f32_16x16x32_bf16(
                    al[rf], bh[cf], acc[rf][cf], 0, 0, 0);
            }
    }

    #pragma unroll
    for (int rf = 0; rf < 2; ++rf)
        #pragma unroll
        for (int j = 0; j < 4; ++j) {
            double v1 = 1e300, v2 = 1e300; int i1 = 0;
            #pragma unroll
            for (int cf = 0; cf < 4; ++cf) {
                const int n = wc + cf * 16 + l15;
                const double v = wn_sh[n] - 2.0 * (double)acc[rf][cf][j];
                if (v < v1)      { v2 = v1; v1 = v; i1 = n; }
                else if (v < v2) { v2 = v; }
            }
            #pragma unroll
            for (int off = 1; off < 16; off <<= 1) {
                const double ov1 = __shfl_xor(v1, off);
                const int    oi1 = __shfl_xor(i1, off);
                const double ov2 = __shfl_xor(v2, off);
                if (ov1 < v1 || (ov1 == v1 && oi1 < i1)) {
                    v2 = fmin(v1, ov2); v1 = ov1; i1 = oi1;
                } else {
                    v2 = fmin(v2, ov1);
                }
            }
            if (l15 == 0) {
                const int r = wr + rf * 16 + lg * 4 + j;
                cmb_v1[r][w_id & 1] = v1;
                cmb_v2[r][w_id & 1] = v2;
                cmb_i [r][w_id & 1] = i1;
            }
        }
    __syncthreads();

    if (tid < 128) {
        const double v1a = cmb_v1[tid][0], v1b = cmb_v1[tid][1];
        double v1, v2; int i1;
        if (v1b < v1a) { v1 = v1b; i1 = cmb_i[tid][1]; v2 = fmin(v1a, cmb_v2[tid][1]); }
        else           { v1 = v1a; i1 = cmb_i[tid][0]; v2 = fmin(v1b, cmb_v2[tid][0]); }
        idx_sh[tid] = i1;
        if (v2 - v1 < GAP_T) sflag[tid >> 3] = 1;
    }
    __syncthreads();
    if (tid < 16 && sflag[tid]) {
        const int p = atomicAdd(flag_cnt, 1);
        flag_ids[p] = b0 + tid;
    }

    for (int t = tid; t < 16384; t += 512) {
        const int s = t >> 10, i = t & 1023;
        const int k = i >> 3, d = i & 7;
        const int n = idx_sh[(s << 3) | d];
        const int off = n * 128 + (((k >> 3) ^ (n & 7)) << 3) + (k & 7);
        const float val = bf16_bits_to_f32((unsigned short)Wsh[off]) +
                          bf16_bits_to_f32((unsigned short)Wsh[16384 + off]);
        zq[(size_t)(b0 + s) * 1024 + i] = val;
        zqh[zq_plane_off(b0 + s, i)] = (short)f32_to_bf16_rn(val);
    }
}

// ================= fixup F1/F2: 64x64-tile f64 GEMM (NT) ===================
#define FLP 68
template<bool GATHER, bool SPLITK, bool FUSERED, typename TA>
__global__ __launch_bounds__(256) void gemm_f64t(
    const TA* __restrict__ A, const float* __restrict__ Wf,
    const int* __restrict__ ids, const int* __restrict__ cntp,
    const float* __restrict__ biasA, const float* __restrict__ bias,
    double* __restrict__ C,
    int AK, int N, int CN, int klen, int cap)
{
    __shared__ double As[16 * FLP];
    __shared__ double Ws[16 * FLP];

    const int tid = threadIdx.x;
    const int tx  = tid & 15;
    const int ty  = tid >> 4;
    const int m0  = blockIdx.y * 64;
    const int n0  = blockIdx.x * 64;
    const int cnt = (*cntp < cap) ? *cntp : cap;
    if (m0 >= cnt) return;

    const int k0 = SPLITK ? blockIdx.z * klen : 0;
    if (SPLITK) C += (size_t)blockIdx.z * cap * CN;

    const int srow = tid >> 2;
    const int sc4  = (tid & 3) << 2;

    const TA* arow;
    if (GATHER) {
        const int m  = m0 + srow;
        const int id = (m < cnt) ? ids[m] : 0;
        arow = A + (size_t)id * AK;
    } else {
        arow = A + (size_t)(m0 + srow) * AK;
    }
    const int   nrow = n0 + srow;
    const float* wrow = Wf + (size_t)(nrow < N ? nrow : 0) * AK;
    const bool  wok  = (nrow < N);

    double acc[4][4];
    #pragma unroll
    for (int i = 0; i < 4; ++i)
        #pragma unroll
        for (int j = 0; j < 4; ++j) acc[i][j] = 0.0;

    for (int kt = 0; kt < klen; kt += 16) {
        const int kb = k0 + kt + sc4;
        if constexpr (FUSERED) {
            const size_t cs = (size_t)cap * AK;
            #pragma unroll
            for (int e = 0; e < 4; ++e) {
                double s = (double)biasA[kb + e];
                #pragma unroll
                for (int c = 0; c < 6; ++c) s += arow[c * cs + kb + e];
                As[(sc4 + e) * FLP + srow] = s > 0.0 ? s : 0.0;
            }
        } else if constexpr (sizeof(TA) == 4) {
            const float4 v = *reinterpret_cast<const float4*>(&arow[kb]);
            As[(sc4 + 0) * FLP + srow] = (double)v.x;
            As[(sc4 + 1) * FLP + srow] = (double)v.y;
            As[(sc4 + 2) * FLP + srow] = (double)v.z;
            As[(sc4 + 3) * FLP + srow] = (double)v.w;
        } else {
            const double2 v0 = *reinterpret_cast<const double2*>(&arow[kb]);
            const double2 v1 = *reinterpret_cast<const double2*>(&arow[kb + 2]);
            As[(sc4 + 0) * FLP + srow] = v0.x;
            As[(sc4 + 1) * FLP + srow] = v0.y;
            As[(sc4 + 2) * FLP + srow] = v1.x;
            As[(sc4 + 3) * FLP + srow] = v1.y;
        }
        float4 w = make_float4(0.f, 0.f, 0.f, 0.f);
        if (wok) w = *reinterpret_cast<const float4*>(&wrow[kb]);
        Ws[(sc4 + 0) * FLP + srow] = (double)w.x;
        Ws[(sc4 + 1) * FLP + srow] = (double)w.y;
        Ws[(sc4 + 2) * FLP + srow] = (double)w.z;
        Ws[(sc4 + 3) * FLP + srow] = (double)w.w;
        __syncthreads();

        #pragma unroll
        for (int k = 0; k < 16; ++k) {
            const double2 A0 = *reinterpret_cast<const double2*>(&As[k * FLP + ty * 4]);
            const double2 A1 = *reinterpret_cast<const double2*>(&As[k * FLP + ty * 4 + 2]);
            const double2 B0 = *reinterpret_cast<const double2*>(&Ws[k * FLP + tx * 4]);
            const double2 B1 = *reinterpret_cast<const double2*>(&Ws[k * FLP + tx * 4 + 2]);
            const double a[4] = {A0.x, A0.y, A1.x, A1.y};
            const double b[4] = {B0.x, B0.y, B1.x, B1.y};
            #pragma unroll
            for (int i = 0; i < 4; ++i)
                #pragma unroll
                for (int j = 0; j < 4; ++j)
                    acc[i][j] = fma(a[i], b[j], acc[i][j]);
        }
        __syncthreads();
    }

    #pragma unroll
    for (int i = 0; i < 4; ++i) {
        const int row = m0 + ty * 4 + i;
        #pragma unroll
        for (int j = 0; j < 4; ++j) {
            const int col = n0 + tx * 4 + j;
            if (col < N)
                C[(size_t)row * CN + col] =
                    acc[i][j] + (bias ? (double)bias[col] : 0.0);
        }
    }
}

// ======= fixup F3: exact f64 distances + argmin + z_q scatter ===============
__global__ __launch_bounds__(512) void fix_argmin(
    const double* __restrict__ Zf, const float* __restrict__ Wemb,
    const int* __restrict__ cntp, const int* __restrict__ ids,
    float* __restrict__ zq, short* __restrict__ zqh, int cap)
{
    __shared__ float  wesh[16384];
    __shared__ double zsh[4][1032];
    __shared__ double dist[4 * 8 * 128];
    __shared__ int    idxf[32];

    const int tid  = threadIdx.x;
    const int lane = tid & 63;
    const int wv   = tid >> 6;
    const int cnt  = (*cntp < cap) ? *cntp : cap;
    const int base = blockIdx.x * 4;
    if (base >= cnt) return;
    const int ns = (cnt - base < 4) ? (cnt - base) : 4;

    for (int i = tid; i < 4096; i += 512)
        reinterpret_cast<float4*>(wesh)[i] =
            reinterpret_cast<const float4*>(Wemb)[i];
    for (int i = tid; i < 4 * 512; i += 512) {
        const int s = i >> 9, e = (i & 511) * 2;
        if (s < ns) {
            const double2 v = *reinterpret_cast<const double2*>(
                &Zf[(size_t)(base + s) * 1024 + e]);
            zsh[s][e] = v.x;
            zsh[s][e + 1] = v.y;
        }
    }
    __syncthreads();

    for (int t = tid; t < ns * 1024; t += 512) {
        const int s = t >> 10, d = (t >> 7) & 7, n = t & 127;
        double acc = 0.0;
        for (int k = 0; k < 128; ++k) {
            const double diff = zsh[s][k * 8 + d] - (double)wesh[k * 128 + n];
            acc = fma(diff, diff, acc);
        }
        dist[(s * 8 + d) * 128 + n] = acc;
    }
    __syncthreads();

    for (int p = wv; p < ns * 8; p += 8) {
        const double* dp = &dist[p * 128];
        double v0 = dp[lane], vx = dp[lane + 64];
        double v; int ix;
        if (vx < v0) { v = vx; ix = lane + 64; }
        else         { v = v0; ix = lane; }
        #pragma unroll
        for (int off = 32; off > 0; off >>= 1) {
            const double ov = __shfl_down(v, off);
            const int    oi = __shfl_down(ix, off);
            if (ov < v || (ov == v && oi < ix)) { v = ov; ix = oi; }
        }
        if (lane == 0) idxf[p] = ix;
    }
    __syncthreads();

    for (int i = tid; i < ns * 1024; i += 512) {
        const int s = i >> 10, ii = i & 1023;
        const int id = ids[base + s];
        const float val = wesh[(ii >> 3) * 128 + idxf[s * 8 + (ii & 7)]];
        zq[(size_t)id * 1024 + ii] = val;
        zqh[zq_plane_off(id, ii)] = (short)f32_to_bf16_rn(val);
    }
}

// ---------------------------------------------------------------------------
extern "C" void kernel_launch(void* const* d_in, const int* in_sizes, int n_in,
                              void* d_out, int out_size, void* d_ws, size_t ws_size,
                              hipStream_t stream)
{
    const float* x    = (const float*)d_in[0];
    const float* W1   = (const float*)d_in[1];
    const float* b1   = (const float*)d_in[2];
    const float* W2   = (const float*)d_in[3];
    const float* b2   = (const float*)d_in[4];
    const float* W3   = (const float*)d_in[5];
    const float* b3   = (const float*)d_in[6];
    const float* W4   = (const float*)d_in[7];
    const float* b4   = (const float*)d_in[8];
    const float* Wemb = (const float*)d_in[9];

    const int B = 16384;
    float* out   = (float*)d_out;
    float* recon = out;                                // B*3072
    float* z_e   = out + (size_t)B * 3072;             // B*1024
    float* emb_o = z_e + (size_t)B * 1024;             // B*1024 == z_q

    constexpr size_t X_PL  = 50331648;
    constexpr size_t H1_PL = 6815744;
    constexpr size_t H3_PL = 6815744;
    constexpr size_t W1_PL = 1572864;
    constexpr size_t W2_PL = 425984;
    constexpr size_t W3_PL = 524288;
    constexpr size_t W4_PL = 1277952;

    short* xh  = (short*)recon;          // x planes in recon section
    short* xl  = xh + X_PL;
    short* h1h = (short*)emb_o;          // h1 planes in emb_o section
    short* h1l = h1h + H1_PL;

    short*  h3h      = (short*)d_ws;
    short*  w1h      = h3h + H3_PL;
    short*  w1l      = w1h + W1_PL;
    short*  w2h      = w1l + W1_PL;
    short*  w2l      = w2h + W2_PL;
    short*  w3h      = w2l + W2_PL;
    short*  w4h      = w3h + W3_PL;
    short*  wembpl   = w4h + W4_PL;
    double* wn       = (double*)(wembpl + 32768);
    int*    flag_cnt = (int*)(wn + 128);
    int*    flag_ids = flag_cnt + 64;

    // recon-section scratch (x-planes dead after g1; g4 writes recon last):
    // Part[6] @ +0 (78.6MB), Zf @ +96MB (33.5MB), zqh plane @ +144MB (33.5MB)
    char*   scr  = (char*)recon;
    double* Part = (double*)scr;
    double* Zf   = (double*)(scr + (96ull  << 20));
    short*  zqh  = (short*) (scr + (144ull << 20));

    // ---- prep (single launch: x planes | W planes | VQ prep) ----
    prep_all<<<dim3(13217), dim3(256), 0, stream>>>(
        x, W1, W2, W3, W4, Wemb, xh, xl, w1h, w1l, w2h, w2l, w3h, w4h,
        wembpl, wn, flag_cnt);

    // ---- encoder ----
    gemm_pl<2, 1, 2><<<dim3(4, 128), dim3(256), 0, stream>>>(
        xh, xl, w1h, w1l, b1, nullptr, h1h, h1l, 400, 96, 13);
    gemm_pl<2, 0, 0><<<dim3(8, 128), dim3(256), 0, stream>>>(
        h1h, h1l, w2h, w2l, b2, z_e, nullptr, nullptr, 1024, 13, 0);

    // ---- VQ + fixup ----
    vq_mfma<<<dim3(1024), dim3(512), 0, stream>>>(z_e, wembpl, wn, emb_o, zqh,
                                                  flag_cnt, flag_ids);
    gemm_f64t<true, true, false, float><<<dim3(7, FIX_CAP / 64, 6), dim3(256), 0, stream>>>(
        x, W1, flag_ids, flag_cnt, nullptr, nullptr, Part, 3072, 400, 400, 512, FIX_CAP);
    gemm_f64t<false, false, true, double><<<dim3(16, FIX_CAP / 64), dim3(256), 0, stream>>>(
        Part, W2, nullptr, flag_cnt, b1, b2, Zf, 400, 1024, 1024, 400, FIX_CAP);
    fix_argmin<<<dim3(FIX_CAP / 4), dim3(512), 0, stream>>>(
        Zf, Wemb, flag_cnt, flag_ids, emb_o, zqh, FIX_CAP);

    // ---- decoder ----
    gemm_pl<1, 1, 1><<<dim3(4, 128), dim3(256), 0, stream>>>(
        zqh, nullptr, w3h, nullptr, b3, nullptr, h3h, nullptr, 400, 32, 13);
    gemm_pl<1, 2, 0><<<dim3(24, 128), dim3(256), 0, stream>>>(
        h3h, nullptr, w4h, nullptr, b4, recon, nullptr, nullptr, 3072, 13, 0);
}

// Round 12
// 670.093 us; speedup vs baseline: 1.1787x; 1.0139x over previous
//
#include <hip/hip_runtime.h>
#include <math.h>

// ---------------------------------------------------------------------------
// VQ-VAE forward on MI355X — round 12: x-split fused into g1 staging (T14
// issue-early/write-late), x-plane prep pass eliminated (x is L3-resident so
// g1's 4x f32 re-read is cheaper than the 600MB prep stream). Numerics
// bit-identical to round 11.
//   g1: h1 = relu(x @ W1^T + b1)        [A: f32 x, in-loop hi/lo split;
//                                        B: W1 planes; out: h1 hi/lo planes]
//   g2: z_e = h1 @ W2^T + b2            [planes -> f32 z_e output]
//   vq_mfma: MFMA dots + top-2 argmin + gap flag; writes z_q f32 + bf16 plane
//   fixup: F1 Part[c] = gatherX @ W1^T (6-way split-K, f64 64^2 tiles)
//          F2 Zf = relu(sum Part + b1) @ W2^T + b2  (fused reduce in staging)
//          F3 exact distances + argmin + z_q scatter (f32 + plane patch)
//   g3: h3 = relu(z_q @ W3^T + b3)      [z_q plane -> h3 hi plane]
//   g4: recon = sigmoid(h3 @ W4^T + b4) [planes -> f32 recon]
// ---------------------------------------------------------------------------

typedef short bf16x8 __attribute__((ext_vector_type(8)));
typedef short short8 __attribute__((ext_vector_type(8)));
typedef float f32x4  __attribute__((ext_vector_type(4)));

#define GAP_T   2e-4
#define FIX_CAP 4096

__device__ __forceinline__ unsigned short f32_to_bf16_rn(float v) {
    union { float f; unsigned u; } c; c.f = v;
    unsigned r = c.u + 0x7FFFu + ((c.u >> 16) & 1u);
    return (unsigned short)(r >> 16);
}
__device__ __forceinline__ float bf16_bits_to_f32(unsigned short b) {
    union { unsigned u; float f; } c; c.u = ((unsigned)b) << 16;
    return c.f;
}
__device__ __forceinline__ void glds16(const short* g, short* l) {
    __builtin_amdgcn_global_load_lds(
        (const __attribute__((address_space(1))) unsigned int*)g,
        (__attribute__((address_space(3))) unsigned int*)l, 16, 0, 0);
}
__device__ __forceinline__ size_t zq_plane_off(int id, int ii) {
    const int mb = id >> 7, r = id & 127;
    const int kt = ii >> 5, kc = ii & 31;
    return ((size_t)(mb * 32 + kt) * 4096)
         + r * 32 + (((kc >> 3) ^ (r & 3)) << 3) + (kc & 7);
}

// ================== merged prep: W planes + VQ prep (x prep removed) ========
__global__ __launch_bounds__(256) void prep_all(
    const float* __restrict__ W1, const float* __restrict__ W2,
    const float* __restrict__ W3, const float* __restrict__ W4,
    const float* __restrict__ Wemb,
    short* __restrict__ w1h, short* __restrict__ w1l,
    short* __restrict__ w2h, short* __restrict__ w2l,
    short* __restrict__ w3h, short* __restrict__ w4h,
    short* __restrict__ wembpl, double* __restrict__ wn,
    int* __restrict__ flag_cnt)
{
    const int tid = threadIdx.x;
    const int bid = blockIdx.x;

    if (bid < 928) {     // -------- weight planes --------
        const float* Wsrc; int N, K, KT, local; short *hi, *lo;
        if (bid < 384)      { Wsrc = W1; N = 400;  K = 3072; KT = 96; local = bid;       hi = w1h; lo = w1l; }
        else if (bid < 488) { Wsrc = W2; N = 1024; K = 400;  KT = 13; local = bid - 384; hi = w2h; lo = w2l; }
        else if (bid < 616) { Wsrc = W3; N = 400;  K = 1024; KT = 32; local = bid - 488; hi = w3h; lo = nullptr; }
        else                { Wsrc = W4; N = 3072; K = 400;  KT = 13; local = bid - 616; hi = w4h; lo = nullptr; }

        const int kt = local % KT;
        const int nb = local / KT;
        const size_t tb = (size_t)local * 4096;
        for (int ci = tid; ci < 512; ci += 256) {
            const int row = ci >> 2;
            const int sl  = ci & 3;
            const int k0  = ((sl ^ (row & 3)) << 3);
            const int n   = nb * 128 + row;
            const int kk  = kt * 32 + k0;
            float f[8];
            #pragma unroll
            for (int e = 0; e < 8; ++e)
                f[e] = (n < N && kk + e < K) ? Wsrc[(size_t)n * K + kk + e] : 0.f;
            short8 h, l;
            #pragma unroll
            for (int e = 0; e < 8; ++e) {
                const unsigned short hb = f32_to_bf16_rn(f[e]);
                h[e] = (short)hb;
                l[e] = (short)f32_to_bf16_rn(f[e] - bf16_bits_to_f32(hb));
            }
            *reinterpret_cast<short8*>(&hi[tb + ci * 8]) = h;
            if (lo) *reinterpret_cast<short8*>(&lo[tb + ci * 8]) = l;
        }
        return;
    }

    // -------- VQ prep (single block) --------
    if (tid == 0) *flag_cnt = 0;
    if (tid < 128) {
        double s = 0.0;
        for (int k = 0; k < 128; ++k) {
            const double w = (double)Wemb[k * 128 + tid];
            s = fma(w, w, s);
        }
        wn[tid] = s;
    }
    for (int t = tid; t < 16384; t += 256) {
        const int k = t >> 7, n = t & 127;
        const float w = Wemb[t];
        const unsigned short hi = f32_to_bf16_rn(w);
        const unsigned short lo = f32_to_bf16_rn(w - bf16_bits_to_f32(hi));
        const int off = n * 128 + (((k >> 3) ^ (n & 7)) << 3) + (k & 7);
        wembpl[off]         = (short)hi;
        wembpl[16384 + off] = (short)lo;
    }
}

// ====================== plane-fed MFMA GEMM (NT), 2-phase ===================
// AMODE: 0 = A from planes (glds); 1 = A from f32 row-major, hi/lo split
//        in-loop (issue loads early, convert+ds_write late; NSPLIT must be 2)
// OUTMODE: 0 f32 C; 1 hi plane; 2 hi+lo planes
template<int NSPLIT, int ACT, int AMODE, int OUTMODE>
__global__ __launch_bounds__(256) void gemm_pl(
    const short* __restrict__ Ahi, const short* __restrict__ Alo,
    const float* __restrict__ Af32, int AK,
    const short* __restrict__ Bhi, const short* __restrict__ Blo,
    const float* __restrict__ bias,
    float* __restrict__ Cf32, short* __restrict__ Cphi, short* __restrict__ Cplo,
    int N, int KT, int KTout)
{
    __shared__ short lds[2 * NSPLIT * 2 * 4096];   // double-buffered

    const int tid  = threadIdx.x;
    const int lane = tid & 63;
    const int w_id = tid >> 6;
    const int wr   = (w_id >> 1) * 64;
    const int wc   = (w_id & 1)  * 64;
    const int m0   = blockIdx.y * 128;
    const int n0   = blockIdx.x * 128;
    const int l15  = lane & 15;
    const int lg   = lane >> 4;
    constexpr int BUF = NSPLIT * 2 * 4096;

    f32x4 acc[4][4];
    #pragma unroll
    for (int i = 0; i < 4; ++i)
        #pragma unroll
        for (int j = 0; j < 4; ++j) acc[i][j] = (f32x4){0.f, 0.f, 0.f, 0.f};

    float xr[AMODE == 1 ? 16 : 1];   // reg-staged A tile (AMODE=1)

    // AMODE=1: load next A tile (f32) into registers (issue-early)
    auto loadA = [&](int kt) {
        #pragma unroll
        for (int i = 0; i < 2; ++i) {
            const int ci  = tid + i * 256;
            const int row = ci >> 2;
            const int sl  = ci & 3;
            const int k0  = ((sl ^ (row & 3)) << 3);
            const float* src = &Af32[(size_t)(m0 + row) * AK + kt * 32 + k0];
            const float4 f0 = *reinterpret_cast<const float4*>(src);
            const float4 f1 = *reinterpret_cast<const float4*>(src + 4);
            xr[i * 8 + 0] = f0.x; xr[i * 8 + 1] = f0.y;
            xr[i * 8 + 2] = f0.z; xr[i * 8 + 3] = f0.w;
            xr[i * 8 + 4] = f1.x; xr[i * 8 + 5] = f1.y;
            xr[i * 8 + 6] = f1.z; xr[i * 8 + 7] = f1.w;
        }
    };
    // AMODE=1: convert + ds_write A tile into buffer `buf` (write-late)
    auto writeA = [&](int buf) {
        short* L = &lds[buf * BUF];
        #pragma unroll
        for (int i = 0; i < 2; ++i) {
            const int ci = tid + i * 256;
            short8 h, l;
            #pragma unroll
            for (int e = 0; e < 8; ++e) {
                const float v = xr[i * 8 + e];
                const unsigned short hb = f32_to_bf16_rn(v);
                h[e] = (short)hb;
                l[e] = (short)f32_to_bf16_rn(v - bf16_bits_to_f32(hb));
            }
            *reinterpret_cast<short8*>(&L[ci * 8])        = h;
            *reinterpret_cast<short8*>(&L[4096 + ci * 8]) = l;
        }
    };
    // stage A (planes) + B into buffer `buf` via async DMA
    auto stageGL = [&](int buf, int kt) {
        short* L = &lds[buf * BUF];
        const size_t bt = ((size_t)blockIdx.x * KT + kt) * 4096;
        #pragma unroll
        for (int q = 0; q < 2; ++q) {
            const int o = (w_id * 2 + q) * 512 + lane * 8;
            if (AMODE == 0) {
                const size_t at = ((size_t)blockIdx.y * KT + kt) * 4096;
                glds16(Ahi + at + o, &L[o]);
                if (NSPLIT > 1) glds16(Alo + at + o, &L[4096 + o]);
            }
            glds16(Bhi + bt + o, &L[NSPLIT * 4096 + o]);
            if (NSPLIT > 1) glds16(Blo + bt + o, &L[(NSPLIT + 1) * 4096 + o]);
        }
    };

    // ---- prologue: fill buffer 0 ----
    if (AMODE == 1) loadA(0);
    stageGL(0, 0);
    if (AMODE == 1) writeA(0);
    __syncthreads();

    int cur = 0;
    for (int kt = 0; kt < KT; ++kt) {
        if (kt + 1 < KT) {
            if (AMODE == 1) loadA(kt + 1);     // x loads in flight during MFMA
            stageGL(cur ^ 1, kt + 1);          // DMA in flight during MFMA
        }

        const short* L = &lds[cur * BUF];
        bf16x8 bfr[4][NSPLIT];
        #pragma unroll
        for (int fc = 0; fc < 4; ++fc) {
            const int rn  = wc + fc * 16 + l15;
            const int idx = rn * 32 + ((lg ^ (rn & 3)) << 3);
            #pragma unroll
            for (int s = 0; s < NSPLIT; ++s)
                bfr[fc][s] = *reinterpret_cast<const bf16x8*>(&L[(NSPLIT + s) * 4096 + idx]);
        }
        #pragma unroll
        for (int fr = 0; fr < 4; ++fr) {
            const int rm  = wr + fr * 16 + l15;
            const int idx = rm * 32 + ((lg ^ (rm & 3)) << 3);
            const bf16x8 a0 = *reinterpret_cast<const bf16x8*>(&L[idx]);
            bf16x8 a1;
            if (NSPLIT > 1)
                a1 = *reinterpret_cast<const bf16x8*>(&L[4096 + idx]);
            #pragma unroll
            for (int fc = 0; fc < 4; ++fc) {
                acc[fr][fc] = __builtin_amdgcn_mfma_f32_16x16x32_bf16(
                    a0, bfr[fc][0], acc[fr][fc], 0, 0, 0);
                if (NSPLIT > 1) {
                    acc[fr][fc] = __builtin_amdgcn_mfma_f32_16x16x32_bf16(
                        a0, bfr[fc][1], acc[fr][fc], 0, 0, 0);
                    acc[fr][fc] = __builtin_amdgcn_mfma_f32_16x16x32_bf16(
                        a1, bfr[fc][0], acc[fr][fc], 0, 0, 0);
                }
            }
        }

        if (AMODE == 1 && kt + 1 < KT) writeA(cur ^ 1);   // write-late
        __syncthreads();             // drains DMA + guards buffer swap
        cur ^= 1;
    }

    float bv[4];
    #pragma unroll
    for (int fc = 0; fc < 4; ++fc) {
        const int col = n0 + wc + fc * 16 + l15;
        bv[fc] = (col < N) ? bias[col] : 0.f;
    }
    #pragma unroll
    for (int fr = 0; fr < 4; ++fr) {
        #pragma unroll
        for (int fc = 0; fc < 4; ++fc) {
            const int col = n0 + wc + fc * 16 + l15;
            #pragma unroll
            for (int j = 0; j < 4; ++j) {
                const int rowg = m0 + wr + fr * 16 + lg * 4 + j;
                float v = acc[fr][fc][j] + bv[fc];
                if (ACT == 1) v = fmaxf(v, 0.f);
                else if (ACT == 2) v = 1.f / (1.f + expf(-v));
                if (OUTMODE == 0) {
                    if (col < N) Cf32[(size_t)rowg * N + col] = v;
                } else {
                    const int kto = col >> 5;
                    if (kto < KTout) {
                        const int r = rowg & 127, k = col & 31;
                        const size_t off = ((size_t)blockIdx.y * KTout + kto) * 4096
                                         + r * 32 + (((k >> 3) ^ (r & 3)) << 3) + (k & 7);
                        const unsigned short hb = f32_to_bf16_rn(v);
                        Cphi[off] = (short)hb;
                        if (OUTMODE == 2)
                            Cplo[off] = (short)f32_to_bf16_rn(v - bf16_bits_to_f32(hb));
                    }
                }
            }
        }
    }
}

// ============================ VQ MFMA + argmin ==============================
__global__ __launch_bounds__(512) void vq_mfma(
    const float* __restrict__ z_e, const short* __restrict__ planes,
    const double* __restrict__ wn_g, float* __restrict__ zq,
    short* __restrict__ zqh,
    int* __restrict__ flag_cnt, int* __restrict__ flag_ids)
{
    __shared__ short  Wsh[32768];
    __shared__ float  zsh[16 * 1024];
    __shared__ double wn_sh[128];
    __shared__ double cmb_v1[128][2];
    __shared__ double cmb_v2[128][2];
    __shared__ int    cmb_i[128][2];
    __shared__ int    idx_sh[128];
    __shared__ int    sflag[16];

    const int tid = threadIdx.x;
    const int b0  = blockIdx.x * 16;

    for (int c = tid; c < 4096; c += 512)
        *reinterpret_cast<int4*>(&Wsh[c * 8]) =
            *reinterpret_cast<const int4*>(&planes[c * 8]);
    for (int c = tid; c < 128; c += 512) wn_sh[c] = wn_g[c];
    for (int c = tid; c < 4096; c += 512) {
        const int D    = c * 16;
        const int s    = D >> 12;
        const int dr   = D & 4095;
        const int srcb = dr ^ (((dr >> 8) & 3) << 5);
        *reinterpret_cast<int4*>(reinterpret_cast<char*>(zsh) + D) =
            *reinterpret_cast<const int4*>(
                reinterpret_cast<const char*>(z_e) + (size_t)(b0 + s) * 4096 + srcb);
    }
    if (tid < 16) sflag[tid] = 0;
    __syncthreads();

    const int lane = tid & 63;
    const int w_id = tid >> 6;
    const int wr   = (w_id >> 1) * 32;
    const int wc   = (w_id & 1) * 64;
    const int l15  = lane & 15;
    const int lg   = lane >> 4;

    f32x4 acc[2][4];
    #pragma unroll
    for (int i = 0; i < 2; ++i)
        #pragma unroll
        for (int j = 0; j < 4; ++j) acc[i][j] = (f32x4){0.f, 0.f, 0.f, 0.f};

    #pragma unroll
    for (int ks = 0; ks < 4; ++ks) {
        bf16x8 bh[4], bl[4];
        #pragma unroll
        for (int cf = 0; cf < 4; ++cf) {
            const int n     = wc + cf * 16 + l15;
            const int slotp = (ks * 4 + lg) ^ (n & 7);
            const int off   = n * 128 + slotp * 8;
            bh[cf] = *reinterpret_cast<const bf16x8*>(&Wsh[off]);
            bl[cf] = *reinterpret_cast<const bf16x8*>(&Wsh[16384 + off]);
        }
        bf16x8 ah[2], al[2];
        #pragma unroll
        for (int rf = 0; rf < 2; ++rf) {
            const int row   = wr + rf * 16 + l15;
            const int s_loc = row >> 3;
            const int d     = row & 7;
            const int kb    = ks * 32 + lg * 8;
            const int xr    = (lg & 3) << 5;
            const char* zb  = reinterpret_cast<const char*>(zsh) + s_loc * 4096;
            bf16x8 h8, L8;
            #pragma unroll
            for (int j = 0; j < 8; ++j) {
                const float a = *reinterpret_cast<const float*>(
                    zb + ((32 * (kb + j) + 4 * d) ^ xr));
                const unsigned short hi = f32_to_bf16_rn(a);
                h8[j] = (short)hi;
                L8[j] = (short)f32_to_bf16_rn(a - bf16_bits_to_f32(hi));
            }
            ah[rf] = h8; al[rf] = L8;
        }
        #pragma unroll
        for (int rf = 0; rf < 2; ++rf)
            #pragma unroll
            for (int cf = 0; cf < 4; ++cf) {
                acc[rf][cf] = __builtin_amdgcn_mfma_f32_16x16x32_bf16(
                    ah[rf], bh[cf], acc[rf][cf], 0, 0, 0);
                acc[rf][cf] = __builtin_amdgcn_mfma_f32_16x16x32_bf16(
                    ah[rf], bl[cf], acc[rf][cf], 0, 0, 0);
                acc[rf][cf] = __builtin_amdgcn_mfma_f32_16x16x32_bf16(
                    al[rf], bh[cf], acc[rf][cf], 0, 0, 0);
            }
    }

    #pragma unroll
    for (int rf = 0; rf < 2; ++rf)
        #pragma unroll
        for (int j = 0; j < 4; ++j) {
            double v1 = 1e300, v2 = 1e300; int i1 = 0;
            #pragma unroll
            for (int cf = 0; cf < 4; ++cf) {
                const int n = wc + cf * 16 + l15;
                const double v = wn_sh[n] - 2.0 * (double)acc[rf][cf][j];
                if (v < v1)      { v2 = v1; v1 = v; i1 = n; }
                else if (v < v2) { v2 = v; }
            }
            #pragma unroll
            for (int off = 1; off < 16; off <<= 1) {
                const double ov1 = __shfl_xor(v1, off);
                const int    oi1 = __shfl_xor(i1, off);
                const double ov2 = __shfl_xor(v2, off);
                if (ov1 < v1 || (ov1 == v1 && oi1 < i1)) {
                    v2 = fmin(v1, ov2); v1 = ov1; i1 = oi1;
                } else {
                    v2 = fmin(v2, ov1);
                }
            }
            if (l15 == 0) {
                const int r = wr + rf * 16 + lg * 4 + j;
                cmb_v1[r][w_id & 1] = v1;
                cmb_v2[r][w_id & 1] = v2;
                cmb_i [r][w_id & 1] = i1;
            }
        }
    __syncthreads();

    if (tid < 128) {
        const double v1a = cmb_v1[tid][0], v1b = cmb_v1[tid][1];
        double v1, v2; int i1;
        if (v1b < v1a) { v1 = v1b; i1 = cmb_i[tid][1]; v2 = fmin(v1a, cmb_v2[tid][1]); }
        else           { v1 = v1a; i1 = cmb_i[tid][0]; v2 = fmin(v1b, cmb_v2[tid][0]); }
        idx_sh[tid] = i1;
        if (v2 - v1 < GAP_T) sflag[tid >> 3] = 1;
    }
    __syncthreads();
    if (tid < 16 && sflag[tid]) {
        const int p = atomicAdd(flag_cnt, 1);
        flag_ids[p] = b0 + tid;
    }

    for (int t = tid; t < 16384; t += 512) {
        const int s = t >> 10, i = t & 1023;
        const int k = i >> 3, d = i & 7;
        const int n = idx_sh[(s << 3) | d];
        const int off = n * 128 + (((k >> 3) ^ (n & 7)) << 3) + (k & 7);
        const float val = bf16_bits_to_f32((unsigned short)Wsh[off]) +
                          bf16_bits_to_f32((unsigned short)Wsh[16384 + off]);
        zq[(size_t)(b0 + s) * 1024 + i] = val;
        zqh[zq_plane_off(b0 + s, i)] = (short)f32_to_bf16_rn(val);
    }
}

// ================= fixup F1/F2: 64x64-tile f64 GEMM (NT) ===================
#define FLP 68
template<bool GATHER, bool SPLITK, bool FUSERED, typename TA>
__global__ __launch_bounds__(256) void gemm_f64t(
    const TA* __restrict__ A, const float* __restrict__ Wf,
    const int* __restrict__ ids, const int* __restrict__ cntp,
    const float* __restrict__ biasA, const float* __restrict__ bias,
    double* __restrict__ C,
    int AK, int N, int CN, int klen, int cap)
{
    __shared__ double As[16 * FLP];
    __shared__ double Ws[16 * FLP];

    const int tid = threadIdx.x;
    const int tx  = tid & 15;
    const int ty  = tid >> 4;
    const int m0  = blockIdx.y * 64;
    const int n0  = blockIdx.x * 64;
    const int cnt = (*cntp < cap) ? *cntp : cap;
    if (m0 >= cnt) return;

    const int k0 = SPLITK ? blockIdx.z * klen : 0;
    if (SPLITK) C += (size_t)blockIdx.z * cap * CN;

    const int srow = tid >> 2;
    const int sc4  = (tid & 3) << 2;

    const TA* arow;
    if (GATHER) {
        const int m  = m0 + srow;
        const int id = (m < cnt) ? ids[m] : 0;
        arow = A + (size_t)id * AK;
    } else {
        arow = A + (size_t)(m0 + srow) * AK;
    }
    const int   nrow = n0 + srow;
    const float* wrow = Wf + (size_t)(nrow < N ? nrow : 0) * AK;
    const bool  wok  = (nrow < N);

    double acc[4][4];
    #pragma unroll
    for (int i = 0; i < 4; ++i)
        #pragma unroll
        for (int j = 0; j < 4; ++j) acc[i][j] = 0.0;

    for (int kt = 0; kt < klen; kt += 16) {
        const int kb = k0 + kt + sc4;
        if constexpr (FUSERED) {
            const size_t cs = (size_t)cap * AK;
            #pragma unroll
            for (int e = 0; e < 4; ++e) {
                double s = (double)biasA[kb + e];
                #pragma unroll
                for (int c = 0; c < 6; ++c) s += arow[c * cs + kb + e];
                As[(sc4 + e) * FLP + srow] = s > 0.0 ? s : 0.0;
            }
        } else if constexpr (sizeof(TA) == 4) {
            const float4 v = *reinterpret_cast<const float4*>(&arow[kb]);
            As[(sc4 + 0) * FLP + srow] = (double)v.x;
            As[(sc4 + 1) * FLP + srow] = (double)v.y;
            As[(sc4 + 2) * FLP + srow] = (double)v.z;
            As[(sc4 + 3) * FLP + srow] = (double)v.w;
        } else {
            const double2 v0 = *reinterpret_cast<const double2*>(&arow[kb]);
            const double2 v1 = *reinterpret_cast<const double2*>(&arow[kb + 2]);
            As[(sc4 + 0) * FLP + srow] = v0.x;
            As[(sc4 + 1) * FLP + srow] = v0.y;
            As[(sc4 + 2) * FLP + srow] = v1.x;
            As[(sc4 + 3) * FLP + srow] = v1.y;
        }
        float4 w = make_float4(0.f, 0.f, 0.f, 0.f);
        if (wok) w = *reinterpret_cast<const float4*>(&wrow[kb]);
        Ws[(sc4 + 0) * FLP + srow] = (double)w.x;
        Ws[(sc4 + 1) * FLP + srow] = (double)w.y;
        Ws[(sc4 + 2) * FLP + srow] = (double)w.z;
        Ws[(sc4 + 3) * FLP + srow] = (double)w.w;
        __syncthreads();

        #pragma unroll
        for (int k = 0; k < 16; ++k) {
            const double2 A0 = *reinterpret_cast<const double2*>(&As[k * FLP + ty * 4]);
            const double2 A1 = *reinterpret_cast<const double2*>(&As[k * FLP + ty * 4 + 2]);
            const double2 B0 = *reinterpret_cast<const double2*>(&Ws[k * FLP + tx * 4]);
            const double2 B1 = *reinterpret_cast<const double2*>(&Ws[k * FLP + tx * 4 + 2]);
            const double a[4] = {A0.x, A0.y, A1.x, A1.y};
            const double b[4] = {B0.x, B0.y, B1.x, B1.y};
            #pragma unroll
            for (int i = 0; i < 4; ++i)
                #pragma unroll
                for (int j = 0; j < 4; ++j)
                    acc[i][j] = fma(a[i], b[j], acc[i][j]);
        }
        __syncthreads();
    }

    #pragma unroll
    for (int i = 0; i < 4; ++i) {
        const int row = m0 + ty * 4 + i;
        #pragma unroll
        for (int j = 0; j < 4; ++j) {
            const int col = n0 + tx * 4 + j;
            if (col < N)
                C[(size_t)row * CN + col] =
                    acc[i][j] + (bias ? (double)bias[col] : 0.0);
        }
    }
}

// ======= fixup F3: exact f64 distances + argmin + z_q scatter ===============
__global__ __launch_bounds__(512) void fix_argmin(
    const double* __restrict__ Zf, const float* __restrict__ Wemb,
    const int* __restrict__ cntp, const int* __restrict__ ids,
    float* __restrict__ zq, short* __restrict__ zqh, int cap)
{
    __shared__ float  wesh[16384];
    __shared__ double zsh[4][1032];
    __shared__ double dist[4 * 8 * 128];
    __shared__ int    idxf[32];

    const int tid  = threadIdx.x;
    const int lane = tid & 63;
    const int wv   = tid >> 6;
    const int cnt  = (*cntp < cap) ? *cntp : cap;
    const int base = blockIdx.x * 4;
    if (base >= cnt) return;
    const int ns = (cnt - base < 4) ? (cnt - base) : 4;

    for (int i = tid; i < 4096; i += 512)
        reinterpret_cast<float4*>(wesh)[i] =
            reinterpret_cast<const float4*>(Wemb)[i];
    for (int i = tid; i < 4 * 512; i += 512) {
        const int s = i >> 9, e = (i & 511) * 2;
        if (s < ns) {
            const double2 v = *reinterpret_cast<const double2*>(
                &Zf[(size_t)(base + s) * 1024 + e]);
            zsh[s][e] = v.x;
            zsh[s][e + 1] = v.y;
        }
    }
    __syncthreads();

    for (int t = tid; t < ns * 1024; t += 512) {
        const int s = t >> 10, d = (t >> 7) & 7, n = t & 127;
        double acc = 0.0;
        for (int k = 0; k < 128; ++k) {
            const double diff = zsh[s][k * 8 + d] - (double)wesh[k * 128 + n];
            acc = fma(diff, diff, acc);
        }
        dist[(s * 8 + d) * 128 + n] = acc;
    }
    __syncthreads();

    for (int p = wv; p < ns * 8; p += 8) {
        const double* dp = &dist[p * 128];
        double v0 = dp[lane], vx = dp[lane + 64];
        double v; int ix;
        if (vx < v0) { v = vx; ix = lane + 64; }
        else         { v = v0; ix = lane; }
        #pragma unroll
        for (int off = 32; off > 0; off >>= 1) {
            const double ov = __shfl_down(v, off);
            const int    oi = __shfl_down(ix, off);
            if (ov < v || (ov == v && oi < ix)) { v = ov; ix = oi; }
        }
        if (lane == 0) idxf[p] = ix;
    }
    __syncthreads();

    for (int i = tid; i < ns * 1024; i += 512) {
        const int s = i >> 10, ii = i & 1023;
        const int id = ids[base + s];
        const float val = wesh[(ii >> 3) * 128 + idxf[s * 8 + (ii & 7)]];
        zq[(size_t)id * 1024 + ii] = val;
        zqh[zq_plane_off(id, ii)] = (short)f32_to_bf16_rn(val);
    }
}

// ---------------------------------------------------------------------------
extern "C" void kernel_launch(void* const* d_in, const int* in_sizes, int n_in,
                              void* d_out, int out_size, void* d_ws, size_t ws_size,
                              hipStream_t stream)
{
    const float* x    = (const float*)d_in[0];
    const float* W1   = (const float*)d_in[1];
    const float* b1   = (const float*)d_in[2];
    const float* W2   = (const float*)d_in[3];
    const float* b2   = (const float*)d_in[4];
    const float* W3   = (const float*)d_in[5];
    const float* b3   = (const float*)d_in[6];
    const float* W4   = (const float*)d_in[7];
    const float* b4   = (const float*)d_in[8];
    const float* Wemb = (const float*)d_in[9];

    const int B = 16384;
    float* out   = (float*)d_out;
    float* recon = out;                                // B*3072
    float* z_e   = out + (size_t)B * 3072;             // B*1024
    float* emb_o = z_e + (size_t)B * 1024;             // B*1024 == z_q

    constexpr size_t H1_PL = 6815744;
    constexpr size_t H3_PL = 6815744;
    constexpr size_t W1_PL = 1572864;
    constexpr size_t W2_PL = 425984;
    constexpr size_t W3_PL = 524288;
    constexpr size_t W4_PL = 1277952;

    short* h1h = (short*)emb_o;          // h1 planes in emb_o section
    short* h1l = h1h + H1_PL;

    short*  h3h      = (short*)d_ws;
    short*  w1h      = h3h + H3_PL;
    short*  w1l      = w1h + W1_PL;
    short*  w2h      = w1l + W1_PL;
    short*  w2l      = w2h + W2_PL;
    short*  w3h      = w2l + W2_PL;
    short*  w4h      = w3h + W3_PL;
    short*  wembpl   = w4h + W4_PL;
    double* wn       = (double*)(wembpl + 32768);
    int*    flag_cnt = (int*)(wn + 128);
    int*    flag_ids = flag_cnt + 64;

    // recon-section scratch (dead until g4 writes recon last):
    // Part[6] @ +0 (78.6MB), Zf @ +96MB (33.5MB), zqh plane @ +144MB (33.5MB)
    char*   scr  = (char*)recon;
    double* Part = (double*)scr;
    double* Zf   = (double*)(scr + (96ull  << 20));
    short*  zqh  = (short*) (scr + (144ull << 20));

    // ---- prep (W planes | VQ prep; x prep eliminated) ----
    prep_all<<<dim3(929), dim3(256), 0, stream>>>(
        W1, W2, W3, W4, Wemb, w1h, w1l, w2h, w2l, w3h, w4h,
        wembpl, wn, flag_cnt);

    // ---- encoder ----
    // g1: A = x f32 with in-loop hi/lo split (issue-early/write-late)
    gemm_pl<2, 1, 1, 2><<<dim3(4, 128), dim3(256), 0, stream>>>(
        nullptr, nullptr, x, 3072, w1h, w1l, b1, nullptr, h1h, h1l, 400, 96, 13);
    gemm_pl<2, 0, 0, 0><<<dim3(8, 128), dim3(256), 0, stream>>>(
        h1h, h1l, nullptr, 0, w2h, w2l, b2, z_e, nullptr, nullptr, 1024, 13, 0);

    // ---- VQ + fixup ----
    vq_mfma<<<dim3(1024), dim3(512), 0, stream>>>(z_e, wembpl, wn, emb_o, zqh,
                                                  flag_cnt, flag_ids);
    gemm_f64t<true, true, false, float><<<dim3(7, FIX_CAP / 64, 6), dim3(256), 0, stream>>>(
        x, W1, flag_ids, flag_cnt, nullptr, nullptr, Part, 3072, 400, 400, 512, FIX_CAP);
    gemm_f64t<false, false, true, double><<<dim3(16, FIX_CAP / 64), dim3(256), 0, stream>>>(
        Part, W2, nullptr, flag_cnt, b1, b2, Zf, 400, 1024, 1024, 400, FIX_CAP);
    fix_argmin<<<dim3(FIX_CAP / 4), dim3(512), 0, stream>>>(
        Zf, Wemb, flag_cnt, flag_ids, emb_o, zqh, FIX_CAP);

    // ---- decoder ----
    gemm_pl<1, 1, 0, 1><<<dim3(4, 128), dim3(256), 0, stream>>>(
        zqh, nullptr, nullptr, 0, w3h, nullptr, b3, nullptr, h3h, nullptr,
        400, 32, 13);
    gemm_pl<1, 2, 0, 0><<<dim3(24, 128), dim3(256), 0, stream>>>(
        h3h, nullptr, nullptr, 0, w4h, nullptr, b4, recon, nullptr, nullptr,
        3072, 13, 0);
}

// Round 13
// 639.483 us; speedup vs baseline: 1.2351x; 1.0479x over previous
//
#include <hip/hip_runtime.h>
#include <math.h>

// ---------------------------------------------------------------------------
// VQ-VAE forward on MI355X — round 13: g1 in-loop x split switched to
// truncation-split (hi=bits&0xFFFF0000, lo=rn(v-hi): ~40% less VALU, capture
// err 2^-17 still ~10 sigma under GAP_T) + XCD-grouped block map so the 4
// column-blocks sharing x rows hit the same XCD L2 (FETCH ~399->~220MB).
//   g1: h1 = relu(x @ W1^T + b1)        [A: f32 x, in-loop trunc split;
//                                        B: W1 planes; out: h1 hi/lo planes]
//   g2: z_e = h1 @ W2^T + b2            [planes -> f32 z_e output]
//   vq_mfma: MFMA dots + top-2 argmin + gap flag; writes z_q f32 + bf16 plane
//   fixup: F1 Part[c]=gatherX@W1^T (f64) | F2 Zf=relu(ΣPart+b1)@W2^T+b2 | F3
//   g3: h3 = relu(z_q @ W3^T + b3)      [z_q plane -> h3 hi plane]
//   g4: recon = sigmoid(h3 @ W4^T + b4) [planes -> f32 recon]
// ---------------------------------------------------------------------------

typedef short bf16x8 __attribute__((ext_vector_type(8)));
typedef short short8 __attribute__((ext_vector_type(8)));
typedef float f32x4  __attribute__((ext_vector_type(4)));

#define GAP_T   2e-4
#define FIX_CAP 4096

__device__ __forceinline__ unsigned short f32_to_bf16_rn(float v) {
    union { float f; unsigned u; } c; c.f = v;
    unsigned r = c.u + 0x7FFFu + ((c.u >> 16) & 1u);
    return (unsigned short)(r >> 16);
}
__device__ __forceinline__ float bf16_bits_to_f32(unsigned short b) {
    union { unsigned u; float f; } c; c.u = ((unsigned)b) << 16;
    return c.f;
}
__device__ __forceinline__ void glds16(const short* g, short* l) {
    __builtin_amdgcn_global_load_lds(
        (const __attribute__((address_space(1))) unsigned int*)g,
        (__attribute__((address_space(3))) unsigned int*)l, 16, 0, 0);
}
__device__ __forceinline__ size_t zq_plane_off(int id, int ii) {
    const int mb = id >> 7, r = id & 127;
    const int kt = ii >> 5, kc = ii & 31;
    return ((size_t)(mb * 32 + kt) * 4096)
         + r * 32 + (((kc >> 3) ^ (r & 3)) << 3) + (kc & 7);
}

// ================== merged prep: W planes + VQ prep =========================
__global__ __launch_bounds__(256) void prep_all(
    const float* __restrict__ W1, const float* __restrict__ W2,
    const float* __restrict__ W3, const float* __restrict__ W4,
    const float* __restrict__ Wemb,
    short* __restrict__ w1h, short* __restrict__ w1l,
    short* __restrict__ w2h, short* __restrict__ w2l,
    short* __restrict__ w3h, short* __restrict__ w4h,
    short* __restrict__ wembpl, double* __restrict__ wn,
    int* __restrict__ flag_cnt)
{
    const int tid = threadIdx.x;
    const int bid = blockIdx.x;

    if (bid < 928) {     // -------- weight planes --------
        const float* Wsrc; int N, K, KT, local; short *hi, *lo;
        if (bid < 384)      { Wsrc = W1; N = 400;  K = 3072; KT = 96; local = bid;       hi = w1h; lo = w1l; }
        else if (bid < 488) { Wsrc = W2; N = 1024; K = 400;  KT = 13; local = bid - 384; hi = w2h; lo = w2l; }
        else if (bid < 616) { Wsrc = W3; N = 400;  K = 1024; KT = 32; local = bid - 488; hi = w3h; lo = nullptr; }
        else                { Wsrc = W4; N = 3072; K = 400;  KT = 13; local = bid - 616; hi = w4h; lo = nullptr; }

        const int kt = local % KT;
        const int nb = local / KT;
        const size_t tb = (size_t)local * 4096;
        for (int ci = tid; ci < 512; ci += 256) {
            const int row = ci >> 2;
            const int sl  = ci & 3;
            const int k0  = ((sl ^ (row & 3)) << 3);
            const int n   = nb * 128 + row;
            const int kk  = kt * 32 + k0;
            float f[8];
            #pragma unroll
            for (int e = 0; e < 8; ++e)
                f[e] = (n < N && kk + e < K) ? Wsrc[(size_t)n * K + kk + e] : 0.f;
            short8 h, l;
            #pragma unroll
            for (int e = 0; e < 8; ++e) {
                const unsigned short hb = f32_to_bf16_rn(f[e]);
                h[e] = (short)hb;
                l[e] = (short)f32_to_bf16_rn(f[e] - bf16_bits_to_f32(hb));
            }
            *reinterpret_cast<short8*>(&hi[tb + ci * 8]) = h;
            if (lo) *reinterpret_cast<short8*>(&lo[tb + ci * 8]) = l;
        }
        return;
    }

    // -------- VQ prep (single block) --------
    if (tid == 0) *flag_cnt = 0;
    if (tid < 128) {
        double s = 0.0;
        for (int k = 0; k < 128; ++k) {
            const double w = (double)Wemb[k * 128 + tid];
            s = fma(w, w, s);
        }
        wn[tid] = s;
    }
    for (int t = tid; t < 16384; t += 256) {
        const int k = t >> 7, n = t & 127;
        const float w = Wemb[t];
        const unsigned short hi = f32_to_bf16_rn(w);
        const unsigned short lo = f32_to_bf16_rn(w - bf16_bits_to_f32(hi));
        const int off = n * 128 + (((k >> 3) ^ (n & 7)) << 3) + (k & 7);
        wembpl[off]         = (short)hi;
        wembpl[16384 + off] = (short)lo;
    }
}

// ====================== plane-fed MFMA GEMM (NT), 2-phase ===================
// AMODE: 0 = A from planes (glds); 1 = A from f32 row-major, trunc hi/lo
//        split in-loop (issue loads early, convert+ds_write late; NSPLIT=2)
// OUTMODE: 0 f32 C; 1 hi plane; 2 hi+lo planes
// XCDMAP: 1D grid 512, xcd-grouped decode (g1 only: 4 col-blocks per x-row
//         group land on one XCD's L2)
template<int NSPLIT, int ACT, int AMODE, int OUTMODE, bool XCDMAP>
__global__ __launch_bounds__(256) void gemm_pl(
    const short* __restrict__ Ahi, const short* __restrict__ Alo,
    const float* __restrict__ Af32, int AK,
    const short* __restrict__ Bhi, const short* __restrict__ Blo,
    const float* __restrict__ bias,
    float* __restrict__ Cf32, short* __restrict__ Cphi, short* __restrict__ Cplo,
    int N, int KT, int KTout)
{
    __shared__ short lds[2 * NSPLIT * 2 * 4096];   // double-buffered

    const int tid  = threadIdx.x;
    const int lane = tid & 63;
    const int w_id = tid >> 6;
    const int wr   = (w_id >> 1) * 64;
    const int wc   = (w_id & 1)  * 64;

    int bx, byy;
    if constexpr (XCDMAP) {          // grid 512: by = xcd*16 + (g>>2), bx = g&3
        const int bid = blockIdx.x;
        const int xcd = bid & 7, g = bid >> 3;
        byy = xcd * 16 + (g >> 2);
        bx  = g & 3;
    } else {
        bx = blockIdx.x; byy = blockIdx.y;
    }
    const int m0   = byy * 128;
    const int n0   = bx * 128;
    const int l15  = lane & 15;
    const int lg   = lane >> 4;
    constexpr int BUF = NSPLIT * 2 * 4096;

    f32x4 acc[4][4];
    #pragma unroll
    for (int i = 0; i < 4; ++i)
        #pragma unroll
        for (int j = 0; j < 4; ++j) acc[i][j] = (f32x4){0.f, 0.f, 0.f, 0.f};

    float xr[AMODE == 1 ? 16 : 1];   // reg-staged A tile (AMODE=1)

    auto loadA = [&](int kt) {       // issue-early f32 x loads
        #pragma unroll
        for (int i = 0; i < 2; ++i) {
            const int ci  = tid + i * 256;
            const int row = ci >> 2;
            const int sl  = ci & 3;
            const int k0  = ((sl ^ (row & 3)) << 3);
            const float* src = &Af32[(size_t)(m0 + row) * AK + kt * 32 + k0];
            const float4 f0 = *reinterpret_cast<const float4*>(src);
            const float4 f1 = *reinterpret_cast<const float4*>(src + 4);
            xr[i * 8 + 0] = f0.x; xr[i * 8 + 1] = f0.y;
            xr[i * 8 + 2] = f0.z; xr[i * 8 + 3] = f0.w;
            xr[i * 8 + 4] = f1.x; xr[i * 8 + 5] = f1.y;
            xr[i * 8 + 6] = f1.z; xr[i * 8 + 7] = f1.w;
        }
    };
    auto writeA = [&](int buf) {     // write-late: trunc hi + rn lo
        short* L = &lds[buf * BUF];
        #pragma unroll
        for (int i = 0; i < 2; ++i) {
            const int ci = tid + i * 256;
            short8 h, l;
            #pragma unroll
            for (int e = 0; e < 8; ++e) {
                const float v = xr[i * 8 + e];
                const unsigned u = __float_as_uint(v);
                const float hf = __uint_as_float(u & 0xFFFF0000u);
                h[e] = (short)(u >> 16);                    // hi = trunc-bf16
                l[e] = (short)f32_to_bf16_rn(v - hf);       // exact residual
            }
            *reinterpret_cast<short8*>(&L[ci * 8])        = h;
            *reinterpret_cast<short8*>(&L[4096 + ci * 8]) = l;
        }
    };
    auto stageGL = [&](int buf, int kt) {
        short* L = &lds[buf * BUF];
        const size_t bt = ((size_t)bx * KT + kt) * 4096;
        #pragma unroll
        for (int q = 0; q < 2; ++q) {
            const int o = (w_id * 2 + q) * 512 + lane * 8;
            if (AMODE == 0) {
                const size_t at = ((size_t)byy * KT + kt) * 4096;
                glds16(Ahi + at + o, &L[o]);
                if (NSPLIT > 1) glds16(Alo + at + o, &L[4096 + o]);
            }
            glds16(Bhi + bt + o, &L[NSPLIT * 4096 + o]);
            if (NSPLIT > 1) glds16(Blo + bt + o, &L[(NSPLIT + 1) * 4096 + o]);
        }
    };

    // ---- prologue: fill buffer 0 ----
    if (AMODE == 1) loadA(0);
    stageGL(0, 0);
    if (AMODE == 1) writeA(0);
    __syncthreads();

    int cur = 0;
    for (int kt = 0; kt < KT; ++kt) {
        if (kt + 1 < KT) {
            if (AMODE == 1) loadA(kt + 1);     // x loads in flight during MFMA
            stageGL(cur ^ 1, kt + 1);          // DMA in flight during MFMA
        }

        const short* L = &lds[cur * BUF];
        bf16x8 bfr[4][NSPLIT];
        #pragma unroll
        for (int fc = 0; fc < 4; ++fc) {
            const int rn  = wc + fc * 16 + l15;
            const int idx = rn * 32 + ((lg ^ (rn & 3)) << 3);
            #pragma unroll
            for (int s = 0; s < NSPLIT; ++s)
                bfr[fc][s] = *reinterpret_cast<const bf16x8*>(&L[(NSPLIT + s) * 4096 + idx]);
        }
        #pragma unroll
        for (int fr = 0; fr < 4; ++fr) {
            const int rm  = wr + fr * 16 + l15;
            const int idx = rm * 32 + ((lg ^ (rm & 3)) << 3);
            const bf16x8 a0 = *reinterpret_cast<const bf16x8*>(&L[idx]);
            bf16x8 a1;
            if (NSPLIT > 1)
                a1 = *reinterpret_cast<const bf16x8*>(&L[4096 + idx]);
            #pragma unroll
            for (int fc = 0; fc < 4; ++fc) {
                acc[fr][fc] = __builtin_amdgcn_mfma_f32_16x16x32_bf16(
                    a0, bfr[fc][0], acc[fr][fc], 0, 0, 0);
                if (NSPLIT > 1) {
                    acc[fr][fc] = __builtin_amdgcn_mfma_f32_16x16x32_bf16(
                        a0, bfr[fc][1], acc[fr][fc], 0, 0, 0);
                    acc[fr][fc] = __builtin_amdgcn_mfma_f32_16x16x32_bf16(
                        a1, bfr[fc][0], acc[fr][fc], 0, 0, 0);
                }
            }
        }

        if (AMODE == 1 && kt + 1 < KT) writeA(cur ^ 1);   // write-late
        __syncthreads();             // drains DMA + guards buffer swap
        cur ^= 1;
    }

    float bv[4];
    #pragma unroll
    for (int fc = 0; fc < 4; ++fc) {
        const int col = n0 + wc + fc * 16 + l15;
        bv[fc] = (col < N) ? bias[col] : 0.f;
    }
    #pragma unroll
    for (int fr = 0; fr < 4; ++fr) {
        #pragma unroll
        for (int fc = 0; fc < 4; ++fc) {
            const int col = n0 + wc + fc * 16 + l15;
            #pragma unroll
            for (int j = 0; j < 4; ++j) {
                const int rowg = m0 + wr + fr * 16 + lg * 4 + j;
                float v = acc[fr][fc][j] + bv[fc];
                if (ACT == 1) v = fmaxf(v, 0.f);
                else if (ACT == 2) v = 1.f / (1.f + expf(-v));
                if (OUTMODE == 0) {
                    if (col < N) Cf32[(size_t)rowg * N + col] = v;
                } else {
                    const int kto = col >> 5;
                    if (kto < KTout) {
                        const int r = rowg & 127, k = col & 31;
                        const size_t off = ((size_t)byy * KTout + kto) * 4096
                                         + r * 32 + (((k >> 3) ^ (r & 3)) << 3) + (k & 7);
                        const unsigned short hb = f32_to_bf16_rn(v);
                        Cphi[off] = (short)hb;
                        if (OUTMODE == 2)
                            Cplo[off] = (short)f32_to_bf16_rn(v - bf16_bits_to_f32(hb));
                    }
                }
            }
        }
    }
}

// ============================ VQ MFMA + argmin ==============================
__global__ __launch_bounds__(512) void vq_mfma(
    const float* __restrict__ z_e, const short* __restrict__ planes,
    const double* __restrict__ wn_g, float* __restrict__ zq,
    short* __restrict__ zqh,
    int* __restrict__ flag_cnt, int* __restrict__ flag_ids)
{
    __shared__ short  Wsh[32768];
    __shared__ float  zsh[16 * 1024];
    __shared__ double wn_sh[128];
    __shared__ double cmb_v1[128][2];
    __shared__ double cmb_v2[128][2];
    __shared__ int    cmb_i[128][2];
    __shared__ int    idx_sh[128];
    __shared__ int    sflag[16];

    const int tid = threadIdx.x;
    const int b0  = blockIdx.x * 16;

    for (int c = tid; c < 4096; c += 512)
        *reinterpret_cast<int4*>(&Wsh[c * 8]) =
            *reinterpret_cast<const int4*>(&planes[c * 8]);
    for (int c = tid; c < 128; c += 512) wn_sh[c] = wn_g[c];
    for (int c = tid; c < 4096; c += 512) {
        const int D    = c * 16;
        const int s    = D >> 12;
        const int dr   = D & 4095;
        const int srcb = dr ^ (((dr >> 8) & 3) << 5);
        *reinterpret_cast<int4*>(reinterpret_cast<char*>(zsh) + D) =
            *reinterpret_cast<const int4*>(
                reinterpret_cast<const char*>(z_e) + (size_t)(b0 + s) * 4096 + srcb);
    }
    if (tid < 16) sflag[tid] = 0;
    __syncthreads();

    const int lane = tid & 63;
    const int w_id = tid >> 6;
    const int wr   = (w_id >> 1) * 32;
    const int wc   = (w_id & 1) * 64;
    const int l15  = lane & 15;
    const int lg   = lane >> 4;

    f32x4 acc[2][4];
    #pragma unroll
    for (int i = 0; i < 2; ++i)
        #pragma unroll
        for (int j = 0; j < 4; ++j) acc[i][j] = (f32x4){0.f, 0.f, 0.f, 0.f};

    #pragma unroll
    for (int ks = 0; ks < 4; ++ks) {
        bf16x8 bh[4], bl[4];
        #pragma unroll
        for (int cf = 0; cf < 4; ++cf) {
            const int n     = wc + cf * 16 + l15;
            const int slotp = (ks * 4 + lg) ^ (n & 7);
            const int off   = n * 128 + slotp * 8;
            bh[cf] = *reinterpret_cast<const bf16x8*>(&Wsh[off]);
            bl[cf] = *reinterpret_cast<const bf16x8*>(&Wsh[16384 + off]);
        }
        bf16x8 ah[2], al[2];
        #pragma unroll
        for (int rf = 0; rf < 2; ++rf) {
            const int row   = wr + rf * 16 + l15;
            const int s_loc = row >> 3;
            const int d     = row & 7;
            const int kb    = ks * 32 + lg * 8;
            const int xrr   = (lg & 3) << 5;
            const char* zb  = reinterpret_cast<const char*>(zsh) + s_loc * 4096;
            bf16x8 h8, L8;
            #pragma unroll
            for (int j = 0; j < 8; ++j) {
                const float a = *reinterpret_cast<const float*>(
                    zb + ((32 * (kb + j) + 4 * d) ^ xrr));
                const unsigned short hi = f32_to_bf16_rn(a);
                h8[j] = (short)hi;
                L8[j] = (short)f32_to_bf16_rn(a - bf16_bits_to_f32(hi));
            }
            ah[rf] = h8; al[rf] = L8;
        }
        #pragma unroll
        for (int rf = 0; rf < 2; ++rf)
            #pragma unroll
            for (int cf = 0; cf < 4; ++cf) {
                acc[rf][cf] = __builtin_amdgcn_mfma_f32_16x16x32_bf16(
                    ah[rf], bh[cf], acc[rf][cf], 0, 0, 0);
                acc[rf][cf] = __builtin_amdgcn_mfma_f32_16x16x32_bf16(
                    ah[rf], bl[cf], acc[rf][cf], 0, 0, 0);
                acc[rf][cf] = __builtin_amdgcn_mfma_f32_16x16x32_bf16(
                    al[rf], bh[cf], acc[rf][cf], 0, 0, 0);
            }
    }

    #pragma unroll
    for (int rf = 0; rf < 2; ++rf)
        #pragma unroll
        for (int j = 0; j < 4; ++j) {
            double v1 = 1e300, v2 = 1e300; int i1 = 0;
            #pragma unroll
            for (int cf = 0; cf < 4; ++cf) {
                const int n = wc + cf * 16 + l15;
                const double v = wn_sh[n] - 2.0 * (double)acc[rf][cf][j];
                if (v < v1)      { v2 = v1; v1 = v; i1 = n; }
                else if (v < v2) { v2 = v; }
            }
            #pragma unroll
            for (int off = 1; off < 16; off <<= 1) {
                const double ov1 = __shfl_xor(v1, off);
                const int    oi1 = __shfl_xor(i1, off);
                const double ov2 = __shfl_xor(v2, off);
                if (ov1 < v1 || (ov1 == v1 && oi1 < i1)) {
                    v2 = fmin(v1, ov2); v1 = ov1; i1 = oi1;
                } else {
                    v2 = fmin(v2, ov1);
                }
            }
            if (l15 == 0) {
                const int r = wr + rf * 16 + lg * 4 + j;
                cmb_v1[r][w_id & 1] = v1;
                cmb_v2[r][w_id & 1] = v2;
                cmb_i [r][w_id & 1] = i1;
            }
        }
    __syncthreads();

    if (tid < 128) {
        const double v1a = cmb_v1[tid][0], v1b = cmb_v1[tid][1];
        double v1, v2; int i1;
        if (v1b < v1a) { v1 = v1b; i1 = cmb_i[tid][1]; v2 = fmin(v1a, cmb_v2[tid][1]); }
        else           { v1 = v1a; i1 = cmb_i[tid][0]; v2 = fmin(v1b, cmb_v2[tid][0]); }
        idx_sh[tid] = i1;
        if (v2 - v1 < GAP_T) sflag[tid >> 3] = 1;
    }
    __syncthreads();
    if (tid < 16 && sflag[tid]) {
        const int p = atomicAdd(flag_cnt, 1);
        flag_ids[p] = b0 + tid;
    }

    for (int t = tid; t < 16384; t += 512) {
        const int s = t >> 10, i = t & 1023;
        const int k = i >> 3, d = i & 7;
        const int n = idx_sh[(s << 3) | d];
        const int off = n * 128 + (((k >> 3) ^ (n & 7)) << 3) + (k & 7);
        const float val = bf16_bits_to_f32((unsigned short)Wsh[off]) +
                          bf16_bits_to_f32((unsigned short)Wsh[16384 + off]);
        zq[(size_t)(b0 + s) * 1024 + i] = val;
        zqh[zq_plane_off(b0 + s, i)] = (short)f32_to_bf16_rn(val);
    }
}

// ================= fixup F1/F2: 64x64-tile f64 GEMM (NT) ===================
#define FLP 68
template<bool GATHER, bool SPLITK, bool FUSERED, typename TA>
__global__ __launch_bounds__(256) void gemm_f64t(
    const TA* __restrict__ A, const float* __restrict__ Wf,
    const int* __restrict__ ids, const int* __restrict__ cntp,
    const float* __restrict__ biasA, const float* __restrict__ bias,
    double* __restrict__ C,
    int AK, int N, int CN, int klen, int cap)
{
    __shared__ double As[16 * FLP];
    __shared__ double Ws[16 * FLP];

    const int tid = threadIdx.x;
    const int tx  = tid & 15;
    const int ty  = tid >> 4;
    const int m0  = blockIdx.y * 64;
    const int n0  = blockIdx.x * 64;
    const int cnt = (*cntp < cap) ? *cntp : cap;
    if (m0 >= cnt) return;

    const int k0 = SPLITK ? blockIdx.z * klen : 0;
    if (SPLITK) C += (size_t)blockIdx.z * cap * CN;

    const int srow = tid >> 2;
    const int sc4  = (tid & 3) << 2;

    const TA* arow;
    if (GATHER) {
        const int m  = m0 + srow;
        const int id = (m < cnt) ? ids[m] : 0;
        arow = A + (size_t)id * AK;
    } else {
        arow = A + (size_t)(m0 + srow) * AK;
    }
    const int   nrow = n0 + srow;
    const float* wrow = Wf + (size_t)(nrow < N ? nrow : 0) * AK;
    const bool  wok  = (nrow < N);

    double acc[4][4];
    #pragma unroll
    for (int i = 0; i < 4; ++i)
        #pragma unroll
        for (int j = 0; j < 4; ++j) acc[i][j] = 0.0;

    for (int kt = 0; kt < klen; kt += 16) {
        const int kb = k0 + kt + sc4;
        if constexpr (FUSERED) {
            const size_t cs = (size_t)cap * AK;
            #pragma unroll
            for (int e = 0; e < 4; ++e) {
                double s = (double)biasA[kb + e];
                #pragma unroll
                for (int c = 0; c < 6; ++c) s += arow[c * cs + kb + e];
                As[(sc4 + e) * FLP + srow] = s > 0.0 ? s : 0.0;
            }
        } else if constexpr (sizeof(TA) == 4) {
            const float4 v = *reinterpret_cast<const float4*>(&arow[kb]);
            As[(sc4 + 0) * FLP + srow] = (double)v.x;
            As[(sc4 + 1) * FLP + srow] = (double)v.y;
            As[(sc4 + 2) * FLP + srow] = (double)v.z;
            As[(sc4 + 3) * FLP + srow] = (double)v.w;
        } else {
            const double2 v0 = *reinterpret_cast<const double2*>(&arow[kb]);
            const double2 v1 = *reinterpret_cast<const double2*>(&arow[kb + 2]);
            As[(sc4 + 0) * FLP + srow] = v0.x;
            As[(sc4 + 1) * FLP + srow] = v0.y;
            As[(sc4 + 2) * FLP + srow] = v1.x;
            As[(sc4 + 3) * FLP + srow] = v1.y;
        }
        float4 w = make_float4(0.f, 0.f, 0.f, 0.f);
        if (wok) w = *reinterpret_cast<const float4*>(&wrow[kb]);
        Ws[(sc4 + 0) * FLP + srow] = (double)w.x;
        Ws[(sc4 + 1) * FLP + srow] = (double)w.y;
        Ws[(sc4 + 2) * FLP + srow] = (double)w.z;
        Ws[(sc4 + 3) * FLP + srow] = (double)w.w;
        __syncthreads();

        #pragma unroll
        for (int k = 0; k < 16; ++k) {
            const double2 A0 = *reinterpret_cast<const double2*>(&As[k * FLP + ty * 4]);
            const double2 A1 = *reinterpret_cast<const double2*>(&As[k * FLP + ty * 4 + 2]);
            const double2 B0 = *reinterpret_cast<const double2*>(&Ws[k * FLP + tx * 4]);
            const double2 B1 = *reinterpret_cast<const double2*>(&Ws[k * FLP + tx * 4 + 2]);
            const double a[4] = {A0.x, A0.y, A1.x, A1.y};
            const double b[4] = {B0.x, B0.y, B1.x, B1.y};
            #pragma unroll
            for (int i = 0; i < 4; ++i)
                #pragma unroll
                for (int j = 0; j < 4; ++j)
                    acc[i][j] = fma(a[i], b[j], acc[i][j]);
        }
        __syncthreads();
    }

    #pragma unroll
    for (int i = 0; i < 4; ++i) {
        const int row = m0 + ty * 4 + i;
        #pragma unroll
        for (int j = 0; j < 4; ++j) {
            const int col = n0 + tx * 4 + j;
            if (col < N)
                C[(size_t)row * CN + col] =
                    acc[i][j] + (bias ? (double)bias[col] : 0.0);
        }
    }
}

// ======= fixup F3: exact f64 distances + argmin + z_q scatter ===============
__global__ __launch_bounds__(512) void fix_argmin(
    const double* __restrict__ Zf, const float* __restrict__ Wemb,
    const int* __restrict__ cntp, const int* __restrict__ ids,
    float* __restrict__ zq, short* __restrict__ zqh, int cap)
{
    __shared__ float  wesh[16384];
    __shared__ double zsh[4][1032];
    __shared__ double dist[4 * 8 * 128];
    __shared__ int    idxf[32];

    const int tid  = threadIdx.x;
    const int lane = tid & 63;
    const int wv   = tid >> 6;
    const int cnt  = (*cntp < cap) ? *cntp : cap;
    const int base = blockIdx.x * 4;
    if (base >= cnt) return;
    const int ns = (cnt - base < 4) ? (cnt - base) : 4;

    for (int i = tid; i < 4096; i += 512)
        reinterpret_cast<float4*>(wesh)[i] =
            reinterpret_cast<const float4*>(Wemb)[i];
    for (int i = tid; i < 4 * 512; i += 512) {
        const int s = i >> 9, e = (i & 511) * 2;
        if (s < ns) {
            const double2 v = *reinterpret_cast<const double2*>(
                &Zf[(size_t)(base + s) * 1024 + e]);
            zsh[s][e] = v.x;
            zsh[s][e + 1] = v.y;
        }
    }
    __syncthreads();

    for (int t = tid; t < ns * 1024; t += 512) {
        const int s = t >> 10, d = (t >> 7) & 7, n = t & 127;
        double acc = 0.0;
        for (int k = 0; k < 128; ++k) {
            const double diff = zsh[s][k * 8 + d] - (double)wesh[k * 128 + n];
            acc = fma(diff, diff, acc);
        }
        dist[(s * 8 + d) * 128 + n] = acc;
    }
    __syncthreads();

    for (int p = wv; p < ns * 8; p += 8) {
        const double* dp = &dist[p * 128];
        double v0 = dp[lane], vx = dp[lane + 64];
        double v; int ix;
        if (vx < v0) { v = vx; ix = lane + 64; }
        else         { v = v0; ix = lane; }
        #pragma unroll
        for (int off = 32; off > 0; off >>= 1) {
            const double ov = __shfl_down(v, off);
            const int    oi = __shfl_down(ix, off);
            if (ov < v || (ov == v && oi < ix)) { v = ov; ix = oi; }
        }
        if (lane == 0) idxf[p] = ix;
    }
    __syncthreads();

    for (int i = tid; i < ns * 1024; i += 512) {
        const int s = i >> 10, ii = i & 1023;
        const int id = ids[base + s];
        const float val = wesh[(ii >> 3) * 128 + idxf[s * 8 + (ii & 7)]];
        zq[(size_t)id * 1024 + ii] = val;
        zqh[zq_plane_off(id, ii)] = (short)f32_to_bf16_rn(val);
    }
}

// ---------------------------------------------------------------------------
extern "C" void kernel_launch(void* const* d_in, const int* in_sizes, int n_in,
                              void* d_out, int out_size, void* d_ws, size_t ws_size,
                              hipStream_t stream)
{
    const float* x    = (const float*)d_in[0];
    const float* W1   = (const float*)d_in[1];
    const float* b1   = (const float*)d_in[2];
    const float* W2   = (const float*)d_in[3];
    const float* b2   = (const float*)d_in[4];
    const float* W3   = (const float*)d_in[5];
    const float* b3   = (const float*)d_in[6];
    const float* W4   = (const float*)d_in[7];
    const float* b4   = (const float*)d_in[8];
    const float* Wemb = (const float*)d_in[9];

    const int B = 16384;
    float* out   = (float*)d_out;
    float* recon = out;                                // B*3072
    float* z_e   = out + (size_t)B * 3072;             // B*1024
    float* emb_o = z_e + (size_t)B * 1024;             // B*1024 == z_q

    constexpr size_t H1_PL = 6815744;
    constexpr size_t H3_PL = 6815744;
    constexpr size_t W1_PL = 1572864;
    constexpr size_t W2_PL = 425984;
    constexpr size_t W3_PL = 524288;
    constexpr size_t W4_PL = 1277952;

    short* h1h = (short*)emb_o;          // h1 planes in emb_o section
    short* h1l = h1h + H1_PL;

    short*  h3h      = (short*)d_ws;
    short*  w1h      = h3h + H3_PL;
    short*  w1l      = w1h + W1_PL;
    short*  w2h      = w1l + W1_PL;
    short*  w2l      = w2h + W2_PL;
    short*  w3h      = w2l + W2_PL;
    short*  w4h      = w3h + W3_PL;
    short*  wembpl   = w4h + W4_PL;
    double* wn       = (double*)(wembpl + 32768);
    int*    flag_cnt = (int*)(wn + 128);
    int*    flag_ids = flag_cnt + 64;

    // recon-section scratch (dead until g4 writes recon last):
    // Part[6] @ +0 (78.6MB), Zf @ +96MB (33.5MB), zqh plane @ +144MB (33.5MB)
    char*   scr  = (char*)recon;
    double* Part = (double*)scr;
    double* Zf   = (double*)(scr + (96ull  << 20));
    short*  zqh  = (short*) (scr + (144ull << 20));

    // ---- prep (W planes | VQ prep) ----
    prep_all<<<dim3(929), dim3(256), 0, stream>>>(
        W1, W2, W3, W4, Wemb, w1h, w1l, w2h, w2l, w3h, w4h,
        wembpl, wn, flag_cnt);

    // ---- encoder ----
    // g1: A = x f32, in-loop trunc split, XCD-grouped block map (grid 512)
    gemm_pl<2, 1, 1, 2, true><<<dim3(512), dim3(256), 0, stream>>>(
        nullptr, nullptr, x, 3072, w1h, w1l, b1, nullptr, h1h, h1l, 400, 96, 13);
    gemm_pl<2, 0, 0, 0, false><<<dim3(8, 128), dim3(256), 0, stream>>>(
        h1h, h1l, nullptr, 0, w2h, w2l, b2, z_e, nullptr, nullptr, 1024, 13, 0);

    // ---- VQ + fixup ----
    vq_mfma<<<dim3(1024), dim3(512), 0, stream>>>(z_e, wembpl, wn, emb_o, zqh,
                                                  flag_cnt, flag_ids);
    gemm_f64t<true, true, false, float><<<dim3(7, FIX_CAP / 64, 6), dim3(256), 0, stream>>>(
        x, W1, flag_ids, flag_cnt, nullptr, nullptr, Part, 3072, 400, 400, 512, FIX_CAP);
    gemm_f64t<false, false, true, double><<<dim3(16, FIX_CAP / 64), dim3(256), 0, stream>>>(
        Part, W2, nullptr, flag_cnt, b1, b2, Zf, 400, 1024, 1024, 400, FIX_CAP);
    fix_argmin<<<dim3(FIX_CAP / 4), dim3(512), 0, stream>>>(
        Zf, Wemb, flag_cnt, flag_ids, emb_o, zqh, FIX_CAP);

    // ---- decoder ----
    gemm_pl<1, 1, 0, 1, false><<<dim3(4, 128), dim3(256), 0, stream>>>(
        zqh, nullptr, nullptr, 0, w3h, nullptr, b3, nullptr, h3h, nullptr,
        400, 32, 13);
    gemm_pl<1, 2, 0, 0, false><<<dim3(24, 128), dim3(256), 0, stream>>>(
        h3h, nullptr, nullptr, 0, w4h, nullptr, b4, recon, nullptr, nullptr,
        3072, 13, 0);
}

// Round 14
// 625.673 us; speedup vs baseline: 1.2623x; 1.0221x over previous
//
#include <hip/hip_runtime.h>
#include <math.h>

// ---------------------------------------------------------------------------
// VQ-VAE forward on MI355X — round 14: vq_mfma occupancy fix. Codebook planes
// no longer staged in LDS (64KB): B fragments + scatter values read straight
// from the global plane buffer (L2-resident, same swizzled offsets, same
// bytes). LDS 134->72KB => 2 blocks/CU (was 1). All else = round 13.
//   g1: h1 = relu(x @ W1^T + b1)        [A: f32 x, in-loop trunc split,
//                                        XCD-grouped map; B: W1 planes]
//   g2: z_e = h1 @ W2^T + b2            [planes -> f32 z_e output]
//   vq_mfma: MFMA dots + top-2 argmin + gap flag; writes z_q f32 + bf16 plane
//   fixup: F1 Part[c]=gatherX@W1^T (f64) | F2 Zf=relu(ΣPart+b1)@W2^T+b2 | F3
//   g3: h3 = relu(z_q @ W3^T + b3)      [z_q plane -> h3 hi plane]
//   g4: recon = sigmoid(h3 @ W4^T + b4) [planes -> f32 recon]
// ---------------------------------------------------------------------------

typedef short bf16x8 __attribute__((ext_vector_type(8)));
typedef short short8 __attribute__((ext_vector_type(8)));
typedef float f32x4  __attribute__((ext_vector_type(4)));

#define GAP_T   2e-4
#define FIX_CAP 4096

__device__ __forceinline__ unsigned short f32_to_bf16_rn(float v) {
    union { float f; unsigned u; } c; c.f = v;
    unsigned r = c.u + 0x7FFFu + ((c.u >> 16) & 1u);
    return (unsigned short)(r >> 16);
}
__device__ __forceinline__ float bf16_bits_to_f32(unsigned short b) {
    union { unsigned u; float f; } c; c.u = ((unsigned)b) << 16;
    return c.f;
}
__device__ __forceinline__ void glds16(const short* g, short* l) {
    __builtin_amdgcn_global_load_lds(
        (const __attribute__((address_space(1))) unsigned int*)g,
        (__attribute__((address_space(3))) unsigned int*)l, 16, 0, 0);
}
__device__ __forceinline__ size_t zq_plane_off(int id, int ii) {
    const int mb = id >> 7, r = id & 127;
    const int kt = ii >> 5, kc = ii & 31;
    return ((size_t)(mb * 32 + kt) * 4096)
         + r * 32 + (((kc >> 3) ^ (r & 3)) << 3) + (kc & 7);
}

// ================== merged prep: W planes + VQ prep =========================
__global__ __launch_bounds__(256) void prep_all(
    const float* __restrict__ W1, const float* __restrict__ W2,
    const float* __restrict__ W3, const float* __restrict__ W4,
    const float* __restrict__ Wemb,
    short* __restrict__ w1h, short* __restrict__ w1l,
    short* __restrict__ w2h, short* __restrict__ w2l,
    short* __restrict__ w3h, short* __restrict__ w4h,
    short* __restrict__ wembpl, double* __restrict__ wn,
    int* __restrict__ flag_cnt)
{
    const int tid = threadIdx.x;
    const int bid = blockIdx.x;

    if (bid < 928) {     // -------- weight planes --------
        const float* Wsrc; int N, K, KT, local; short *hi, *lo;
        if (bid < 384)      { Wsrc = W1; N = 400;  K = 3072; KT = 96; local = bid;       hi = w1h; lo = w1l; }
        else if (bid < 488) { Wsrc = W2; N = 1024; K = 400;  KT = 13; local = bid - 384; hi = w2h; lo = w2l; }
        else if (bid < 616) { Wsrc = W3; N = 400;  K = 1024; KT = 32; local = bid - 488; hi = w3h; lo = nullptr; }
        else                { Wsrc = W4; N = 3072; K = 400;  KT = 13; local = bid - 616; hi = w4h; lo = nullptr; }

        const int kt = local % KT;
        const int nb = local / KT;
        const size_t tb = (size_t)local * 4096;
        for (int ci = tid; ci < 512; ci += 256) {
            const int row = ci >> 2;
            const int sl  = ci & 3;
            const int k0  = ((sl ^ (row & 3)) << 3);
            const int n   = nb * 128 + row;
            const int kk  = kt * 32 + k0;
            float f[8];
            #pragma unroll
            for (int e = 0; e < 8; ++e)
                f[e] = (n < N && kk + e < K) ? Wsrc[(size_t)n * K + kk + e] : 0.f;
            short8 h, l;
            #pragma unroll
            for (int e = 0; e < 8; ++e) {
                const unsigned short hb = f32_to_bf16_rn(f[e]);
                h[e] = (short)hb;
                l[e] = (short)f32_to_bf16_rn(f[e] - bf16_bits_to_f32(hb));
            }
            *reinterpret_cast<short8*>(&hi[tb + ci * 8]) = h;
            if (lo) *reinterpret_cast<short8*>(&lo[tb + ci * 8]) = l;
        }
        return;
    }

    // -------- VQ prep (single block) --------
    if (tid == 0) *flag_cnt = 0;
    if (tid < 128) {
        double s = 0.0;
        for (int k = 0; k < 128; ++k) {
            const double w = (double)Wemb[k * 128 + tid];
            s = fma(w, w, s);
        }
        wn[tid] = s;
    }
    for (int t = tid; t < 16384; t += 256) {
        const int k = t >> 7, n = t & 127;
        const float w = Wemb[t];
        const unsigned short hi = f32_to_bf16_rn(w);
        const unsigned short lo = f32_to_bf16_rn(w - bf16_bits_to_f32(hi));
        const int off = n * 128 + (((k >> 3) ^ (n & 7)) << 3) + (k & 7);
        wembpl[off]         = (short)hi;
        wembpl[16384 + off] = (short)lo;
    }
}

// ====================== plane-fed MFMA GEMM (NT), 2-phase ===================
// AMODE: 0 = A from planes (glds); 1 = A from f32 row-major, trunc hi/lo
//        split in-loop (issue loads early, convert+ds_write late; NSPLIT=2)
// OUTMODE: 0 f32 C; 1 hi plane; 2 hi+lo planes
// XCDMAP: 1D grid 512, xcd-grouped decode (g1 only)
template<int NSPLIT, int ACT, int AMODE, int OUTMODE, bool XCDMAP>
__global__ __launch_bounds__(256) void gemm_pl(
    const short* __restrict__ Ahi, const short* __restrict__ Alo,
    const float* __restrict__ Af32, int AK,
    const short* __restrict__ Bhi, const short* __restrict__ Blo,
    const float* __restrict__ bias,
    float* __restrict__ Cf32, short* __restrict__ Cphi, short* __restrict__ Cplo,
    int N, int KT, int KTout)
{
    __shared__ short lds[2 * NSPLIT * 2 * 4096];   // double-buffered

    const int tid  = threadIdx.x;
    const int lane = tid & 63;
    const int w_id = tid >> 6;
    const int wr   = (w_id >> 1) * 64;
    const int wc   = (w_id & 1)  * 64;

    int bx, byy;
    if constexpr (XCDMAP) {          // grid 512: by = xcd*16 + (g>>2), bx = g&3
        const int bid = blockIdx.x;
        const int xcd = bid & 7, g = bid >> 3;
        byy = xcd * 16 + (g >> 2);
        bx  = g & 3;
    } else {
        bx = blockIdx.x; byy = blockIdx.y;
    }
    const int m0   = byy * 128;
    const int n0   = bx * 128;
    const int l15  = lane & 15;
    const int lg   = lane >> 4;
    constexpr int BUF = NSPLIT * 2 * 4096;

    f32x4 acc[4][4];
    #pragma unroll
    for (int i = 0; i < 4; ++i)
        #pragma unroll
        for (int j = 0; j < 4; ++j) acc[i][j] = (f32x4){0.f, 0.f, 0.f, 0.f};

    float xr[AMODE == 1 ? 16 : 1];   // reg-staged A tile (AMODE=1)

    auto loadA = [&](int kt) {       // issue-early f32 x loads
        #pragma unroll
        for (int i = 0; i < 2; ++i) {
            const int ci  = tid + i * 256;
            const int row = ci >> 2;
            const int sl  = ci & 3;
            const int k0  = ((sl ^ (row & 3)) << 3);
            const float* src = &Af32[(size_t)(m0 + row) * AK + kt * 32 + k0];
            const float4 f0 = *reinterpret_cast<const float4*>(src);
            const float4 f1 = *reinterpret_cast<const float4*>(src + 4);
            xr[i * 8 + 0] = f0.x; xr[i * 8 + 1] = f0.y;
            xr[i * 8 + 2] = f0.z; xr[i * 8 + 3] = f0.w;
            xr[i * 8 + 4] = f1.x; xr[i * 8 + 5] = f1.y;
            xr[i * 8 + 6] = f1.z; xr[i * 8 + 7] = f1.w;
        }
    };
    auto writeA = [&](int buf) {     // write-late: trunc hi + rn lo
        short* L = &lds[buf * BUF];
        #pragma unroll
        for (int i = 0; i < 2; ++i) {
            const int ci = tid + i * 256;
            short8 h, l;
            #pragma unroll
            for (int e = 0; e < 8; ++e) {
                const float v = xr[i * 8 + e];
                const unsigned u = __float_as_uint(v);
                const float hf = __uint_as_float(u & 0xFFFF0000u);
                h[e] = (short)(u >> 16);                    // hi = trunc-bf16
                l[e] = (short)f32_to_bf16_rn(v - hf);       // exact residual
            }
            *reinterpret_cast<short8*>(&L[ci * 8])        = h;
            *reinterpret_cast<short8*>(&L[4096 + ci * 8]) = l;
        }
    };
    auto stageGL = [&](int buf, int kt) {
        short* L = &lds[buf * BUF];
        const size_t bt = ((size_t)bx * KT + kt) * 4096;
        #pragma unroll
        for (int q = 0; q < 2; ++q) {
            const int o = (w_id * 2 + q) * 512 + lane * 8;
            if (AMODE == 0) {
                const size_t at = ((size_t)byy * KT + kt) * 4096;
                glds16(Ahi + at + o, &L[o]);
                if (NSPLIT > 1) glds16(Alo + at + o, &L[4096 + o]);
            }
            glds16(Bhi + bt + o, &L[NSPLIT * 4096 + o]);
            if (NSPLIT > 1) glds16(Blo + bt + o, &L[(NSPLIT + 1) * 4096 + o]);
        }
    };

    // ---- prologue: fill buffer 0 ----
    if (AMODE == 1) loadA(0);
    stageGL(0, 0);
    if (AMODE == 1) writeA(0);
    __syncthreads();

    int cur = 0;
    for (int kt = 0; kt < KT; ++kt) {
        if (kt + 1 < KT) {
            if (AMODE == 1) loadA(kt + 1);     // x loads in flight during MFMA
            stageGL(cur ^ 1, kt + 1);          // DMA in flight during MFMA
        }

        const short* L = &lds[cur * BUF];
        bf16x8 bfr[4][NSPLIT];
        #pragma unroll
        for (int fc = 0; fc < 4; ++fc) {
            const int rn  = wc + fc * 16 + l15;
            const int idx = rn * 32 + ((lg ^ (rn & 3)) << 3);
            #pragma unroll
            for (int s = 0; s < NSPLIT; ++s)
                bfr[fc][s] = *reinterpret_cast<const bf16x8*>(&L[(NSPLIT + s) * 4096 + idx]);
        }
        #pragma unroll
        for (int fr = 0; fr < 4; ++fr) {
            const int rm  = wr + fr * 16 + l15;
            const int idx = rm * 32 + ((lg ^ (rm & 3)) << 3);
            const bf16x8 a0 = *reinterpret_cast<const bf16x8*>(&L[idx]);
            bf16x8 a1;
            if (NSPLIT > 1)
                a1 = *reinterpret_cast<const bf16x8*>(&L[4096 + idx]);
            #pragma unroll
            for (int fc = 0; fc < 4; ++fc) {
                acc[fr][fc] = __builtin_amdgcn_mfma_f32_16x16x32_bf16(
                    a0, bfr[fc][0], acc[fr][fc], 0, 0, 0);
                if (NSPLIT > 1) {
                    acc[fr][fc] = __builtin_amdgcn_mfma_f32_16x16x32_bf16(
                        a0, bfr[fc][1], acc[fr][fc], 0, 0, 0);
                    acc[fr][fc] = __builtin_amdgcn_mfma_f32_16x16x32_bf16(
                        a1, bfr[fc][0], acc[fr][fc], 0, 0, 0);
                }
            }
        }

        if (AMODE == 1 && kt + 1 < KT) writeA(cur ^ 1);   // write-late
        __syncthreads();             // drains DMA + guards buffer swap
        cur ^= 1;
    }

    float bv[4];
    #pragma unroll
    for (int fc = 0; fc < 4; ++fc) {
        const int col = n0 + wc + fc * 16 + l15;
        bv[fc] = (col < N) ? bias[col] : 0.f;
    }
    #pragma unroll
    for (int fr = 0; fr < 4; ++fr) {
        #pragma unroll
        for (int fc = 0; fc < 4; ++fc) {
            const int col = n0 + wc + fc * 16 + l15;
            #pragma unroll
            for (int j = 0; j < 4; ++j) {
                const int rowg = m0 + wr + fr * 16 + lg * 4 + j;
                float v = acc[fr][fc][j] + bv[fc];
                if (ACT == 1) v = fmaxf(v, 0.f);
                else if (ACT == 2) v = 1.f / (1.f + expf(-v));
                if (OUTMODE == 0) {
                    if (col < N) Cf32[(size_t)rowg * N + col] = v;
                } else {
                    const int kto = col >> 5;
                    if (kto < KTout) {
                        const int r = rowg & 127, k = col & 31;
                        const size_t off = ((size_t)byy * KTout + kto) * 4096
                                         + r * 32 + (((k >> 3) ^ (r & 3)) << 3) + (k & 7);
                        const unsigned short hb = f32_to_bf16_rn(v);
                        Cphi[off] = (short)hb;
                        if (OUTMODE == 2)
                            Cplo[off] = (short)f32_to_bf16_rn(v - bf16_bits_to_f32(hb));
                    }
                }
            }
        }
    }
}

// ============================ VQ MFMA + argmin ==============================
// Round-14: codebook planes read directly from global (L2-resident, same
// swizzled offsets); LDS = z rows only (72KB) -> 2 blocks/CU.
__global__ __launch_bounds__(512) void vq_mfma(
    const float* __restrict__ z_e, const short* __restrict__ planes,
    const double* __restrict__ wn_g, float* __restrict__ zq,
    short* __restrict__ zqh,
    int* __restrict__ flag_cnt, int* __restrict__ flag_ids)
{
    __shared__ float  zsh[16 * 1024];   // 64KB
    __shared__ double wn_sh[128];
    __shared__ double cmb_v1[128][2];
    __shared__ double cmb_v2[128][2];
    __shared__ int    cmb_i[128][2];
    __shared__ int    idx_sh[128];
    __shared__ int    sflag[16];

    const int tid = threadIdx.x;
    const int b0  = blockIdx.x * 16;

    for (int c = tid; c < 128; c += 512) wn_sh[c] = wn_g[c];
    for (int c = tid; c < 4096; c += 512) {
        const int D    = c * 16;
        const int s    = D >> 12;
        const int dr   = D & 4095;
        const int srcb = dr ^ (((dr >> 8) & 3) << 5);
        *reinterpret_cast<int4*>(reinterpret_cast<char*>(zsh) + D) =
            *reinterpret_cast<const int4*>(
                reinterpret_cast<const char*>(z_e) + (size_t)(b0 + s) * 4096 + srcb);
    }
    if (tid < 16) sflag[tid] = 0;
    __syncthreads();

    const int lane = tid & 63;
    const int w_id = tid >> 6;
    const int wr   = (w_id >> 1) * 32;
    const int wc   = (w_id & 1) * 64;
    const int l15  = lane & 15;
    const int lg   = lane >> 4;

    f32x4 acc[2][4];
    #pragma unroll
    for (int i = 0; i < 2; ++i)
        #pragma unroll
        for (int j = 0; j < 4; ++j) acc[i][j] = (f32x4){0.f, 0.f, 0.f, 0.f};

    #pragma unroll
    for (int ks = 0; ks < 4; ++ks) {
        bf16x8 bh[4], bl[4];
        #pragma unroll
        for (int cf = 0; cf < 4; ++cf) {
            const int n     = wc + cf * 16 + l15;
            const int slotp = (ks * 4 + lg) ^ (n & 7);
            const int off   = n * 128 + slotp * 8;
            bh[cf] = *reinterpret_cast<const bf16x8*>(&planes[off]);
            bl[cf] = *reinterpret_cast<const bf16x8*>(&planes[16384 + off]);
        }
        bf16x8 ah[2], al[2];
        #pragma unroll
        for (int rf = 0; rf < 2; ++rf) {
            const int row   = wr + rf * 16 + l15;
            const int s_loc = row >> 3;
            const int d     = row & 7;
            const int kb    = ks * 32 + lg * 8;
            const int xrr   = (lg & 3) << 5;
            const char* zb  = reinterpret_cast<const char*>(zsh) + s_loc * 4096;
            bf16x8 h8, L8;
            #pragma unroll
            for (int j = 0; j < 8; ++j) {
                const float a = *reinterpret_cast<const float*>(
                    zb + ((32 * (kb + j) + 4 * d) ^ xrr));
                const unsigned short hi = f32_to_bf16_rn(a);
                h8[j] = (short)hi;
                L8[j] = (short)f32_to_bf16_rn(a - bf16_bits_to_f32(hi));
            }
            ah[rf] = h8; al[rf] = L8;
        }
        #pragma unroll
        for (int rf = 0; rf < 2; ++rf)
            #pragma unroll
            for (int cf = 0; cf < 4; ++cf) {
                acc[rf][cf] = __builtin_amdgcn_mfma_f32_16x16x32_bf16(
                    ah[rf], bh[cf], acc[rf][cf], 0, 0, 0);
                acc[rf][cf] = __builtin_amdgcn_mfma_f32_16x16x32_bf16(
                    ah[rf], bl[cf], acc[rf][cf], 0, 0, 0);
                acc[rf][cf] = __builtin_amdgcn_mfma_f32_16x16x32_bf16(
                    al[rf], bh[cf], acc[rf][cf], 0, 0, 0);
            }
    }

    #pragma unroll
    for (int rf = 0; rf < 2; ++rf)
        #pragma unroll
        for (int j = 0; j < 4; ++j) {
            double v1 = 1e300, v2 = 1e300; int i1 = 0;
            #pragma unroll
            for (int cf = 0; cf < 4; ++cf) {
                const int n = wc + cf * 16 + l15;
                const double v = wn_sh[n] - 2.0 * (double)acc[rf][cf][j];
                if (v < v1)      { v2 = v1; v1 = v; i1 = n; }
                else if (v < v2) { v2 = v; }
            }
            #pragma unroll
            for (int off = 1; off < 16; off <<= 1) {
                const double ov1 = __shfl_xor(v1, off);
                const int    oi1 = __shfl_xor(i1, off);
                const double ov2 = __shfl_xor(v2, off);
                if (ov1 < v1 || (ov1 == v1 && oi1 < i1)) {
                    v2 = fmin(v1, ov2); v1 = ov1; i1 = oi1;
                } else {
                    v2 = fmin(v2, ov1);
                }
            }
            if (l15 == 0) {
                const int r = wr + rf * 16 + lg * 4 + j;
                cmb_v1[r][w_id & 1] = v1;
                cmb_v2[r][w_id & 1] = v2;
                cmb_i [r][w_id & 1] = i1;
            }
        }
    __syncthreads();

    if (tid < 128) {
        const double v1a = cmb_v1[tid][0], v1b = cmb_v1[tid][1];
        double v1, v2; int i1;
        if (v1b < v1a) { v1 = v1b; i1 = cmb_i[tid][1]; v2 = fmin(v1a, cmb_v2[tid][1]); }
        else           { v1 = v1a; i1 = cmb_i[tid][0]; v2 = fmin(v1b, cmb_v2[tid][0]); }
        idx_sh[tid] = i1;
        if (v2 - v1 < GAP_T) sflag[tid >> 3] = 1;
    }
    __syncthreads();
    if (tid < 16 && sflag[tid]) {
        const int p = atomicAdd(flag_cnt, 1);
        flag_ids[p] = b0 + tid;
    }

    for (int t = tid; t < 16384; t += 512) {
        const int s = t >> 10, i = t & 1023;
        const int k = i >> 3, d = i & 7;
        const int n = idx_sh[(s << 3) | d];
        const int off = n * 128 + (((k >> 3) ^ (n & 7)) << 3) + (k & 7);
        const float val = bf16_bits_to_f32((unsigned short)planes[off]) +
                          bf16_bits_to_f32((unsigned short)planes[16384 + off]);
        zq[(size_t)(b0 + s) * 1024 + i] = val;
        zqh[zq_plane_off(b0 + s, i)] = (short)f32_to_bf16_rn(val);
    }
}

// ================= fixup F1/F2: 64x64-tile f64 GEMM (NT) ===================
#define FLP 68
template<bool GATHER, bool SPLITK, bool FUSERED, typename TA>
__global__ __launch_bounds__(256) void gemm_f64t(
    const TA* __restrict__ A, const float* __restrict__ Wf,
    const int* __restrict__ ids, const int* __restrict__ cntp,
    const float* __restrict__ biasA, const float* __restrict__ bias,
    double* __restrict__ C,
    int AK, int N, int CN, int klen, int cap)
{
    __shared__ double As[16 * FLP];
    __shared__ double Ws[16 * FLP];

    const int tid = threadIdx.x;
    const int tx  = tid & 15;
    const int ty  = tid >> 4;
    const int m0  = blockIdx.y * 64;
    const int n0  = blockIdx.x * 64;
    const int cnt = (*cntp < cap) ? *cntp : cap;
    if (m0 >= cnt) return;

    const int k0 = SPLITK ? blockIdx.z * klen : 0;
    if (SPLITK) C += (size_t)blockIdx.z * cap * CN;

    const int srow = tid >> 2;
    const int sc4  = (tid & 3) << 2;

    const TA* arow;
    if (GATHER) {
        const int m  = m0 + srow;
        const int id = (m < cnt) ? ids[m] : 0;
        arow = A + (size_t)id * AK;
    } else {
        arow = A + (size_t)(m0 + srow) * AK;
    }
    const int   nrow = n0 + srow;
    const float* wrow = Wf + (size_t)(nrow < N ? nrow : 0) * AK;
    const bool  wok  = (nrow < N);

    double acc[4][4];
    #pragma unroll
    for (int i = 0; i < 4; ++i)
        #pragma unroll
        for (int j = 0; j < 4; ++j) acc[i][j] = 0.0;

    for (int kt = 0; kt < klen; kt += 16) {
        const int kb = k0 + kt + sc4;
        if constexpr (FUSERED) {
            const size_t cs = (size_t)cap * AK;
            #pragma unroll
            for (int e = 0; e < 4; ++e) {
                double s = (double)biasA[kb + e];
                #pragma unroll
                for (int c = 0; c < 6; ++c) s += arow[c * cs + kb + e];
                As[(sc4 + e) * FLP + srow] = s > 0.0 ? s : 0.0;
            }
        } else if constexpr (sizeof(TA) == 4) {
            const float4 v = *reinterpret_cast<const float4*>(&arow[kb]);
            As[(sc4 + 0) * FLP + srow] = (double)v.x;
            As[(sc4 + 1) * FLP + srow] = (double)v.y;
            As[(sc4 + 2) * FLP + srow] = (double)v.z;
            As[(sc4 + 3) * FLP + srow] = (double)v.w;
        } else {
            const double2 v0 = *reinterpret_cast<const double2*>(&arow[kb]);
            const double2 v1 = *reinterpret_cast<const double2*>(&arow[kb + 2]);
            As[(sc4 + 0) * FLP + srow] = v0.x;
            As[(sc4 + 1) * FLP + srow] = v0.y;
            As[(sc4 + 2) * FLP + srow] = v1.x;
            As[(sc4 + 3) * FLP + srow] = v1.y;
        }
        float4 w = make_float4(0.f, 0.f, 0.f, 0.f);
        if (wok) w = *reinterpret_cast<const float4*>(&wrow[kb]);
        Ws[(sc4 + 0) * FLP + srow] = (double)w.x;
        Ws[(sc4 + 1) * FLP + srow] = (double)w.y;
        Ws[(sc4 + 2) * FLP + srow] = (double)w.z;
        Ws[(sc4 + 3) * FLP + srow] = (double)w.w;
        __syncthreads();

        #pragma unroll
        for (int k = 0; k < 16; ++k) {
            const double2 A0 = *reinterpret_cast<const double2*>(&As[k * FLP + ty * 4]);
            const double2 A1 = *reinterpret_cast<const double2*>(&As[k * FLP + ty * 4 + 2]);
            const double2 B0 = *reinterpret_cast<const double2*>(&Ws[k * FLP + tx * 4]);
            const double2 B1 = *reinterpret_cast<const double2*>(&Ws[k * FLP + tx * 4 + 2]);
            const double a[4] = {A0.x, A0.y, A1.x, A1.y};
            const double b[4] = {B0.x, B0.y, B1.x, B1.y};
            #pragma unroll
            for (int i = 0; i < 4; ++i)
                #pragma unroll
                for (int j = 0; j < 4; ++j)
                    acc[i][j] = fma(a[i], b[j], acc[i][j]);
        }
        __syncthreads();
    }

    #pragma unroll
    for (int i = 0; i < 4; ++i) {
        const int row = m0 + ty * 4 + i;
        #pragma unroll
        for (int j = 0; j < 4; ++j) {
            const int col = n0 + tx * 4 + j;
            if (col < N)
                C[(size_t)row * CN + col] =
                    acc[i][j] + (bias ? (double)bias[col] : 0.0);
        }
    }
}

// ======= fixup F3: exact f64 distances + argmin + z_q scatter ===============
__global__ __launch_bounds__(512) void fix_argmin(
    const double* __restrict__ Zf, const float* __restrict__ Wemb,
    const int* __restrict__ cntp, const int* __restrict__ ids,
    float* __restrict__ zq, short* __restrict__ zqh, int cap)
{
    __shared__ float  wesh[16384];
    __shared__ double zsh[4][1032];
    __shared__ double dist[4 * 8 * 128];
    __shared__ int    idxf[32];

    const int tid  = threadIdx.x;
    const int lane = tid & 63;
    const int wv   = tid >> 6;
    const int cnt  = (*cntp < cap) ? *cntp : cap;
    const int base = blockIdx.x * 4;
    if (base >= cnt) return;
    const int ns = (cnt - base < 4) ? (cnt - base) : 4;

    for (int i = tid; i < 4096; i += 512)
        reinterpret_cast<float4*>(wesh)[i] =
            reinterpret_cast<const float4*>(Wemb)[i];
    for (int i = tid; i < 4 * 512; i += 512) {
        const int s = i >> 9, e = (i & 511) * 2;
        if (s < ns) {
            const double2 v = *reinterpret_cast<const double2*>(
                &Zf[(size_t)(base + s) * 1024 + e]);
            zsh[s][e] = v.x;
            zsh[s][e + 1] = v.y;
        }
    }
    __syncthreads();

    for (int t = tid; t < ns * 1024; t += 512) {
        const int s = t >> 10, d = (t >> 7) & 7, n = t & 127;
        double acc = 0.0;
        for (int k = 0; k < 128; ++k) {
            const double diff = zsh[s][k * 8 + d] - (double)wesh[k * 128 + n];
            acc = fma(diff, diff, acc);
        }
        dist[(s * 8 + d) * 128 + n] = acc;
    }
    __syncthreads();

    for (int p = wv; p < ns * 8; p += 8) {
        const double* dp = &dist[p * 128];
        double v0 = dp[lane], vx = dp[lane + 64];
        double v; int ix;
        if (vx < v0) { v = vx; ix = lane + 64; }
        else         { v = v0; ix = lane; }
        #pragma unroll
        for (int off = 32; off > 0; off >>= 1) {
            const double ov = __shfl_down(v, off);
            const int    oi = __shfl_down(ix, off);
            if (ov < v || (ov == v && oi < ix)) { v = ov; ix = oi; }
        }
        if (lane == 0) idxf[p] = ix;
    }
    __syncthreads();

    for (int i = tid; i < ns * 1024; i += 512) {
        const int s = i >> 10, ii = i & 1023;
        const int id = ids[base + s];
        const float val = wesh[(ii >> 3) * 128 + idxf[s * 8 + (ii & 7)]];
        zq[(size_t)id * 1024 + ii] = val;
        zqh[zq_plane_off(id, ii)] = (short)f32_to_bf16_rn(val);
    }
}

// ---------------------------------------------------------------------------
extern "C" void kernel_launch(void* const* d_in, const int* in_sizes, int n_in,
                              void* d_out, int out_size, void* d_ws, size_t ws_size,
                              hipStream_t stream)
{
    const float* x    = (const float*)d_in[0];
    const float* W1   = (const float*)d_in[1];
    const float* b1   = (const float*)d_in[2];
    const float* W2   = (const float*)d_in[3];
    const float* b2   = (const float*)d_in[4];
    const float* W3   = (const float*)d_in[5];
    const float* b3   = (const float*)d_in[6];
    const float* W4   = (const float*)d_in[7];
    const float* b4   = (const float*)d_in[8];
    const float* Wemb = (const float*)d_in[9];

    const int B = 16384;
    float* out   = (float*)d_out;
    float* recon = out;                                // B*3072
    float* z_e   = out + (size_t)B * 3072;             // B*1024
    float* emb_o = z_e + (size_t)B * 1024;             // B*1024 == z_q

    constexpr size_t H1_PL = 6815744;
    constexpr size_t H3_PL = 6815744;
    constexpr size_t W1_PL = 1572864;
    constexpr size_t W2_PL = 425984;
    constexpr size_t W3_PL = 524288;
    constexpr size_t W4_PL = 1277952;

    short* h1h = (short*)emb_o;          // h1 planes in emb_o section
    short* h1l = h1h + H1_PL;

    short*  h3h      = (short*)d_ws;
    short*  w1h      = h3h + H3_PL;
    short*  w1l      = w1h + W1_PL;
    short*  w2h      = w1l + W1_PL;
    short*  w2l      = w2h + W2_PL;
    short*  w3h      = w2l + W2_PL;
    short*  w4h      = w3h + W3_PL;
    short*  wembpl   = w4h + W4_PL;
    double* wn       = (double*)(wembpl + 32768);
    int*    flag_cnt = (int*)(wn + 128);
    int*    flag_ids = flag_cnt + 64;

    // recon-section scratch (dead until g4 writes recon last):
    // Part[6] @ +0 (78.6MB), Zf @ +96MB (33.5MB), zqh plane @ +144MB (33.5MB)
    char*   scr  = (char*)recon;
    double* Part = (double*)scr;
    double* Zf   = (double*)(scr + (96ull  << 20));
    short*  zqh  = (short*) (scr + (144ull << 20));

    // ---- prep (W planes | VQ prep) ----
    prep_all<<<dim3(929), dim3(256), 0, stream>>>(
        W1, W2, W3, W4, Wemb, w1h, w1l, w2h, w2l, w3h, w4h,
        wembpl, wn, flag_cnt);

    // ---- encoder ----
    gemm_pl<2, 1, 1, 2, true><<<dim3(512), dim3(256), 0, stream>>>(
        nullptr, nullptr, x, 3072, w1h, w1l, b1, nullptr, h1h, h1l, 400, 96, 13);
    gemm_pl<2, 0, 0, 0, false><<<dim3(8, 128), dim3(256), 0, stream>>>(
        h1h, h1l, nullptr, 0, w2h, w2l, b2, z_e, nullptr, nullptr, 1024, 13, 0);

    // ---- VQ + fixup ----
    vq_mfma<<<dim3(1024), dim3(512), 0, stream>>>(z_e, wembpl, wn, emb_o, zqh,
                                                  flag_cnt, flag_ids);
    gemm_f64t<true, true, false, float><<<dim3(7, FIX_CAP / 64, 6), dim3(256), 0, stream>>>(
        x, W1, flag_ids, flag_cnt, nullptr, nullptr, Part, 3072, 400, 400, 512, FIX_CAP);
    gemm_f64t<false, false, true, double><<<dim3(16, FIX_CAP / 64), dim3(256), 0, stream>>>(
        Part, W2, nullptr, flag_cnt, b1, b2, Zf, 400, 1024, 1024, 400, FIX_CAP);
    fix_argmin<<<dim3(FIX_CAP / 4), dim3(512), 0, stream>>>(
        Zf, Wemb, flag_cnt, flag_ids, emb_o, zqh, FIX_CAP);

    // ---- decoder ----
    gemm_pl<1, 1, 0, 1, false><<<dim3(4, 128), dim3(256), 0, stream>>>(
        zqh, nullptr, nullptr, 0, w3h, nullptr, b3, nullptr, h3h, nullptr,
        400, 32, 13);
    gemm_pl<1, 2, 0, 0, false><<<dim3(24, 128), dim3(256), 0, stream>>>(
        h3h, nullptr, nullptr, 0, w4h, nullptr, b4, recon, nullptr, nullptr,
        3072, 13, 0);
}

// Round 15
// 588.512 us; speedup vs baseline: 1.3421x; 1.0631x over previous
//
#include <hip/hip_runtime.h>
#include <math.h>

// ---------------------------------------------------------------------------
// VQ-VAE forward on MI355X — round 15: safe micro-sweeps. (1) g4 sigmoid via
// __expf + v_rcp_f32 (epilogue VALU ~36->6 cyc/elem; error ~1e-7 << bf16
// compare); (2) vq_mfma z-staging and (3) fix_argmin Wemb staging switched to
// global_load_lds DMA (dest already wave-uniform+lane*16; source per-lane
// swizzled = m173 pattern). All else identical to round 14.
//   g1: h1 = relu(x @ W1^T + b1)        [A: f32 x, in-loop trunc split,
//                                        XCD-grouped map; B: W1 planes]
//   g2: z_e = h1 @ W2^T + b2            [planes -> f32 z_e output]
//   vq_mfma: MFMA dots + top-2 argmin + gap flag; writes z_q f32 + bf16 plane
//   fixup: F1 Part[c]=gatherX@W1^T (f64) | F2 Zf=relu(ΣPart+b1)@W2^T+b2 | F3
//   g3: h3 = relu(z_q @ W3^T + b3)      [z_q plane -> h3 hi plane]
//   g4: recon = sigmoid(h3 @ W4^T + b4) [planes -> f32 recon]
// ---------------------------------------------------------------------------

typedef short bf16x8 __attribute__((ext_vector_type(8)));
typedef short short8 __attribute__((ext_vector_type(8)));
typedef float f32x4  __attribute__((ext_vector_type(4)));

#define GAP_T   2e-4
#define FIX_CAP 4096

__device__ __forceinline__ unsigned short f32_to_bf16_rn(float v) {
    union { float f; unsigned u; } c; c.f = v;
    unsigned r = c.u + 0x7FFFu + ((c.u >> 16) & 1u);
    return (unsigned short)(r >> 16);
}
__device__ __forceinline__ float bf16_bits_to_f32(unsigned short b) {
    union { unsigned u; float f; } c; c.u = ((unsigned)b) << 16;
    return c.f;
}
__device__ __forceinline__ void glds16(const short* g, short* l) {
    __builtin_amdgcn_global_load_lds(
        (const __attribute__((address_space(1))) unsigned int*)g,
        (__attribute__((address_space(3))) unsigned int*)l, 16, 0, 0);
}
__device__ __forceinline__ size_t zq_plane_off(int id, int ii) {
    const int mb = id >> 7, r = id & 127;
    const int kt = ii >> 5, kc = ii & 31;
    return ((size_t)(mb * 32 + kt) * 4096)
         + r * 32 + (((kc >> 3) ^ (r & 3)) << 3) + (kc & 7);
}

// ================== merged prep: W planes + VQ prep =========================
__global__ __launch_bounds__(256) void prep_all(
    const float* __restrict__ W1, const float* __restrict__ W2,
    const float* __restrict__ W3, const float* __restrict__ W4,
    const float* __restrict__ Wemb,
    short* __restrict__ w1h, short* __restrict__ w1l,
    short* __restrict__ w2h, short* __restrict__ w2l,
    short* __restrict__ w3h, short* __restrict__ w4h,
    short* __restrict__ wembpl, double* __restrict__ wn,
    int* __restrict__ flag_cnt)
{
    const int tid = threadIdx.x;
    const int bid = blockIdx.x;

    if (bid < 928) {     // -------- weight planes --------
        const float* Wsrc; int N, K, KT, local; short *hi, *lo;
        if (bid < 384)      { Wsrc = W1; N = 400;  K = 3072; KT = 96; local = bid;       hi = w1h; lo = w1l; }
        else if (bid < 488) { Wsrc = W2; N = 1024; K = 400;  KT = 13; local = bid - 384; hi = w2h; lo = w2l; }
        else if (bid < 616) { Wsrc = W3; N = 400;  K = 1024; KT = 32; local = bid - 488; hi = w3h; lo = nullptr; }
        else                { Wsrc = W4; N = 3072; K = 400;  KT = 13; local = bid - 616; hi = w4h; lo = nullptr; }

        const int kt = local % KT;
        const int nb = local / KT;
        const size_t tb = (size_t)local * 4096;
        for (int ci = tid; ci < 512; ci += 256) {
            const int row = ci >> 2;
            const int sl  = ci & 3;
            const int k0  = ((sl ^ (row & 3)) << 3);
            const int n   = nb * 128 + row;
            const int kk  = kt * 32 + k0;
            float f[8];
            #pragma unroll
            for (int e = 0; e < 8; ++e)
                f[e] = (n < N && kk + e < K) ? Wsrc[(size_t)n * K + kk + e] : 0.f;
            short8 h, l;
            #pragma unroll
            for (int e = 0; e < 8; ++e) {
                const unsigned short hb = f32_to_bf16_rn(f[e]);
                h[e] = (short)hb;
                l[e] = (short)f32_to_bf16_rn(f[e] - bf16_bits_to_f32(hb));
            }
            *reinterpret_cast<short8*>(&hi[tb + ci * 8]) = h;
            if (lo) *reinterpret_cast<short8*>(&lo[tb + ci * 8]) = l;
        }
        return;
    }

    // -------- VQ prep (single block) --------
    if (tid == 0) *flag_cnt = 0;
    if (tid < 128) {
        double s = 0.0;
        for (int k = 0; k < 128; ++k) {
            const double w = (double)Wemb[k * 128 + tid];
            s = fma(w, w, s);
        }
        wn[tid] = s;
    }
    for (int t = tid; t < 16384; t += 256) {
        const int k = t >> 7, n = t & 127;
        const float w = Wemb[t];
        const unsigned short hi = f32_to_bf16_rn(w);
        const unsigned short lo = f32_to_bf16_rn(w - bf16_bits_to_f32(hi));
        const int off = n * 128 + (((k >> 3) ^ (n & 7)) << 3) + (k & 7);
        wembpl[off]         = (short)hi;
        wembpl[16384 + off] = (short)lo;
    }
}

// ====================== plane-fed MFMA GEMM (NT), 2-phase ===================
// AMODE: 0 = A from planes (glds); 1 = A from f32 row-major, trunc hi/lo
//        split in-loop (issue loads early, convert+ds_write late; NSPLIT=2)
// OUTMODE: 0 f32 C; 1 hi plane; 2 hi+lo planes
// XCDMAP: 1D grid 512, xcd-grouped decode (g1 only)
template<int NSPLIT, int ACT, int AMODE, int OUTMODE, bool XCDMAP>
__global__ __launch_bounds__(256) void gemm_pl(
    const short* __restrict__ Ahi, const short* __restrict__ Alo,
    const float* __restrict__ Af32, int AK,
    const short* __restrict__ Bhi, const short* __restrict__ Blo,
    const float* __restrict__ bias,
    float* __restrict__ Cf32, short* __restrict__ Cphi, short* __restrict__ Cplo,
    int N, int KT, int KTout)
{
    __shared__ short lds[2 * NSPLIT * 2 * 4096];   // double-buffered

    const int tid  = threadIdx.x;
    const int lane = tid & 63;
    const int w_id = tid >> 6;
    const int wr   = (w_id >> 1) * 64;
    const int wc   = (w_id & 1)  * 64;

    int bx, byy;
    if constexpr (XCDMAP) {          // grid 512: by = xcd*16 + (g>>2), bx = g&3
        const int bid = blockIdx.x;
        const int xcd = bid & 7, g = bid >> 3;
        byy = xcd * 16 + (g >> 2);
        bx  = g & 3;
    } else {
        bx = blockIdx.x; byy = blockIdx.y;
    }
    const int m0   = byy * 128;
    const int n0   = bx * 128;
    const int l15  = lane & 15;
    const int lg   = lane >> 4;
    constexpr int BUF = NSPLIT * 2 * 4096;

    f32x4 acc[4][4];
    #pragma unroll
    for (int i = 0; i < 4; ++i)
        #pragma unroll
        for (int j = 0; j < 4; ++j) acc[i][j] = (f32x4){0.f, 0.f, 0.f, 0.f};

    float xr[AMODE == 1 ? 16 : 1];   // reg-staged A tile (AMODE=1)

    auto loadA = [&](int kt) {       // issue-early f32 x loads
        #pragma unroll
        for (int i = 0; i < 2; ++i) {
            const int ci  = tid + i * 256;
            const int row = ci >> 2;
            const int sl  = ci & 3;
            const int k0  = ((sl ^ (row & 3)) << 3);
            const float* src = &Af32[(size_t)(m0 + row) * AK + kt * 32 + k0];
            const float4 f0 = *reinterpret_cast<const float4*>(src);
            const float4 f1 = *reinterpret_cast<const float4*>(src + 4);
            xr[i * 8 + 0] = f0.x; xr[i * 8 + 1] = f0.y;
            xr[i * 8 + 2] = f0.z; xr[i * 8 + 3] = f0.w;
            xr[i * 8 + 4] = f1.x; xr[i * 8 + 5] = f1.y;
            xr[i * 8 + 6] = f1.z; xr[i * 8 + 7] = f1.w;
        }
    };
    auto writeA = [&](int buf) {     // write-late: trunc hi + rn lo
        short* L = &lds[buf * BUF];
        #pragma unroll
        for (int i = 0; i < 2; ++i) {
            const int ci = tid + i * 256;
            short8 h, l;
            #pragma unroll
            for (int e = 0; e < 8; ++e) {
                const float v = xr[i * 8 + e];
                const unsigned u = __float_as_uint(v);
                const float hf = __uint_as_float(u & 0xFFFF0000u);
                h[e] = (short)(u >> 16);                    // hi = trunc-bf16
                l[e] = (short)f32_to_bf16_rn(v - hf);       // exact residual
            }
            *reinterpret_cast<short8*>(&L[ci * 8])        = h;
            *reinterpret_cast<short8*>(&L[4096 + ci * 8]) = l;
        }
    };
    auto stageGL = [&](int buf, int kt) {
        short* L = &lds[buf * BUF];
        const size_t bt = ((size_t)bx * KT + kt) * 4096;
        #pragma unroll
        for (int q = 0; q < 2; ++q) {
            const int o = (w_id * 2 + q) * 512 + lane * 8;
            if (AMODE == 0) {
                const size_t at = ((size_t)byy * KT + kt) * 4096;
                glds16(Ahi + at + o, &L[o]);
                if (NSPLIT > 1) glds16(Alo + at + o, &L[4096 + o]);
            }
            glds16(Bhi + bt + o, &L[NSPLIT * 4096 + o]);
            if (NSPLIT > 1) glds16(Blo + bt + o, &L[(NSPLIT + 1) * 4096 + o]);
        }
    };

    // ---- prologue: fill buffer 0 ----
    if (AMODE == 1) loadA(0);
    stageGL(0, 0);
    if (AMODE == 1) writeA(0);
    __syncthreads();

    int cur = 0;
    for (int kt = 0; kt < KT; ++kt) {
        if (kt + 1 < KT) {
            if (AMODE == 1) loadA(kt + 1);     // x loads in flight during MFMA
            stageGL(cur ^ 1, kt + 1);          // DMA in flight during MFMA
        }

        const short* L = &lds[cur * BUF];
        bf16x8 bfr[4][NSPLIT];
        #pragma unroll
        for (int fc = 0; fc < 4; ++fc) {
            const int rn  = wc + fc * 16 + l15;
            const int idx = rn * 32 + ((lg ^ (rn & 3)) << 3);
            #pragma unroll
            for (int s = 0; s < NSPLIT; ++s)
                bfr[fc][s] = *reinterpret_cast<const bf16x8*>(&L[(NSPLIT + s) * 4096 + idx]);
        }
        #pragma unroll
        for (int fr = 0; fr < 4; ++fr) {
            const int rm  = wr + fr * 16 + l15;
            const int idx = rm * 32 + ((lg ^ (rm & 3)) << 3);
            const bf16x8 a0 = *reinterpret_cast<const bf16x8*>(&L[idx]);
            bf16x8 a1;
            if (NSPLIT > 1)
                a1 = *reinterpret_cast<const bf16x8*>(&L[4096 + idx]);
            #pragma unroll
            for (int fc = 0; fc < 4; ++fc) {
                acc[fr][fc] = __builtin_amdgcn_mfma_f32_16x16x32_bf16(
                    a0, bfr[fc][0], acc[fr][fc], 0, 0, 0);
                if (NSPLIT > 1) {
                    acc[fr][fc] = __builtin_amdgcn_mfma_f32_16x16x32_bf16(
                        a0, bfr[fc][1], acc[fr][fc], 0, 0, 0);
                    acc[fr][fc] = __builtin_amdgcn_mfma_f32_16x16x32_bf16(
                        a1, bfr[fc][0], acc[fr][fc], 0, 0, 0);
                }
            }
        }

        if (AMODE == 1 && kt + 1 < KT) writeA(cur ^ 1);   // write-late
        __syncthreads();             // drains DMA + guards buffer swap
        cur ^= 1;
    }

    float bv[4];
    #pragma unroll
    for (int fc = 0; fc < 4; ++fc) {
        const int col = n0 + wc + fc * 16 + l15;
        bv[fc] = (col < N) ? bias[col] : 0.f;
    }
    #pragma unroll
    for (int fr = 0; fr < 4; ++fr) {
        #pragma unroll
        for (int fc = 0; fc < 4; ++fc) {
            const int col = n0 + wc + fc * 16 + l15;
            #pragma unroll
            for (int j = 0; j < 4; ++j) {
                const int rowg = m0 + wr + fr * 16 + lg * 4 + j;
                float v = acc[fr][fc][j] + bv[fc];
                if (ACT == 1) v = fmaxf(v, 0.f);
                else if (ACT == 2) {
                    // fast sigmoid: |err| ~1e-7 << bf16-compare threshold
                    v = __builtin_amdgcn_rcpf(1.f + __expf(-v));
                }
                if (OUTMODE == 0) {
                    if (col < N) Cf32[(size_t)rowg * N + col] = v;
                } else {
                    const int kto = col >> 5;
                    if (kto < KTout) {
                        const int r = rowg & 127, k = col & 31;
                        const size_t off = ((size_t)byy * KTout + kto) * 4096
                                         + r * 32 + (((k >> 3) ^ (r & 3)) << 3) + (k & 7);
                        const unsigned short hb = f32_to_bf16_rn(v);
                        Cphi[off] = (short)hb;
                        if (OUTMODE == 2)
                            Cplo[off] = (short)f32_to_bf16_rn(v - bf16_bits_to_f32(hb));
                    }
                }
            }
        }
    }
}

// ============================ VQ MFMA + argmin ==============================
// Codebook planes read directly from global (L2-resident); z staged via
// global_load_lds DMA (linear dest, pre-swizzled per-lane source).
__global__ __launch_bounds__(512) void vq_mfma(
    const float* __restrict__ z_e, const short* __restrict__ planes,
    const double* __restrict__ wn_g, float* __restrict__ zq,
    short* __restrict__ zqh,
    int* __restrict__ flag_cnt, int* __restrict__ flag_ids)
{
    __shared__ float  zsh[16 * 1024];   // 64KB
    __shared__ double wn_sh[128];
    __shared__ double cmb_v1[128][2];
    __shared__ double cmb_v2[128][2];
    __shared__ int    cmb_i[128][2];
    __shared__ int    idx_sh[128];
    __shared__ int    sflag[16];

    const int tid = threadIdx.x;
    const int b0  = blockIdx.x * 16;

    for (int c = tid; c < 128; c += 512) wn_sh[c] = wn_g[c];
    // z staging: DMA, dest = wave-uniform base + lane*16, source swizzled
    for (int c = tid; c < 4096; c += 512) {
        const int D    = c * 16;
        const int s    = D >> 12;
        const int dr   = D & 4095;
        const int srcb = dr ^ (((dr >> 8) & 3) << 5);
        glds16(reinterpret_cast<const short*>(
                   reinterpret_cast<const char*>(z_e) + (size_t)(b0 + s) * 4096 + srcb),
               reinterpret_cast<short*>(reinterpret_cast<char*>(zsh) + D));
    }
    if (tid < 16) sflag[tid] = 0;
    __syncthreads();

    const int lane = tid & 63;
    const int w_id = tid >> 6;
    const int wr   = (w_id >> 1) * 32;
    const int wc   = (w_id & 1) * 64;
    const int l15  = lane & 15;
    const int lg   = lane >> 4;

    f32x4 acc[2][4];
    #pragma unroll
    for (int i = 0; i < 2; ++i)
        #pragma unroll
        for (int j = 0; j < 4; ++j) acc[i][j] = (f32x4){0.f, 0.f, 0.f, 0.f};

    #pragma unroll
    for (int ks = 0; ks < 4; ++ks) {
        bf16x8 bh[4], bl[4];
        #pragma unroll
        for (int cf = 0; cf < 4; ++cf) {
            const int n     = wc + cf * 16 + l15;
            const int slotp = (ks * 4 + lg) ^ (n & 7);
            const int off   = n * 128 + slotp * 8;
            bh[cf] = *reinterpret_cast<const bf16x8*>(&planes[off]);
            bl[cf] = *reinterpret_cast<const bf16x8*>(&planes[16384 + off]);
        }
        bf16x8 ah[2], al[2];
        #pragma unroll
        for (int rf = 0; rf < 2; ++rf) {
            const int row   = wr + rf * 16 + l15;
            const int s_loc = row >> 3;
            const int d     = row & 7;
            const int kb    = ks * 32 + lg * 8;
            const int xrr   = (lg & 3) << 5;
            const char* zb  = reinterpret_cast<const char*>(zsh) + s_loc * 4096;
            bf16x8 h8, L8;
            #pragma unroll
            for (int j = 0; j < 8; ++j) {
                const float a = *reinterpret_cast<const float*>(
                    zb + ((32 * (kb + j) + 4 * d) ^ xrr));
                const unsigned short hi = f32_to_bf16_rn(a);
                h8[j] = (short)hi;
                L8[j] = (short)f32_to_bf16_rn(a - bf16_bits_to_f32(hi));
            }
            ah[rf] = h8; al[rf] = L8;
        }
        #pragma unroll
        for (int rf = 0; rf < 2; ++rf)
            #pragma unroll
            for (int cf = 0; cf < 4; ++cf) {
                acc[rf][cf] = __builtin_amdgcn_mfma_f32_16x16x32_bf16(
                    ah[rf], bh[cf], acc[rf][cf], 0, 0, 0);
                acc[rf][cf] = __builtin_amdgcn_mfma_f32_16x16x32_bf16(
                    ah[rf], bl[cf], acc[rf][cf], 0, 0, 0);
                acc[rf][cf] = __builtin_amdgcn_mfma_f32_16x16x32_bf16(
                    al[rf], bh[cf], acc[rf][cf], 0, 0, 0);
            }
    }

    #pragma unroll
    for (int rf = 0; rf < 2; ++rf)
        #pragma unroll
        for (int j = 0; j < 4; ++j) {
            double v1 = 1e300, v2 = 1e300; int i1 = 0;
            #pragma unroll
            for (int cf = 0; cf < 4; ++cf) {
                const int n = wc + cf * 16 + l15;
                const double v = wn_sh[n] - 2.0 * (double)acc[rf][cf][j];
                if (v < v1)      { v2 = v1; v1 = v; i1 = n; }
                else if (v < v2) { v2 = v; }
            }
            #pragma unroll
            for (int off = 1; off < 16; off <<= 1) {
                const double ov1 = __shfl_xor(v1, off);
                const int    oi1 = __shfl_xor(i1, off);
                const double ov2 = __shfl_xor(v2, off);
                if (ov1 < v1 || (ov1 == v1 && oi1 < i1)) {
                    v2 = fmin(v1, ov2); v1 = ov1; i1 = oi1;
                } else {
                    v2 = fmin(v2, ov1);
                }
            }
            if (l15 == 0) {
                const int r = wr + rf * 16 + lg * 4 + j;
                cmb_v1[r][w_id & 1] = v1;
                cmb_v2[r][w_id & 1] = v2;
                cmb_i [r][w_id & 1] = i1;
            }
        }
    __syncthreads();

    if (tid < 128) {
        const double v1a = cmb_v1[tid][0], v1b = cmb_v1[tid][1];
        double v1, v2; int i1;
        if (v1b < v1a) { v1 = v1b; i1 = cmb_i[tid][1]; v2 = fmin(v1a, cmb_v2[tid][1]); }
        else           { v1 = v1a; i1 = cmb_i[tid][0]; v2 = fmin(v1b, cmb_v2[tid][0]); }
        idx_sh[tid] = i1;
        if (v2 - v1 < GAP_T) sflag[tid >> 3] = 1;
    }
    __syncthreads();
    if (tid < 16 && sflag[tid]) {
        const int p = atomicAdd(flag_cnt, 1);
        flag_ids[p] = b0 + tid;
    }

    for (int t = tid; t < 16384; t += 512) {
        const int s = t >> 10, i = t & 1023;
        const int k = i >> 3, d = i & 7;
        const int n = idx_sh[(s << 3) | d];
        const int off = n * 128 + (((k >> 3) ^ (n & 7)) << 3) + (k & 7);
        const float val = bf16_bits_to_f32((unsigned short)planes[off]) +
                          bf16_bits_to_f32((unsigned short)planes[16384 + off]);
        zq[(size_t)(b0 + s) * 1024 + i] = val;
        zqh[zq_plane_off(b0 + s, i)] = (short)f32_to_bf16_rn(val);
    }
}

// ================= fixup F1/F2: 64x64-tile f64 GEMM (NT) ===================
#define FLP 68
template<bool GATHER, bool SPLITK, bool FUSERED, typename TA>
__global__ __launch_bounds__(256) void gemm_f64t(
    const TA* __restrict__ A, const float* __restrict__ Wf,
    const int* __restrict__ ids, const int* __restrict__ cntp,
    const float* __restrict__ biasA, const float* __restrict__ bias,
    double* __restrict__ C,
    int AK, int N, int CN, int klen, int cap)
{
    __shared__ double As[16 * FLP];
    __shared__ double Ws[16 * FLP];

    const int tid = threadIdx.x;
    const int tx  = tid & 15;
    const int ty  = tid >> 4;
    const int m0  = blockIdx.y * 64;
    const int n0  = blockIdx.x * 64;
    const int cnt = (*cntp < cap) ? *cntp : cap;
    if (m0 >= cnt) return;

    const int k0 = SPLITK ? blockIdx.z * klen : 0;
    if (SPLITK) C += (size_t)blockIdx.z * cap * CN;

    const int srow = tid >> 2;
    const int sc4  = (tid & 3) << 2;

    const TA* arow;
    if (GATHER) {
        const int m  = m0 + srow;
        const int id = (m < cnt) ? ids[m] : 0;
        arow = A + (size_t)id * AK;
    } else {
        arow = A + (size_t)(m0 + srow) * AK;
    }
    const int   nrow = n0 + srow;
    const float* wrow = Wf + (size_t)(nrow < N ? nrow : 0) * AK;
    const bool  wok  = (nrow < N);

    double acc[4][4];
    #pragma unroll
    for (int i = 0; i < 4; ++i)
        #pragma unroll
        for (int j = 0; j < 4; ++j) acc[i][j] = 0.0;

    for (int kt = 0; kt < klen; kt += 16) {
        const int kb = k0 + kt + sc4;
        if constexpr (FUSERED) {
            const size_t cs = (size_t)cap * AK;
            #pragma unroll
            for (int e = 0; e < 4; ++e) {
                double s = (double)biasA[kb + e];
                #pragma unroll
                for (int c = 0; c < 6; ++c) s += arow[c * cs + kb + e];
                As[(sc4 + e) * FLP + srow] = s > 0.0 ? s : 0.0;
            }
        } else if constexpr (sizeof(TA) == 4) {
            const float4 v = *reinterpret_cast<const float4*>(&arow[kb]);
            As[(sc4 + 0) * FLP + srow] = (double)v.x;
            As[(sc4 + 1) * FLP + srow] = (double)v.y;
            As[(sc4 + 2) * FLP + srow] = (double)v.z;
            As[(sc4 + 3) * FLP + srow] = (double)v.w;
        } else {
            const double2 v0 = *reinterpret_cast<const double2*>(&arow[kb]);
            const double2 v1 = *reinterpret_cast<const double2*>(&arow[kb + 2]);
            As[(sc4 + 0) * FLP + srow] = v0.x;
            As[(sc4 + 1) * FLP + srow] = v0.y;
            As[(sc4 + 2) * FLP + srow] = v1.x;
            As[(sc4 + 3) * FLP + srow] = v1.y;
        }
        float4 w = make_float4(0.f, 0.f, 0.f, 0.f);
        if (wok) w = *reinterpret_cast<const float4*>(&wrow[kb]);
        Ws[(sc4 + 0) * FLP + srow] = (double)w.x;
        Ws[(sc4 + 1) * FLP + srow] = (double)w.y;
        Ws[(sc4 + 2) * FLP + srow] = (double)w.z;
        Ws[(sc4 + 3) * FLP + srow] = (double)w.w;
        __syncthreads();

        #pragma unroll
        for (int k = 0; k < 16; ++k) {
            const double2 A0 = *reinterpret_cast<const double2*>(&As[k * FLP + ty * 4]);
            const double2 A1 = *reinterpret_cast<const double2*>(&As[k * FLP + ty * 4 + 2]);
            const double2 B0 = *reinterpret_cast<const double2*>(&Ws[k * FLP + tx * 4]);
            const double2 B1 = *reinterpret_cast<const double2*>(&Ws[k * FLP + tx * 4 + 2]);
            const double a[4] = {A0.x, A0.y, A1.x, A1.y};
            const double b[4] = {B0.x, B0.y, B1.x, B1.y};
            #pragma unroll
            for (int i = 0; i < 4; ++i)
                #pragma unroll
                for (int j = 0; j < 4; ++j)
                    acc[i][j] = fma(a[i], b[j], acc[i][j]);
        }
        __syncthreads();
    }

    #pragma unroll
    for (int i = 0; i < 4; ++i) {
        const int row = m0 + ty * 4 + i;
        #pragma unroll
        for (int j = 0; j < 4; ++j) {
            const int col = n0 + tx * 4 + j;
            if (col < N)
                C[(size_t)row * CN + col] =
                    acc[i][j] + (bias ? (double)bias[col] : 0.0);
        }
    }
}

// ======= fixup F3: exact f64 distances + argmin + z_q scatter ===============
__global__ __launch_bounds__(512) void fix_argmin(
    const double* __restrict__ Zf, const float* __restrict__ Wemb,
    const int* __restrict__ cntp, const int* __restrict__ ids,
    float* __restrict__ zq, short* __restrict__ zqh, int cap)
{
    __shared__ float  wesh[16384];
    __shared__ double zsh[4][1032];
    __shared__ double dist[4 * 8 * 128];
    __shared__ int    idxf[32];

    const int tid  = threadIdx.x;
    const int lane = tid & 63;
    const int wv   = tid >> 6;
    const int cnt  = (*cntp < cap) ? *cntp : cap;
    const int base = blockIdx.x * 4;
    if (base >= cnt) return;
    const int ns = (cnt - base < 4) ? (cnt - base) : 4;

    // Wemb staging via DMA (linear/linear)
    for (int i = tid; i < 4096; i += 512)
        glds16(reinterpret_cast<const short*>(Wemb) + (size_t)i * 8,
               reinterpret_cast<short*>(wesh) + (size_t)i * 8);
    for (int i = tid; i < 4 * 512; i += 512) {
        const int s = i >> 9, e = (i & 511) * 2;
        if (s < ns) {
            const double2 v = *reinterpret_cast<const double2*>(
                &Zf[(size_t)(base + s) * 1024 + e]);
            zsh[s][e] = v.x;
            zsh[s][e + 1] = v.y;
        }
    }
    __syncthreads();

    for (int t = tid; t < ns * 1024; t += 512) {
        const int s = t >> 10, d = (t >> 7) & 7, n = t & 127;
        double acc = 0.0;
        for (int k = 0; k < 128; ++k) {
            const double diff = zsh[s][k * 8 + d] - (double)wesh[k * 128 + n];
            acc = fma(diff, diff, acc);
        }
        dist[(s * 8 + d) * 128 + n] = acc;
    }
    __syncthreads();

    for (int p = wv; p < ns * 8; p += 8) {
        const double* dp = &dist[p * 128];
        double v0 = dp[lane], vx = dp[lane + 64];
        double v; int ix;
        if (vx < v0) { v = vx; ix = lane + 64; }
        else         { v = v0; ix = lane; }
        #pragma unroll
        for (int off = 32; off > 0; off >>= 1) {
            const double ov = __shfl_down(v, off);
            const int    oi = __shfl_down(ix, off);
            if (ov < v || (ov == v && oi < ix)) { v = ov; ix = oi; }
        }
        if (lane == 0) idxf[p] = ix;
    }
    __syncthreads();

    for (int i = tid; i < ns * 1024; i += 512) {
        const int s = i >> 10, ii = i & 1023;
        const int id = ids[base + s];
        const float val = wesh[(ii >> 3) * 128 + idxf[s * 8 + (ii & 7)]];
        zq[(size_t)id * 1024 + ii] = val;
        zqh[zq_plane_off(id, ii)] = (short)f32_to_bf16_rn(val);
    }
}

// ---------------------------------------------------------------------------
extern "C" void kernel_launch(void* const* d_in, const int* in_sizes, int n_in,
                              void* d_out, int out_size, void* d_ws, size_t ws_size,
                              hipStream_t stream)
{
    const float* x    = (const float*)d_in[0];
    const float* W1   = (const float*)d_in[1];
    const float* b1   = (const float*)d_in[2];
    const float* W2   = (const float*)d_in[3];
    const float* b2   = (const float*)d_in[4];
    const float* W3   = (const float*)d_in[5];
    const float* b3   = (const float*)d_in[6];
    const float* W4   = (const float*)d_in[7];
    const float* b4   = (const float*)d_in[8];
    const float* Wemb = (const float*)d_in[9];

    const int B = 16384;
    float* out   = (float*)d_out;
    float* recon = out;                                // B*3072
    float* z_e   = out + (size_t)B * 3072;             // B*1024
    float* emb_o = z_e + (size_t)B * 1024;             // B*1024 == z_q

    constexpr size_t H1_PL = 6815744;
    constexpr size_t H3_PL = 6815744;
    constexpr size_t W1_PL = 1572864;
    constexpr size_t W2_PL = 425984;
    constexpr size_t W3_PL = 524288;
    constexpr size_t W4_PL = 1277952;

    short* h1h = (short*)emb_o;          // h1 planes in emb_o section
    short* h1l = h1h + H1_PL;

    short*  h3h      = (short*)d_ws;
    short*  w1h      = h3h + H3_PL;
    short*  w1l      = w1h + W1_PL;
    short*  w2h      = w1l + W1_PL;
    short*  w2l      = w2h + W2_PL;
    short*  w3h      = w2l + W2_PL;
    short*  w4h      = w3h + W3_PL;
    short*  wembpl   = w4h + W4_PL;
    double* wn       = (double*)(wembpl + 32768);
    int*    flag_cnt = (int*)(wn + 128);
    int*    flag_ids = flag_cnt + 64;

    // recon-section scratch (dead until g4 writes recon last):
    // Part[6] @ +0 (78.6MB), Zf @ +96MB (33.5MB), zqh plane @ +144MB (33.5MB)
    char*   scr  = (char*)recon;
    double* Part = (double*)scr;
    double* Zf   = (double*)(scr + (96ull  << 20));
    short*  zqh  = (short*) (scr + (144ull << 20));

    // ---- prep (W planes | VQ prep) ----
    prep_all<<<dim3(929), dim3(256), 0, stream>>>(
        W1, W2, W3, W4, Wemb, w1h, w1l, w2h, w2l, w3h, w4h,
        wembpl, wn, flag_cnt);

    // ---- encoder ----
    gemm_pl<2, 1, 1, 2, true><<<dim3(512), dim3(256), 0, stream>>>(
        nullptr, nullptr, x, 3072, w1h, w1l, b1, nullptr, h1h, h1l, 400, 96, 13);
    gemm_pl<2, 0, 0, 0, false><<<dim3(8, 128), dim3(256), 0, stream>>>(
        h1h, h1l, nullptr, 0, w2h, w2l, b2, z_e, nullptr, nullptr, 1024, 13, 0);

    // ---- VQ + fixup ----
    vq_mfma<<<dim3(1024), dim3(512), 0, stream>>>(z_e, wembpl, wn, emb_o, zqh,
                                                  flag_cnt, flag_ids);
    gemm_f64t<true, true, false, float><<<dim3(7, FIX_CAP / 64, 6), dim3(256), 0, stream>>>(
        x, W1, flag_ids, flag_cnt, nullptr, nullptr, Part, 3072, 400, 400, 512, FIX_CAP);
    gemm_f64t<false, false, true, double><<<dim3(16, FIX_CAP / 64), dim3(256), 0, stream>>>(
        Part, W2, nullptr, flag_cnt, b1, b2, Zf, 400, 1024, 1024, 400, FIX_CAP);
    fix_argmin<<<dim3(FIX_CAP / 4), dim3(512), 0, stream>>>(
        Zf, Wemb, flag_cnt, flag_ids, emb_o, zqh, FIX_CAP);

    // ---- decoder ----
    gemm_pl<1, 1, 0, 1, false><<<dim3(4, 128), dim3(256), 0, stream>>>(
        zqh, nullptr, nullptr, 0, w3h, nullptr, b3, nullptr, h3h, nullptr,
        400, 32, 13);
    gemm_pl<1, 2, 0, 0, false><<<dim3(24, 128), dim3(256), 0, stream>>>(
        h3h, nullptr, nullptr, 0, w4h, nullptr, b4, recon, nullptr, nullptr,
        3072, 13, 0);
}

// Round 16
// 580.614 us; speedup vs baseline: 1.3603x; 1.0136x over previous
//
#include <hip/hip_runtime.h>
#include <math.h>

// ---------------------------------------------------------------------------
// VQ-VAE forward on MI355X — round 16: XCD-grouped block maps generalized to
// ALL gemm_pl launches (T1). g1's map (round 13) cut its FETCH 399->123MB;
// g2/g3/g4 have the same A-operand re-read pattern (8x/4x/24x) unexploited.
// Pure scheduling change — numerics bit-identical to round 15.
//   g1: h1 = relu(x @ W1^T + b1)        [A: f32 x, in-loop trunc split]
//   g2: z_e = h1 @ W2^T + b2            [planes -> f32 z_e output]
//   vq_mfma: MFMA dots + top-2 argmin + gap flag; writes z_q f32 + bf16 plane
//   fixup: F1 Part[c]=gatherX@W1^T (f64) | F2 Zf=relu(ΣPart+b1)@W2^T+b2 | F3
//   g3: h3 = relu(z_q @ W3^T + b3)      [z_q plane -> h3 hi plane]
//   g4: recon = sigmoid(h3 @ W4^T + b4) [planes -> f32 recon]
// ---------------------------------------------------------------------------

typedef short bf16x8 __attribute__((ext_vector_type(8)));
typedef short short8 __attribute__((ext_vector_type(8)));
typedef float f32x4  __attribute__((ext_vector_type(4)));

#define GAP_T   2e-4
#define FIX_CAP 4096

__device__ __forceinline__ unsigned short f32_to_bf16_rn(float v) {
    union { float f; unsigned u; } c; c.f = v;
    unsigned r = c.u + 0x7FFFu + ((c.u >> 16) & 1u);
    return (unsigned short)(r >> 16);
}
__device__ __forceinline__ float bf16_bits_to_f32(unsigned short b) {
    union { unsigned u; float f; } c; c.u = ((unsigned)b) << 16;
    return c.f;
}
__device__ __forceinline__ void glds16(const short* g, short* l) {
    __builtin_amdgcn_global_load_lds(
        (const __attribute__((address_space(1))) unsigned int*)g,
        (__attribute__((address_space(3))) unsigned int*)l, 16, 0, 0);
}
__device__ __forceinline__ size_t zq_plane_off(int id, int ii) {
    const int mb = id >> 7, r = id & 127;
    const int kt = ii >> 5, kc = ii & 31;
    return ((size_t)(mb * 32 + kt) * 4096)
         + r * 32 + (((kc >> 3) ^ (r & 3)) << 3) + (kc & 7);
}

// ================== merged prep: W planes + VQ prep =========================
__global__ __launch_bounds__(256) void prep_all(
    const float* __restrict__ W1, const float* __restrict__ W2,
    const float* __restrict__ W3, const float* __restrict__ W4,
    const float* __restrict__ Wemb,
    short* __restrict__ w1h, short* __restrict__ w1l,
    short* __restrict__ w2h, short* __restrict__ w2l,
    short* __restrict__ w3h, short* __restrict__ w4h,
    short* __restrict__ wembpl, double* __restrict__ wn,
    int* __restrict__ flag_cnt)
{
    const int tid = threadIdx.x;
    const int bid = blockIdx.x;

    if (bid < 928) {     // -------- weight planes --------
        const float* Wsrc; int N, K, KT, local; short *hi, *lo;
        if (bid < 384)      { Wsrc = W1; N = 400;  K = 3072; KT = 96; local = bid;       hi = w1h; lo = w1l; }
        else if (bid < 488) { Wsrc = W2; N = 1024; K = 400;  KT = 13; local = bid - 384; hi = w2h; lo = w2l; }
        else if (bid < 616) { Wsrc = W3; N = 400;  K = 1024; KT = 32; local = bid - 488; hi = w3h; lo = nullptr; }
        else                { Wsrc = W4; N = 3072; K = 400;  KT = 13; local = bid - 616; hi = w4h; lo = nullptr; }

        const int kt = local % KT;
        const int nb = local / KT;
        const size_t tb = (size_t)local * 4096;
        for (int ci = tid; ci < 512; ci += 256) {
            const int row = ci >> 2;
            const int sl  = ci & 3;
            const int k0  = ((sl ^ (row & 3)) << 3);
            const int n   = nb * 128 + row;
            const int kk  = kt * 32 + k0;
            float f[8];
            #pragma unroll
            for (int e = 0; e < 8; ++e)
                f[e] = (n < N && kk + e < K) ? Wsrc[(size_t)n * K + kk + e] : 0.f;
            short8 h, l;
            #pragma unroll
            for (int e = 0; e < 8; ++e) {
                const unsigned short hb = f32_to_bf16_rn(f[e]);
                h[e] = (short)hb;
                l[e] = (short)f32_to_bf16_rn(f[e] - bf16_bits_to_f32(hb));
            }
            *reinterpret_cast<short8*>(&hi[tb + ci * 8]) = h;
            if (lo) *reinterpret_cast<short8*>(&lo[tb + ci * 8]) = l;
        }
        return;
    }

    // -------- VQ prep (single block) --------
    if (tid == 0) *flag_cnt = 0;
    if (tid < 128) {
        double s = 0.0;
        for (int k = 0; k < 128; ++k) {
            const double w = (double)Wemb[k * 128 + tid];
            s = fma(w, w, s);
        }
        wn[tid] = s;
    }
    for (int t = tid; t < 16384; t += 256) {
        const int k = t >> 7, n = t & 127;
        const float w = Wemb[t];
        const unsigned short hi = f32_to_bf16_rn(w);
        const unsigned short lo = f32_to_bf16_rn(w - bf16_bits_to_f32(hi));
        const int off = n * 128 + (((k >> 3) ^ (n & 7)) << 3) + (k & 7);
        wembpl[off]         = (short)hi;
        wembpl[16384 + off] = (short)lo;
    }
}

// ====================== plane-fed MFMA GEMM (NT), 2-phase ===================
// AMODE: 0 = A from planes (glds); 1 = A from f32 row-major, trunc hi/lo
//        split in-loop (issue loads early, convert+ds_write late; NSPLIT=2)
// OUTMODE: 0 f32 C; 1 hi plane; 2 hi+lo planes
// XNBX:  columns-per-row-group for the XCD-grouped 1D map (grid = XNBX*128):
//        xcd = bid&7, g = bid>>3, by = xcd*16 + g/XNBX, bx = g%XNBX.
//        All XNBX col-blocks of a row-group land on one XCD -> A re-reads
//        become same-XCD L2 hits (T1).
template<int NSPLIT, int ACT, int AMODE, int OUTMODE, int XNBX>
__global__ __launch_bounds__(256) void gemm_pl(
    const short* __restrict__ Ahi, const short* __restrict__ Alo,
    const float* __restrict__ Af32, int AK,
    const short* __restrict__ Bhi, const short* __restrict__ Blo,
    const float* __restrict__ bias,
    float* __restrict__ Cf32, short* __restrict__ Cphi, short* __restrict__ Cplo,
    int N, int KT, int KTout)
{
    __shared__ short lds[2 * NSPLIT * 2 * 4096];   // double-buffered

    const int tid  = threadIdx.x;
    const int lane = tid & 63;
    const int w_id = tid >> 6;
    const int wr   = (w_id >> 1) * 64;
    const int wc   = (w_id & 1)  * 64;

    const int bid = blockIdx.x;
    const int xcd = bid & 7, g = bid >> 3;
    const int byy = xcd * 16 + g / XNBX;
    const int bx  = g % XNBX;

    const int m0   = byy * 128;
    const int n0   = bx * 128;
    const int l15  = lane & 15;
    const int lg   = lane >> 4;
    constexpr int BUF = NSPLIT * 2 * 4096;

    f32x4 acc[4][4];
    #pragma unroll
    for (int i = 0; i < 4; ++i)
        #pragma unroll
        for (int j = 0; j < 4; ++j) acc[i][j] = (f32x4){0.f, 0.f, 0.f, 0.f};

    float xr[AMODE == 1 ? 16 : 1];   // reg-staged A tile (AMODE=1)

    auto loadA = [&](int kt) {       // issue-early f32 x loads
        #pragma unroll
        for (int i = 0; i < 2; ++i) {
            const int ci  = tid + i * 256;
            const int row = ci >> 2;
            const int sl  = ci & 3;
            const int k0  = ((sl ^ (row & 3)) << 3);
            const float* src = &Af32[(size_t)(m0 + row) * AK + kt * 32 + k0];
            const float4 f0 = *reinterpret_cast<const float4*>(src);
            const float4 f1 = *reinterpret_cast<const float4*>(src + 4);
            xr[i * 8 + 0] = f0.x; xr[i * 8 + 1] = f0.y;
            xr[i * 8 + 2] = f0.z; xr[i * 8 + 3] = f0.w;
            xr[i * 8 + 4] = f1.x; xr[i * 8 + 5] = f1.y;
            xr[i * 8 + 6] = f1.z; xr[i * 8 + 7] = f1.w;
        }
    };
    auto writeA = [&](int buf) {     // write-late: trunc hi + rn lo
        short* L = &lds[buf * BUF];
        #pragma unroll
        for (int i = 0; i < 2; ++i) {
            const int ci = tid + i * 256;
            short8 h, l;
            #pragma unroll
            for (int e = 0; e < 8; ++e) {
                const float v = xr[i * 8 + e];
                const unsigned u = __float_as_uint(v);
                const float hf = __uint_as_float(u & 0xFFFF0000u);
                h[e] = (short)(u >> 16);                    // hi = trunc-bf16
                l[e] = (short)f32_to_bf16_rn(v - hf);       // exact residual
            }
            *reinterpret_cast<short8*>(&L[ci * 8])        = h;
            *reinterpret_cast<short8*>(&L[4096 + ci * 8]) = l;
        }
    };
    auto stageGL = [&](int buf, int kt) {
        short* L = &lds[buf * BUF];
        const size_t bt = ((size_t)bx * KT + kt) * 4096;
        #pragma unroll
        for (int q = 0; q < 2; ++q) {
            const int o = (w_id * 2 + q) * 512 + lane * 8;
            if (AMODE == 0) {
                const size_t at = ((size_t)byy * KT + kt) * 4096;
                glds16(Ahi + at + o, &L[o]);
                if (NSPLIT > 1) glds16(Alo + at + o, &L[4096 + o]);
            }
            glds16(Bhi + bt + o, &L[NSPLIT * 4096 + o]);
            if (NSPLIT > 1) glds16(Blo + bt + o, &L[(NSPLIT + 1) * 4096 + o]);
        }
    };

    // ---- prologue: fill buffer 0 ----
    if (AMODE == 1) loadA(0);
    stageGL(0, 0);
    if (AMODE == 1) writeA(0);
    __syncthreads();

    int cur = 0;
    for (int kt = 0; kt < KT; ++kt) {
        if (kt + 1 < KT) {
            if (AMODE == 1) loadA(kt + 1);     // x loads in flight during MFMA
            stageGL(cur ^ 1, kt + 1);          // DMA in flight during MFMA
        }

        const short* L = &lds[cur * BUF];
        bf16x8 bfr[4][NSPLIT];
        #pragma unroll
        for (int fc = 0; fc < 4; ++fc) {
            const int rn  = wc + fc * 16 + l15;
            const int idx = rn * 32 + ((lg ^ (rn & 3)) << 3);
            #pragma unroll
            for (int s = 0; s < NSPLIT; ++s)
                bfr[fc][s] = *reinterpret_cast<const bf16x8*>(&L[(NSPLIT + s) * 4096 + idx]);
        }
        #pragma unroll
        for (int fr = 0; fr < 4; ++fr) {
            const int rm  = wr + fr * 16 + l15;
            const int idx = rm * 32 + ((lg ^ (rm & 3)) << 3);
            const bf16x8 a0 = *reinterpret_cast<const bf16x8*>(&L[idx]);
            bf16x8 a1;
            if (NSPLIT > 1)
                a1 = *reinterpret_cast<const bf16x8*>(&L[4096 + idx]);
            #pragma unroll
            for (int fc = 0; fc < 4; ++fc) {
                acc[fr][fc] = __builtin_amdgcn_mfma_f32_16x16x32_bf16(
                    a0, bfr[fc][0], acc[fr][fc], 0, 0, 0);
                if (NSPLIT > 1) {
                    acc[fr][fc] = __builtin_amdgcn_mfma_f32_16x16x32_bf16(
                        a0, bfr[fc][1], acc[fr][fc], 0, 0, 0);
                    acc[fr][fc] = __builtin_amdgcn_mfma_f32_16x16x32_bf16(
                        a1, bfr[fc][0], acc[fr][fc], 0, 0, 0);
                }
            }
        }

        if (AMODE == 1 && kt + 1 < KT) writeA(cur ^ 1);   // write-late
        __syncthreads();             // drains DMA + guards buffer swap
        cur ^= 1;
    }

    float bv[4];
    #pragma unroll
    for (int fc = 0; fc < 4; ++fc) {
        const int col = n0 + wc + fc * 16 + l15;
        bv[fc] = (col < N) ? bias[col] : 0.f;
    }
    #pragma unroll
    for (int fr = 0; fr < 4; ++fr) {
        #pragma unroll
        for (int fc = 0; fc < 4; ++fc) {
            const int col = n0 + wc + fc * 16 + l15;
            #pragma unroll
            for (int j = 0; j < 4; ++j) {
                const int rowg = m0 + wr + fr * 16 + lg * 4 + j;
                float v = acc[fr][fc][j] + bv[fc];
                if (ACT == 1) v = fmaxf(v, 0.f);
                else if (ACT == 2) {
                    // fast sigmoid: |err| ~1e-7 << bf16-compare threshold
                    v = __builtin_amdgcn_rcpf(1.f + __expf(-v));
                }
                if (OUTMODE == 0) {
                    if (col < N) Cf32[(size_t)rowg * N + col] = v;
                } else {
                    const int kto = col >> 5;
                    if (kto < KTout) {
                        const int r = rowg & 127, k = col & 31;
                        const size_t off = ((size_t)byy * KTout + kto) * 4096
                                         + r * 32 + (((k >> 3) ^ (r & 3)) << 3) + (k & 7);
                        const unsigned short hb = f32_to_bf16_rn(v);
                        Cphi[off] = (short)hb;
                        if (OUTMODE == 2)
                            Cplo[off] = (short)f32_to_bf16_rn(v - bf16_bits_to_f32(hb));
                    }
                }
            }
        }
    }
}

// ============================ VQ MFMA + argmin ==============================
__global__ __launch_bounds__(512) void vq_mfma(
    const float* __restrict__ z_e, const short* __restrict__ planes,
    const double* __restrict__ wn_g, float* __restrict__ zq,
    short* __restrict__ zqh,
    int* __restrict__ flag_cnt, int* __restrict__ flag_ids)
{
    __shared__ float  zsh[16 * 1024];   // 64KB
    __shared__ double wn_sh[128];
    __shared__ double cmb_v1[128][2];
    __shared__ double cmb_v2[128][2];
    __shared__ int    cmb_i[128][2];
    __shared__ int    idx_sh[128];
    __shared__ int    sflag[16];

    const int tid = threadIdx.x;
    const int b0  = blockIdx.x * 16;

    for (int c = tid; c < 128; c += 512) wn_sh[c] = wn_g[c];
    for (int c = tid; c < 4096; c += 512) {
        const int D    = c * 16;
        const int s    = D >> 12;
        const int dr   = D & 4095;
        const int srcb = dr ^ (((dr >> 8) & 3) << 5);
        glds16(reinterpret_cast<const short*>(
                   reinterpret_cast<const char*>(z_e) + (size_t)(b0 + s) * 4096 + srcb),
               reinterpret_cast<short*>(reinterpret_cast<char*>(zsh) + D));
    }
    if (tid < 16) sflag[tid] = 0;
    __syncthreads();

    const int lane = tid & 63;
    const int w_id = tid >> 6;
    const int wr   = (w_id >> 1) * 32;
    const int wc   = (w_id & 1) * 64;
    const int l15  = lane & 15;
    const int lg   = lane >> 4;

    f32x4 acc[2][4];
    #pragma unroll
    for (int i = 0; i < 2; ++i)
        #pragma unroll
        for (int j = 0; j < 4; ++j) acc[i][j] = (f32x4){0.f, 0.f, 0.f, 0.f};

    #pragma unroll
    for (int ks = 0; ks < 4; ++ks) {
        bf16x8 bh[4], bl[4];
        #pragma unroll
        for (int cf = 0; cf < 4; ++cf) {
            const int n     = wc + cf * 16 + l15;
            const int slotp = (ks * 4 + lg) ^ (n & 7);
            const int off   = n * 128 + slotp * 8;
            bh[cf] = *reinterpret_cast<const bf16x8*>(&planes[off]);
            bl[cf] = *reinterpret_cast<const bf16x8*>(&planes[16384 + off]);
        }
        bf16x8 ah[2], al[2];
        #pragma unroll
        for (int rf = 0; rf < 2; ++rf) {
            const int row   = wr + rf * 16 + l15;
            const int s_loc = row >> 3;
            const int d     = row & 7;
            const int kb    = ks * 32 + lg * 8;
            const int xrr   = (lg & 3) << 5;
            const char* zb  = reinterpret_cast<const char*>(zsh) + s_loc * 4096;
            bf16x8 h8, L8;
            #pragma unroll
            for (int j = 0; j < 8; ++j) {
                const float a = *reinterpret_cast<const float*>(
                    zb + ((32 * (kb + j) + 4 * d) ^ xrr));
                const unsigned short hi = f32_to_bf16_rn(a);
                h8[j] = (short)hi;
                L8[j] = (short)f32_to_bf16_rn(a - bf16_bits_to_f32(hi));
            }
            ah[rf] = h8; al[rf] = L8;
        }
        #pragma unroll
        for (int rf = 0; rf < 2; ++rf)
            #pragma unroll
            for (int cf = 0; cf < 4; ++cf) {
                acc[rf][cf] = __builtin_amdgcn_mfma_f32_16x16x32_bf16(
                    ah[rf], bh[cf], acc[rf][cf], 0, 0, 0);
                acc[rf][cf] = __builtin_amdgcn_mfma_f32_16x16x32_bf16(
                    ah[rf], bl[cf], acc[rf][cf], 0, 0, 0);
                acc[rf][cf] = __builtin_amdgcn_mfma_f32_16x16x32_bf16(
                    al[rf], bh[cf], acc[rf][cf], 0, 0, 0);
            }
    }

    #pragma unroll
    for (int rf = 0; rf < 2; ++rf)
        #pragma unroll
        for (int j = 0; j < 4; ++j) {
            double v1 = 1e300, v2 = 1e300; int i1 = 0;
            #pragma unroll
            for (int cf = 0; cf < 4; ++cf) {
                const int n = wc + cf * 16 + l15;
                const double v = wn_sh[n] - 2.0 * (double)acc[rf][cf][j];
                if (v < v1)      { v2 = v1; v1 = v; i1 = n; }
                else if (v < v2) { v2 = v; }
            }
            #pragma unroll
            for (int off = 1; off < 16; off <<= 1) {
                const double ov1 = __shfl_xor(v1, off);
                const int    oi1 = __shfl_xor(i1, off);
                const double ov2 = __shfl_xor(v2, off);
                if (ov1 < v1 || (ov1 == v1 && oi1 < i1)) {
                    v2 = fmin(v1, ov2); v1 = ov1; i1 = oi1;
                } else {
                    v2 = fmin(v2, ov1);
                }
            }
            if (l15 == 0) {
                const int r = wr + rf * 16 + lg * 4 + j;
                cmb_v1[r][w_id & 1] = v1;
                cmb_v2[r][w_id & 1] = v2;
                cmb_i [r][w_id & 1] = i1;
            }
        }
    __syncthreads();

    if (tid < 128) {
        const double v1a = cmb_v1[tid][0], v1b = cmb_v1[tid][1];
        double v1, v2; int i1;
        if (v1b < v1a) { v1 = v1b; i1 = cmb_i[tid][1]; v2 = fmin(v1a, cmb_v2[tid][1]); }
        else           { v1 = v1a; i1 = cmb_i[tid][0]; v2 = fmin(v1b, cmb_v2[tid][0]); }
        idx_sh[tid] = i1;
        if (v2 - v1 < GAP_T) sflag[tid >> 3] = 1;
    }
    __syncthreads();
    if (tid < 16 && sflag[tid]) {
        const int p = atomicAdd(flag_cnt, 1);
        flag_ids[p] = b0 + tid;
    }

    for (int t = tid; t < 16384; t += 512) {
        const int s = t >> 10, i = t & 1023;
        const int k = i >> 3, d = i & 7;
        const int n = idx_sh[(s << 3) | d];
        const int off = n * 128 + (((k >> 3) ^ (n & 7)) << 3) + (k & 7);
        const float val = bf16_bits_to_f32((unsigned short)planes[off]) +
                          bf16_bits_to_f32((unsigned short)planes[16384 + off]);
        zq[(size_t)(b0 + s) * 1024 + i] = val;
        zqh[zq_plane_off(b0 + s, i)] = (short)f32_to_bf16_rn(val);
    }
}

// ================= fixup F1/F2: 64x64-tile f64 GEMM (NT) ===================
#define FLP 68
template<bool GATHER, bool SPLITK, bool FUSERED, typename TA>
__global__ __launch_bounds__(256) void gemm_f64t(
    const TA* __restrict__ A, const float* __restrict__ Wf,
    const int* __restrict__ ids, const int* __restrict__ cntp,
    const float* __restrict__ biasA, const float* __restrict__ bias,
    double* __restrict__ C,
    int AK, int N, int CN, int klen, int cap)
{
    __shared__ double As[16 * FLP];
    __shared__ double Ws[16 * FLP];

    const int tid = threadIdx.x;
    const int tx  = tid & 15;
    const int ty  = tid >> 4;
    const int m0  = blockIdx.y * 64;
    const int n0  = blockIdx.x * 64;
    const int cnt = (*cntp < cap) ? *cntp : cap;
    if (m0 >= cnt) return;

    const int k0 = SPLITK ? blockIdx.z * klen : 0;
    if (SPLITK) C += (size_t)blockIdx.z * cap * CN;

    const int srow = tid >> 2;
    const int sc4  = (tid & 3) << 2;

    const TA* arow;
    if (GATHER) {
        const int m  = m0 + srow;
        const int id = (m < cnt) ? ids[m] : 0;
        arow = A + (size_t)id * AK;
    } else {
        arow = A + (size_t)(m0 + srow) * AK;
    }
    const int   nrow = n0 + srow;
    const float* wrow = Wf + (size_t)(nrow < N ? nrow : 0) * AK;
    const bool  wok  = (nrow < N);

    double acc[4][4];
    #pragma unroll
    for (int i = 0; i < 4; ++i)
        #pragma unroll
        for (int j = 0; j < 4; ++j) acc[i][j] = 0.0;

    for (int kt = 0; kt < klen; kt += 16) {
        const int kb = k0 + kt + sc4;
        if constexpr (FUSERED) {
            const size_t cs = (size_t)cap * AK;
            #pragma unroll
            for (int e = 0; e < 4; ++e) {
                double s = (double)biasA[kb + e];
                #pragma unroll
                for (int c = 0; c < 6; ++c) s += arow[c * cs + kb + e];
                As[(sc4 + e) * FLP + srow] = s > 0.0 ? s : 0.0;
            }
        } else if constexpr (sizeof(TA) == 4) {
            const float4 v = *reinterpret_cast<const float4*>(&arow[kb]);
            As[(sc4 + 0) * FLP + srow] = (double)v.x;
            As[(sc4 + 1) * FLP + srow] = (double)v.y;
            As[(sc4 + 2) * FLP + srow] = (double)v.z;
            As[(sc4 + 3) * FLP + srow] = (double)v.w;
        } else {
            const double2 v0 = *reinterpret_cast<const double2*>(&arow[kb]);
            const double2 v1 = *reinterpret_cast<const double2*>(&arow[kb + 2]);
            As[(sc4 + 0) * FLP + srow] = v0.x;
            As[(sc4 + 1) * FLP + srow] = v0.y;
            As[(sc4 + 2) * FLP + srow] = v1.x;
            As[(sc4 + 3) * FLP + srow] = v1.y;
        }
        float4 w = make_float4(0.f, 0.f, 0.f, 0.f);
        if (wok) w = *reinterpret_cast<const float4*>(&wrow[kb]);
        Ws[(sc4 + 0) * FLP + srow] = (double)w.x;
        Ws[(sc4 + 1) * FLP + srow] = (double)w.y;
        Ws[(sc4 + 2) * FLP + srow] = (double)w.z;
        Ws[(sc4 + 3) * FLP + srow] = (double)w.w;
        __syncthreads();

        #pragma unroll
        for (int k = 0; k < 16; ++k) {
            const double2 A0 = *reinterpret_cast<const double2*>(&As[k * FLP + ty * 4]);
            const double2 A1 = *reinterpret_cast<const double2*>(&As[k * FLP + ty * 4 + 2]);
            const double2 B0 = *reinterpret_cast<const double2*>(&Ws[k * FLP + tx * 4]);
            const double2 B1 = *reinterpret_cast<const double2*>(&Ws[k * FLP + tx * 4 + 2]);
            const double a[4] = {A0.x, A0.y, A1.x, A1.y};
            const double b[4] = {B0.x, B0.y, B1.x, B1.y};
            #pragma unroll
            for (int i = 0; i < 4; ++i)
                #pragma unroll
                for (int j = 0; j < 4; ++j)
                    acc[i][j] = fma(a[i], b[j], acc[i][j]);
        }
        __syncthreads();
    }

    #pragma unroll
    for (int i = 0; i < 4; ++i) {
        const int row = m0 + ty * 4 + i;
        #pragma unroll
        for (int j = 0; j < 4; ++j) {
            const int col = n0 + tx * 4 + j;
            if (col < N)
                C[(size_t)row * CN + col] =
                    acc[i][j] + (bias ? (double)bias[col] : 0.0);
        }
    }
}

// ======= fixup F3: exact f64 distances + argmin + z_q scatter ===============
__global__ __launch_bounds__(512) void fix_argmin(
    const double* __restrict__ Zf, const float* __restrict__ Wemb,
    const int* __restrict__ cntp, const int* __restrict__ ids,
    float* __restrict__ zq, short* __restrict__ zqh, int cap)
{
    __shared__ float  wesh[16384];
    __shared__ double zsh[4][1032];
    __shared__ double dist[4 * 8 * 128];
    __shared__ int    idxf[32];

    const int tid  = threadIdx.x;
    const int lane = tid & 63;
    const int wv   = tid >> 6;
    const int cnt  = (*cntp < cap) ? *cntp : cap;
    const int base = blockIdx.x * 4;
    if (base >= cnt) return;
    const int ns = (cnt - base < 4) ? (cnt - base) : 4;

    for (int i = tid; i < 4096; i += 512)
        glds16(reinterpret_cast<const short*>(Wemb) + (size_t)i * 8,
               reinterpret_cast<short*>(wesh) + (size_t)i * 8);
    for (int i = tid; i < 4 * 512; i += 512) {
        const int s = i >> 9, e = (i & 511) * 2;
        if (s < ns) {
            const double2 v = *reinterpret_cast<const double2*>(
                &Zf[(size_t)(base + s) * 1024 + e]);
            zsh[s][e] = v.x;
            zsh[s][e + 1] = v.y;
        }
    }
    __syncthreads();

    for (int t = tid; t < ns * 1024; t += 512) {
        const int s = t >> 10, d = (t >> 7) & 7, n = t & 127;
        double acc = 0.0;
        for (int k = 0; k < 128; ++k) {
            const double diff = zsh[s][k * 8 + d] - (double)wesh[k * 128 + n];
            acc = fma(diff, diff, acc);
        }
        dist[(s * 8 + d) * 128 + n] = acc;
    }
    __syncthreads();

    for (int p = wv; p < ns * 8; p += 8) {
        const double* dp = &dist[p * 128];
        double v0 = dp[lane], vx = dp[lane + 64];
        double v; int ix;
        if (vx < v0) { v = vx; ix = lane + 64; }
        else         { v = v0; ix = lane; }
        #pragma unroll
        for (int off = 32; off > 0; off >>= 1) {
            const double ov = __shfl_down(v, off);
            const int    oi = __shfl_down(ix, off);
            if (ov < v || (ov == v && oi < ix)) { v = ov; ix = oi; }
        }
        if (lane == 0) idxf[p] = ix;
    }
    __syncthreads();

    for (int i = tid; i < ns * 1024; i += 512) {
        const int s = i >> 10, ii = i & 1023;
        const int id = ids[base + s];
        const float val = wesh[(ii >> 3) * 128 + idxf[s * 8 + (ii & 7)]];
        zq[(size_t)id * 1024 + ii] = val;
        zqh[zq_plane_off(id, ii)] = (short)f32_to_bf16_rn(val);
    }
}

// ---------------------------------------------------------------------------
extern "C" void kernel_launch(void* const* d_in, const int* in_sizes, int n_in,
                              void* d_out, int out_size, void* d_ws, size_t ws_size,
                              hipStream_t stream)
{
    const float* x    = (const float*)d_in[0];
    const float* W1   = (const float*)d_in[1];
    const float* b1   = (const float*)d_in[2];
    const float* W2   = (const float*)d_in[3];
    const float* b2   = (const float*)d_in[4];
    const float* W3   = (const float*)d_in[5];
    const float* b3   = (const float*)d_in[6];
    const float* W4   = (const float*)d_in[7];
    const float* b4   = (const float*)d_in[8];
    const float* Wemb = (const float*)d_in[9];

    const int B = 16384;
    float* out   = (float*)d_out;
    float* recon = out;                                // B*3072
    float* z_e   = out + (size_t)B * 3072;             // B*1024
    float* emb_o = z_e + (size_t)B * 1024;             // B*1024 == z_q

    constexpr size_t H1_PL = 6815744;
    constexpr size_t H3_PL = 6815744;
    constexpr size_t W1_PL = 1572864;
    constexpr size_t W2_PL = 425984;
    constexpr size_t W3_PL = 524288;
    constexpr size_t W4_PL = 1277952;

    short* h1h = (short*)emb_o;          // h1 planes in emb_o section
    short* h1l = h1h + H1_PL;

    short*  h3h      = (short*)d_ws;
    short*  w1h      = h3h + H3_PL;
    short*  w1l      = w1h + W1_PL;
    short*  w2h      = w1l + W1_PL;
    short*  w2l      = w2h + W2_PL;
    short*  w3h      = w2l + W2_PL;
    short*  w4h      = w3h + W3_PL;
    short*  wembpl   = w4h + W4_PL;
    double* wn       = (double*)(wembpl + 32768);
    int*    flag_cnt = (int*)(wn + 128);
    int*    flag_ids = flag_cnt + 64;

    // recon-section scratch (dead until g4 writes recon last):
    // Part[6] @ +0 (78.6MB), Zf @ +96MB (33.5MB), zqh plane @ +144MB (33.5MB)
    char*   scr  = (char*)recon;
    double* Part = (double*)scr;
    double* Zf   = (double*)(scr + (96ull  << 20));
    short*  zqh  = (short*) (scr + (144ull << 20));

    // ---- prep (W planes | VQ prep) ----
    prep_all<<<dim3(929), dim3(256), 0, stream>>>(
        W1, W2, W3, W4, Wemb, w1h, w1l, w2h, w2l, w3h, w4h,
        wembpl, wn, flag_cnt);

    // ---- encoder (XCD-grouped 1D grids: XNBX col-blocks per row-group) ----
    gemm_pl<2, 1, 1, 2, 4><<<dim3(512), dim3(256), 0, stream>>>(
        nullptr, nullptr, x, 3072, w1h, w1l, b1, nullptr, h1h, h1l, 400, 96, 13);
    gemm_pl<2, 0, 0, 0, 8><<<dim3(1024), dim3(256), 0, stream>>>(
        h1h, h1l, nullptr, 0, w2h, w2l, b2, z_e, nullptr, nullptr, 1024, 13, 0);

    // ---- VQ + fixup ----
    vq_mfma<<<dim3(1024), dim3(512), 0, stream>>>(z_e, wembpl, wn, emb_o, zqh,
                                                  flag_cnt, flag_ids);
    gemm_f64t<true, true, false, float><<<dim3(7, FIX_CAP / 64, 6), dim3(256), 0, stream>>>(
        x, W1, flag_ids, flag_cnt, nullptr, nullptr, Part, 3072, 400, 400, 512, FIX_CAP);
    gemm_f64t<false, false, true, double><<<dim3(16, FIX_CAP / 64), dim3(256), 0, stream>>>(
        Part, W2, nullptr, flag_cnt, b1, b2, Zf, 400, 1024, 1024, 400, FIX_CAP);
    fix_argmin<<<dim3(FIX_CAP / 4), dim3(512), 0, stream>>>(
        Zf, Wemb, flag_cnt, flag_ids, emb_o, zqh, FIX_CAP);

    // ---- decoder (XCD-grouped) ----
    gemm_pl<1, 1, 0, 1, 4><<<dim3(512), dim3(256), 0, stream>>>(
        zqh, nullptr, nullptr, 0, w3h, nullptr, b3, nullptr, h3h, nullptr,
        400, 32, 13);
    gemm_pl<1, 2, 0, 0, 24><<<dim3(3072), dim3(256), 0, stream>>>(
        h3h, nullptr, nullptr, 0, w4h, nullptr, b4, recon, nullptr, nullptr,
        3072, 13, 0);
}